// Round 1
// 604.524 us; speedup vs baseline: 1.2008x; 1.2008x over previous
//
#include <hip/hip_runtime.h>
#include <cstddef>

// UniPhyBlock on gfx950 — f32 inputs, f32 internal pipeline, F32 PLANAR OUTPUT.
// Round 12: k7_pool rewritten as bf16-MFMA GEMM pair (was 216us VALU/LDS-issue
// bound f32 FMA: MfmaUtil=0, VALUBusy=50%, 6.3M LDS bank conflicts).
// Activations hi/lo-split bf16 (f32-accurate); weights/hidden single bf16
// (~3e-3 extra error vs 0.0625 budget). Everything else unchanged.
// Output: PLANAR f32 — out[cidx]=real, out[ND+cidx]=imag, cidx over [B,T,D,H,W].
// ws (f32): [0]=zn_re (later x_re), [1]=zn_im (later x_im), [2]=cliff_re,
//           [3]=cliff_im, [4]=freq_re, [5]=freq_im  -> 6*ND*4B = 96 MB.

#define EPS_ 1e-5f
#define PI_  3.14159265358979323846f
#define ND_  4194304ull

typedef __attribute__((ext_vector_type(8))) short bf16x8;   // 8 bf16 (4 VGPRs)
typedef __attribute__((ext_vector_type(4))) float f32x4;    // MFMA C/D

__device__ __forceinline__ short f2bf(float f) {
  unsigned u = __float_as_uint(f);
  unsigned r = (u + 0x7fffu + ((u >> 16) & 1u)) >> 16;  // RNE
  return (short)r;
}

// ---------------- K1: input transpose + spatial cnorm ----------------
__global__ __launch_bounds__(256) void k1_cnorm_spatial(
    const float* __restrict__ xr, const float* __restrict__ xi,
    const float* __restrict__ g, const float* __restrict__ b,
    float* __restrict__ znr, float* __restrict__ zni) {
  int tok = blockIdx.x * 256 + threadIdx.x;      // (bt,h,w)
  int bt = tok >> 12;
  int hw = tok & 4095;
  const float* pr = xr + (size_t)bt * 131072 + hw;   // bt*D*HW
  const float* pi = xi + (size_t)bt * 131072 + hw;
  float r[32], q[32];
  float s = 0.f;
#pragma unroll
  for (int d = 0; d < 32; d++) {
    r[d] = pr[(size_t)d * 4096];
    q[d] = pi[(size_t)d * 4096];
    s += r[d] + q[d];
  }
  float mu = s * 0.015625f;
  float v = 0.f;
#pragma unroll
  for (int d = 0; d < 32; d++) {
    float a = r[d] - mu, c = q[d] - mu;
    v += a * a + c * c;
  }
  float rstd = rsqrtf(v * 0.015625f + EPS_);
#pragma unroll
  for (int d = 0; d < 32; d++) {
    r[d] = (r[d] - mu) * rstd * g[d] + b[d];
    q[d] = (q[d] - mu) * rstd * g[32 + d] + b[32 + d];
  }
  float4* outr = (float4*)(znr + (size_t)tok * 32);
  float4* outi = (float4*)(zni + (size_t)tok * 32);
#pragma unroll
  for (int j = 0; j < 8; j++) {
    outr[j] = make_float4(r[4 * j], r[4 * j + 1], r[4 * j + 2], r[4 * j + 3]);
    outi[j] = make_float4(q[4 * j], q[4 * j + 1], q[4 * j + 2], q[4 * j + 3]);
  }
}

// ---------------- K2: 3x3 SAME conv via bf16 MFMA implicit GEMM ----------------
// Block = one (bt,h) output row: M=64 tokens(w) x N=64 oc, K=9*64.
__global__ __launch_bounds__(256) void k2_conv(
    const float* __restrict__ znr, const float* __restrict__ zni,
    const float* __restrict__ wgt, const float* __restrict__ bias,
    float* __restrict__ clr, float* __restrict__ cli) {
  __shared__ __align__(16) short sA[3 * 66 * 88];  // 34.8 KB
  __shared__ __align__(16) short sB[64 * 88];      // 11.3 KB
  int h = blockIdx.x, bt = blockIdx.y;
  // stage activations (3 rows, w in [-1,64], 64 ch) as bf16
  for (int i = threadIdx.x; i < 3 * 66 * 64; i += 256) {
    int c = i & 63;
    int wp = (i >> 6) % 66;
    int rr = i / (66 * 64);
    int hh = h + rr - 1;
    int w = wp - 1;
    float v = 0.f;
    if ((unsigned)hh < 64u && (unsigned)w < 64u) {
      int tok = (bt * 64 + hh) * 64 + w;
      v = (c < 32) ? znr[(size_t)tok * 32 + c] : zni[(size_t)tok * 32 + c - 32];
    }
    sA[(rr * 66 + wp) * 88 + c] = f2bf(v);
  }
  int lane = threadIdx.x & 63;
  int wv = threadIdx.x >> 6;
  int m0 = wv * 16;          // this wave's 16-token strip
  int lr = lane & 15;        // A-row / B-col / D-col
  int quad = lane >> 4;      // k-chunk selector; D-row group
  f32x4 acc[4];
#pragma unroll
  for (int nt = 0; nt < 4; nt++) {
    float bz = bias[nt * 16 + lr];
    acc[nt][0] = bz; acc[nt][1] = bz; acc[nt][2] = bz; acc[nt][3] = bz;
  }
  for (int kk = 0; kk < 9; kk++) {
    int kh = kk / 3, kw = kk - kh * 3;
    __syncthreads();
    // stage weight chunk transposed: sB[oc][ic] = wgt[kk][ic][oc]
    for (int i = threadIdx.x; i < 4096; i += 256) {
      int oc = i & 63;
      int ic = i >> 6;
      sB[oc * 88 + ic] = f2bf(wgt[((size_t)kk * 64 + ic) * 64 + oc]);
    }
    __syncthreads();
    // A row for this lane: w_in = (m0+lr) + kw - 1  -> wpos = m0+lr+kw
    const short* arow = &sA[((size_t)kh * 66 + (m0 + lr + kw)) * 88 + quad * 8];
#pragma unroll
    for (int ks = 0; ks < 2; ks++) {
      bf16x8 afrag = *(const bf16x8*)(arow + ks * 32);
#pragma unroll
      for (int nt = 0; nt < 4; nt++) {
        bf16x8 bfrag = *(const bf16x8*)&sB[(size_t)(nt * 16 + lr) * 88 + ks * 32 + quad * 8];
        acc[nt] = __builtin_amdgcn_mfma_f32_16x16x32_bf16(afrag, bfrag, acc[nt], 0, 0, 0);
      }
    }
  }
  // epilogue: D[row=quad*4+reg][col=lr] per n-tile -> clr/cli (f32)
  int tokbase = (bt * 64 + h) * 64 + m0;
#pragma unroll
  for (int nt = 0; nt < 4; nt++) {
    int oc = nt * 16 + lr;
    float* dst = (oc < 32) ? (clr + oc) : (cli + (oc - 32));
#pragma unroll
    for (int reg = 0; reg < 4; reg++) {
      int m = quad * 4 + reg;
      dst[(size_t)(tokbase + m) * 32] = acc[nt][reg];
    }
  }
}

// ---------------- K3: forward DFT along W ----------------
__global__ __launch_bounds__(256) void k3_dftw(
    const float* __restrict__ znr, const float* __restrict__ zni,
    float* __restrict__ fqr, float* __restrict__ fqi) {
  __shared__ float sr[2048], si[2048];
  __shared__ float twr[64], twi[64];
  int h = blockIdx.x, bt = blockIdx.y;
  size_t base = (size_t)((bt * 64 + h) * 64) * 32;
  if (threadIdx.x < 64) {
    float ang = -2.f * PI_ * (float)threadIdx.x * (1.f / 64.f);
    twr[threadIdx.x] = cosf(ang);
    twi[threadIdx.x] = sinf(ang);
  }
  for (int i = threadIdx.x; i < 2048; i += 256) {
    sr[i] = znr[base + i];
    si[i] = zni[base + i];
  }
  __syncthreads();
  int k = threadIdx.x & 63;
  int dbase = (threadIdx.x >> 6) * 8;
  float ar[8] = {0, 0, 0, 0, 0, 0, 0, 0}, ai[8] = {0, 0, 0, 0, 0, 0, 0, 0};
  for (int w = 0; w < 64; w++) {
    int idx = (w * k) & 63;
    float tr = twr[idx], ti = twi[idx];
    const float4* pr4 = (const float4*)&sr[w * 32 + dbase];
    const float4* pi4 = (const float4*)&si[w * 32 + dbase];
    float4 a0 = pr4[0], a1 = pr4[1], b0 = pi4[0], b1 = pi4[1];
    float rr[8] = {a0.x, a0.y, a0.z, a0.w, a1.x, a1.y, a1.z, a1.w};
    float ii[8] = {b0.x, b0.y, b0.z, b0.w, b1.x, b1.y, b1.z, b1.w};
#pragma unroll
    for (int j = 0; j < 8; j++) {
      ar[j] += rr[j] * tr - ii[j] * ti;
      ai[j] += rr[j] * ti + ii[j] * tr;
    }
  }
  __syncthreads();
#pragma unroll
  for (int j = 0; j < 8; j++) {
    sr[k * 32 + dbase + j] = ar[j];
    si[k * 32 + dbase + j] = ai[j];
  }
  __syncthreads();
  for (int i = threadIdx.x; i < 2048; i += 256) {
    fqr[base + i] = sr[i];
    fqi[base + i] = si[i];
  }
}

// ---------------- K4: fwd DFT along H, * filt, inv DFT along H (in place) ----------------
__global__ __launch_bounds__(256) void k4_dfth(
    float* __restrict__ fqr, float* __restrict__ fqi,
    const float* __restrict__ flr, const float* __restrict__ fli) {
  __shared__ float sr[2048], si[2048], Fr[2048], Fi[2048];
  __shared__ float twr[64], twi[64];
  int kw = blockIdx.x, bt = blockIdx.y;
  if (threadIdx.x < 64) {
    float ang = -2.f * PI_ * (float)threadIdx.x * (1.f / 64.f);
    twr[threadIdx.x] = cosf(ang);
    twi[threadIdx.x] = sinf(ang);
  }
  for (int i = threadIdx.x; i < 2048; i += 256) {
    int hh = i >> 5, d = i & 31;
    size_t ga = (size_t)((bt * 64 + hh) * 64 + kw) * 32 + d;
    sr[i] = fqr[ga];
    si[i] = fqi[ga];
  }
  __syncthreads();
  int kh = threadIdx.x & 63;
  int dbase = (threadIdx.x >> 6) * 8;
  {
    float ar[8] = {0, 0, 0, 0, 0, 0, 0, 0}, ai[8] = {0, 0, 0, 0, 0, 0, 0, 0};
    for (int hh = 0; hh < 64; hh++) {
      int idx = (hh * kh) & 63;
      float tr = twr[idx], ti = twi[idx];
      const float4* pr4 = (const float4*)&sr[hh * 32 + dbase];
      const float4* pi4 = (const float4*)&si[hh * 32 + dbase];
      float4 a0 = pr4[0], a1 = pr4[1], b0 = pi4[0], b1 = pi4[1];
      float rr[8] = {a0.x, a0.y, a0.z, a0.w, a1.x, a1.y, a1.z, a1.w};
      float ii[8] = {b0.x, b0.y, b0.z, b0.w, b1.x, b1.y, b1.z, b1.w};
#pragma unroll
      for (int j = 0; j < 8; j++) {
        ar[j] += rr[j] * tr - ii[j] * ti;
        ai[j] += rr[j] * ti + ii[j] * tr;
      }
    }
    // multiply by filt[kh][kw][d]
    const float4* fr4 = (const float4*)&flr[(size_t)(kh * 64 + kw) * 32 + dbase];
    const float4* fi4 = (const float4*)&fli[(size_t)(kh * 64 + kw) * 32 + dbase];
    float4 f0 = fr4[0], f1 = fr4[1], g0 = fi4[0], g1 = fi4[1];
    float fre[8] = {f0.x, f0.y, f0.z, f0.w, f1.x, f1.y, f1.z, f1.w};
    float fim[8] = {g0.x, g0.y, g0.z, g0.w, g1.x, g1.y, g1.z, g1.w};
#pragma unroll
    for (int j = 0; j < 8; j++) {
      float pr = ar[j] * fre[j] - ai[j] * fim[j];
      float pi = ar[j] * fim[j] + ai[j] * fre[j];
      Fr[kh * 32 + dbase + j] = pr;
      Fi[kh * 32 + dbase + j] = pi;
    }
  }
  __syncthreads();
  int hh2 = threadIdx.x & 63;
  {
    float ar[8] = {0, 0, 0, 0, 0, 0, 0, 0}, ai[8] = {0, 0, 0, 0, 0, 0, 0, 0};
    for (int k2 = 0; k2 < 64; k2++) {
      int idx = (hh2 * k2) & 63;
      float tr = twr[idx], ti = -twi[idx];  // conj -> inverse
      const float4* pr4 = (const float4*)&Fr[k2 * 32 + dbase];
      const float4* pi4 = (const float4*)&Fi[k2 * 32 + dbase];
      float4 a0 = pr4[0], a1 = pr4[1], b0 = pi4[0], b1 = pi4[1];
      float rr[8] = {a0.x, a0.y, a0.z, a0.w, a1.x, a1.y, a1.z, a1.w};
      float ii[8] = {b0.x, b0.y, b0.z, b0.w, b1.x, b1.y, b1.z, b1.w};
#pragma unroll
      for (int j = 0; j < 8; j++) {
        ar[j] += rr[j] * tr - ii[j] * ti;
        ai[j] += rr[j] * ti + ii[j] * tr;
      }
    }
#pragma unroll
    for (int j = 0; j < 8; j++) {
      sr[hh2 * 32 + dbase + j] = ar[j] * 0.015625f;  // 1/64 (H-inverse)
      si[hh2 * 32 + dbase + j] = ai[j] * 0.015625f;
    }
  }
  __syncthreads();
  for (int i = threadIdx.x; i < 2048; i += 256) {
    int hh = i >> 5, d = i & 31;
    size_t ga = (size_t)((bt * 64 + hh) * 64 + kw) * 32 + d;
    fqr[ga] = sr[i];
    fqi[ga] = si[i];
  }
}

// ---------------- K5: inv DFT along W + gate combine + residual -> x ----------------
__global__ __launch_bounds__(256) void k5_idftw_combine(
    const float* __restrict__ fqr, const float* __restrict__ fqi,
    const float* __restrict__ clr, const float* __restrict__ cli,
    const float* __restrict__ xr_in, const float* __restrict__ xi_in,
    const float* __restrict__ gate,
    float* __restrict__ xr, float* __restrict__ xi) {
  __shared__ float sr[2048], si[2048];
  __shared__ float twr[64], twi[64];
  int h = blockIdx.x, bt = blockIdx.y;
  size_t base = (size_t)((bt * 64 + h) * 64) * 32;
  if (threadIdx.x < 64) {
    float ang = -2.f * PI_ * (float)threadIdx.x * (1.f / 64.f);
    twr[threadIdx.x] = cosf(ang);
    twi[threadIdx.x] = sinf(ang);
  }
  for (int i = threadIdx.x; i < 2048; i += 256) {
    sr[i] = fqr[base + i];
    si[i] = fqi[base + i];
  }
  __syncthreads();
  int w = threadIdx.x & 63;
  int dbase = (threadIdx.x >> 6) * 8;
  float ar[8] = {0, 0, 0, 0, 0, 0, 0, 0}, ai[8] = {0, 0, 0, 0, 0, 0, 0, 0};
  for (int kw = 0; kw < 64; kw++) {
    int idx = (w * kw) & 63;
    float tr = twr[idx], ti = -twi[idx];
    const float4* pr4 = (const float4*)&sr[kw * 32 + dbase];
    const float4* pi4 = (const float4*)&si[kw * 32 + dbase];
    float4 a0 = pr4[0], a1 = pr4[1], b0 = pi4[0], b1 = pi4[1];
    float rr[8] = {a0.x, a0.y, a0.z, a0.w, a1.x, a1.y, a1.z, a1.w};
    float ii[8] = {b0.x, b0.y, b0.z, b0.w, b1.x, b1.y, b1.z, b1.w};
#pragma unroll
    for (int j = 0; j < 8; j++) {
      ar[j] += rr[j] * tr - ii[j] * ti;
      ai[j] += rr[j] * ti + ii[j] * tr;
    }
  }
  float g = gate[0];
  float gi = 1.f - g;
  const float4* c4r = (const float4*)&clr[base + w * 32 + dbase];
  const float4* c4i = (const float4*)&cli[base + w * 32 + dbase];
  float4 cr0 = c4r[0], cr1 = c4r[1], ci0 = c4i[0], ci1 = c4i[1];
  float cre[8] = {cr0.x, cr0.y, cr0.z, cr0.w, cr1.x, cr1.y, cr1.z, cr1.w};
  float cim[8] = {ci0.x, ci0.y, ci0.z, ci0.w, ci1.x, ci1.y, ci1.z, ci1.w};
  float orr[8], oii[8];
#pragma unroll
  for (int j = 0; j < 8; j++) {
    int d = dbase + j;
    size_t ga = (size_t)(bt * 32 + d) * 4096 + h * 64 + w;  // input [B,T,D,H,W]
    orr[j] = g * cre[j] + gi * (ar[j] * 0.015625f) + xr_in[ga];
    oii[j] = g * cim[j] + gi * (ai[j] * 0.015625f) + xi_in[ga];
  }
  __syncthreads();
#pragma unroll
  for (int j = 0; j < 8; j++) {
    sr[w * 32 + dbase + j] = orr[j];
    si[w * 32 + dbase + j] = oii[j];
  }
  __syncthreads();
  for (int i = threadIdx.x; i < 2048; i += 256) {
    xr[base + i] = sr[i];
    xi[base + i] = si[i];
  }
}

// ---------------- K6: temporal cnorm + eigen encode + decay scan + decode ----------------
__global__ __launch_bounds__(256) void k6_temporal(
    float* __restrict__ xr, float* __restrict__ xi,
    const float* __restrict__ lamr, const float* __restrict__ lami,
    const float* __restrict__ Er, const float* __restrict__ Ei,
    const float* __restrict__ Dmr, const float* __restrict__ Dmi,
    const float* __restrict__ lg, const float* __restrict__ lb,
    const float* __restrict__ dtp) {
  __shared__ float sEr[1024], sEi[1024], sDr[1024], sDi[1024];
  __shared__ float htr[128 * 33], hti[128 * 33];  // xt, then h (overwritten per t)
  int n0 = blockIdx.x * 8;
  for (int i = threadIdx.x; i < 1024; i += 256) {
    sEr[i] = Er[i];
    sEi[i] = Ei[i];
    sDr[i] = Dmr[i];
    sDi[i] = Dmi[i];
  }
  if (threadIdx.x < 128) {
    int sI = threadIdx.x >> 4;
    int t = threadIdx.x & 15;
    int n = n0 + sI;
    int bb = n >> 12;
    int hw = n & 4095;
    size_t tokb = ((size_t)(bb * 16 + t)) * 4096 + hw;
    const float4* pr = (const float4*)(xr + tokb * 32);
    const float4* pi = (const float4*)(xi + tokb * 32);
    float rv[32], iv[32];
    float s = 0.f;
#pragma unroll
    for (int j = 0; j < 8; j++) {
      float4 a = pr[j];
      float4 c = pi[j];
      rv[4 * j] = a.x; rv[4 * j + 1] = a.y; rv[4 * j + 2] = a.z; rv[4 * j + 3] = a.w;
      iv[4 * j] = c.x; iv[4 * j + 1] = c.y; iv[4 * j + 2] = c.z; iv[4 * j + 3] = c.w;
      s += a.x + a.y + a.z + a.w + c.x + c.y + c.z + c.w;
    }
    float mu = s * 0.015625f;
    float v = 0.f;
#pragma unroll
    for (int d = 0; d < 32; d++) {
      float a = rv[d] - mu, c = iv[d] - mu;
      v += a * a + c * c;
    }
    float rstd = rsqrtf(v * 0.015625f + EPS_);
    int row = threadIdx.x * 33;
#pragma unroll
    for (int d = 0; d < 32; d++) {
      htr[row + d] = (rv[d] - mu) * rstd * lg[d] + lb[d];
      hti[row + d] = (iv[d] - mu) * rstd * lg[32 + d] + lb[32 + d];
    }
  }
  __syncthreads();
  int sI = threadIdx.x >> 5;
  int e = threadIdx.x & 31;
  float dts = dtp[0];
  float lr = lamr[e], li = lami[e];
  float ex = expf(lr * dts);
  float dcr = ex * cosf(li * dts);
  float dci = ex * sinf(li * dts);
  float nr = dcr - 1.f, ni = dci;
  float invden = 1.f / (lr * lr + li * li);
  float fr = (nr * lr + ni * li) * invden;
  float fi = (ni * lr - nr * li) * invden;
  float hr = 0.f, hi = 0.f;
  for (int t = 0; t < 16; t++) {
    int row = (sI * 16 + t) * 33;
    float xer = 0.f, xei = 0.f;
#pragma unroll
    for (int d = 0; d < 32; d++) {
      float a = htr[row + d], c = hti[row + d];
      float er_ = sEr[d * 32 + e], ei_ = sEi[d * 32 + e];
      xer += a * er_ - c * ei_;
      xei += a * ei_ + c * er_;
    }
    float ur = xer * fr - xei * fi;
    float ui = xer * fi + xei * fr;
    float t1 = dcr * hr - dci * hi + ur;
    hi = dcr * hi + dci * hr + ui;
    hr = t1;
    __syncthreads();
    htr[row + e] = hr;
    hti[row + e] = hi;
    __syncthreads();
  }
  for (int t = 0; t < 16; t++) {
    int row = (sI * 16 + t) * 33;
    float acc = 0.f;
#pragma unroll
    for (int d = 0; d < 32; d++) {
      acc += htr[row + d] * sDr[d * 32 + e] - hti[row + d] * sDi[d * 32 + e];
    }
    int n = n0 + sI;
    int bb = n >> 12;
    int hw = n & 4095;
    size_t tokb = ((size_t)(bb * 16 + t)) * 4096 + hw;
    xr[tokb * 32 + e] += acc;  // drift is real-only
  }
}

// ---------------- K7: para pool MLP via bf16 MFMA + residual + output (F32 PLANAR) ----------------
// Block = 64 tokens, 4 waves x 16-token strips. GEMM1 (K=64, N=256 in 4 chunks
// of 64 hidden ch) -> gelu -> f32 LDS transpose -> GEMM2 (K=256 accumulated
// across chunks, N=64). Activations split hi/lo bf16 -> two MFMAs per tile
// gives ~f32 input precision; hidden + weights single bf16.
__global__ __launch_bounds__(256) void k7_pool(
    const float* __restrict__ xr, const float* __restrict__ xi,
    const float* __restrict__ pw1, const float* __restrict__ pb1,
    const float* __restrict__ pw2, const float* __restrict__ pb2,
    float* __restrict__ out, long long out_n) {
  __shared__ __align__(16) short sXh[64 * 72];  // xp hi bf16 [tok][c]   9.2 KB
  __shared__ __align__(16) short sXl[64 * 72];  // xp lo bf16            9.2 KB
  __shared__ __align__(16) short sW[64 * 72];   // weight chunk [n][k]   9.2 KB
  __shared__ __align__(16) float sH[64 * 68];   // hidden f32 [tok][el] 17.4 KB
  int tok0 = blockIdx.x * 64;
  // stage xp as hi/lo bf16 pair: x = hi + lo to ~16 mantissa bits
  for (int i = threadIdx.x; i < 4096; i += 256) {
    int t = i >> 6, c = i & 63;
    float v = (c < 32) ? xr[(size_t)(tok0 + t) * 32 + c]
                       : xi[(size_t)(tok0 + t) * 32 + c - 32];
    short hb = f2bf(v);
    float hf = __uint_as_float(((unsigned)(unsigned short)hb) << 16);
    sXh[t * 72 + c] = hb;
    sXl[t * 72 + c] = f2bf(v - hf);
  }
  int lane = threadIdx.x & 63;
  int wv = threadIdx.x >> 6;
  int lr = lane & 15;
  int quad = lane >> 4;
  int m0 = wv * 16;          // this wave's 16-token strip
  f32x4 acc2[4];             // persistent GEMM2 accumulator, bias preloaded
#pragma unroll
  for (int nt = 0; nt < 4; nt++) {
    float bz = pb2[nt * 16 + lr];
    acc2[nt][0] = bz; acc2[nt][1] = bz; acc2[nt][2] = bz; acc2[nt][3] = bz;
  }
  for (int ec = 0; ec < 4; ec++) {
    __syncthreads();  // prev GEMM2 done with sW/sH; xp staged (ec=0)
    // stage w1 chunk: sW[el][c] = w1[ec*64+el][c]  (already B^T layout)
    for (int i = threadIdx.x; i < 4096; i += 256) {
      int el = i >> 6, c = i & 63;
      sW[el * 72 + c] = f2bf(pw1[(size_t)(ec * 64 + el) * 64 + c]);
    }
    __syncthreads();
    f32x4 acc1[4];
#pragma unroll
    for (int nt = 0; nt < 4; nt++) {
      float bz = pb1[ec * 64 + nt * 16 + lr];
      acc1[nt][0] = bz; acc1[nt][1] = bz; acc1[nt][2] = bz; acc1[nt][3] = bz;
    }
    const short* arh = &sXh[(size_t)(m0 + lr) * 72 + quad * 8];
    const short* arl = &sXl[(size_t)(m0 + lr) * 72 + quad * 8];
#pragma unroll
    for (int ks = 0; ks < 2; ks++) {
      bf16x8 ah = *(const bf16x8*)(arh + ks * 32);
      bf16x8 al = *(const bf16x8*)(arl + ks * 32);
#pragma unroll
      for (int nt = 0; nt < 4; nt++) {
        bf16x8 bfrag = *(const bf16x8*)&sW[(size_t)(nt * 16 + lr) * 72 + ks * 32 + quad * 8];
        acc1[nt] = __builtin_amdgcn_mfma_f32_16x16x32_bf16(ah, bfrag, acc1[nt], 0, 0, 0);
        acc1[nt] = __builtin_amdgcn_mfma_f32_16x16x32_bf16(al, bfrag, acc1[nt], 0, 0, 0);
      }
    }
    // gelu (tanh approx, jax default) -> sH[tok][e_local] (f32, 2-way banks = free)
#pragma unroll
    for (int nt = 0; nt < 4; nt++) {
#pragma unroll
      for (int reg = 0; reg < 4; reg++) {
        float x = acc1[nt][reg];
        float u = 0.7978845608f * (x + 0.044715f * x * x * x);
        float e2 = __expf(2.f * u);
        float th = 1.f - 2.f / (e2 + 1.f);
        sH[(m0 + quad * 4 + reg) * 68 + nt * 16 + lr] = 0.5f * x * (1.f + th);
      }
    }
    __syncthreads();  // GEMM1 reads of sW done, sH writes done
    // stage w2 chunk: sW[oc][el] = w2[oc][ec*64+el]
    for (int i = threadIdx.x; i < 4096; i += 256) {
      int oc = i >> 6, el = i & 63;
      sW[oc * 72 + el] = f2bf(pw2[(size_t)oc * 256 + ec * 64 + el]);
    }
    __syncthreads();
    // GEMM2: A = gelu(hidden) converted bf16 on the fly, accumulate into acc2
    const float* hrow = &sH[(size_t)(m0 + lr) * 68 + quad * 8];
#pragma unroll
    for (int ks = 0; ks < 2; ks++) {
      float4 h0 = *(const float4*)(hrow + ks * 32);
      float4 h1 = *(const float4*)(hrow + ks * 32 + 4);
      bf16x8 af;
      af[0] = f2bf(h0.x); af[1] = f2bf(h0.y); af[2] = f2bf(h0.z); af[3] = f2bf(h0.w);
      af[4] = f2bf(h1.x); af[5] = f2bf(h1.y); af[6] = f2bf(h1.z); af[7] = f2bf(h1.w);
#pragma unroll
      for (int nt = 0; nt < 4; nt++) {
        bf16x8 bfrag = *(const bf16x8*)&sW[(size_t)(nt * 16 + lr) * 72 + ks * 32 + quad * 8];
        acc2[nt] = __builtin_amdgcn_mfma_f32_16x16x32_bf16(af, bfrag, acc2[nt], 0, 0, 0);
      }
    }
  }
  // epilogue: D[row=quad*4+reg][col=lr] -> + residual -> planar f32 out
#pragma unroll
  for (int nt = 0; nt < 4; nt++) {
    int oc = nt * 16 + lr;
#pragma unroll
    for (int reg = 0; reg < 4; reg++) {
      int t = tok0 + m0 + quad * 4 + reg;
      float resid = (oc < 32) ? xr[(size_t)t * 32 + oc] : xi[(size_t)t * 32 + oc - 32];
      float val = acc2[nt][reg] + resid;
      int bt = t >> 12;
      int hw = t & 4095;
      int d = (oc < 32) ? oc : oc - 32;
      size_t cidx = (size_t)(bt * 32 + d) * 4096 + hw;  // [B,T,D,H,W] index
      long long pos = (long long)cidx + ((oc < 32) ? 0ll : (long long)ND_);
      if (pos < out_n) out[pos] = val;
    }
  }
}

// ---------------- launch ----------------
extern "C" void kernel_launch(void* const* d_in, const int* in_sizes, int n_in,
                              void* d_out, int out_size, void* d_ws, size_t ws_size,
                              hipStream_t stream) {
  (void)in_sizes; (void)n_in;
  const float* xr_in = (const float*)d_in[0];
  const float* xi_in = (const float*)d_in[1];
  const float* dt = (const float*)d_in[2];
  const float* ln_s_g = (const float*)d_in[3];
  const float* ln_s_b = (const float*)d_in[4];
  const float* conv_w = (const float*)d_in[5];
  const float* conv_b = (const float*)d_in[6];
  const float* spec_fr = (const float*)d_in[7];
  const float* spec_fi = (const float*)d_in[8];
  const float* lam_r = (const float*)d_in[9];
  const float* lam_i = (const float*)d_in[10];
  const float* E_r = (const float*)d_in[11];
  const float* E_i = (const float*)d_in[12];
  const float* Dm_r = (const float*)d_in[13];
  const float* Dm_i = (const float*)d_in[14];
  const float* ln_t_g = (const float*)d_in[15];
  const float* ln_t_b = (const float*)d_in[16];
  const float* pw1 = (const float*)d_in[17];
  const float* pb1 = (const float*)d_in[18];
  const float* pw2 = (const float*)d_in[19];
  const float* pb2 = (const float*)d_in[20];
  const float* gate = (const float*)d_in[21];

  if (ws_size < 6ull * ND_ * 4ull) return;  // need 96 MB f32 scratch

  float* ws = (float*)d_ws;
  float* znr = ws;                 // -> becomes x_re after K5
  float* zni = ws + ND_;           // -> becomes x_im after K5
  float* clr = ws + 2 * ND_;
  float* cli = ws + 3 * ND_;
  float* fqr = ws + 4 * ND_;
  float* fqi = ws + 5 * ND_;
  float* out = (float*)d_out;

  k1_cnorm_spatial<<<512, 256, 0, stream>>>(xr_in, xi_in, ln_s_g, ln_s_b, znr, zni);
  k2_conv<<<dim3(64, 32), 256, 0, stream>>>(znr, zni, conv_w, conv_b, clr, cli);
  k3_dftw<<<dim3(64, 32), 256, 0, stream>>>(znr, zni, fqr, fqi);
  k4_dfth<<<dim3(64, 32), 256, 0, stream>>>(fqr, fqi, spec_fr, spec_fi);
  k5_idftw_combine<<<dim3(64, 32), 256, 0, stream>>>(fqr, fqi, clr, cli, xr_in, xi_in,
                                                     gate, znr, zni);
  k6_temporal<<<1024, 256, 0, stream>>>(znr, zni, lam_r, lam_i, E_r, E_i, Dm_r, Dm_i,
                                        ln_t_g, ln_t_b, dt);
  k7_pool<<<2048, 256, 0, stream>>>(znr, zni, pw1, pb1, pw2, pb2, out, (long long)out_size);
}

// Round 2
// 473.734 us; speedup vs baseline: 1.5323x; 1.2761x over previous
//
#include <hip/hip_runtime.h>
#include <cstddef>

// UniPhyBlock on gfx950 — f32 inputs, f32 internal pipeline, F32 PLANAR OUTPUT.
// Round 13: k2_conv de-bottlenecked. Was 183us with MfmaUtil=2%, VALUBusy=22%,
// 1e7 LDS bank conflicts: per-(block,kk) scalar f32 weight restage + transpose
// + 18 barriers dominated. Now: k0_prepw pre-transposes weights to bf16
// [kk][oc][ic] once; k1 emits a bf16 [tok][64] copy of zn; k2 stages both via
// ushort8 vector copies with a double-buffered weight LDS (1 barrier per kk).
// Numerics bit-identical to round 12 (same RNE bf16 conversions, same MFMAs).
// Output: PLANAR f32 — out[cidx]=real, out[ND+cidx]=imag, cidx over [B,T,D,H,W].
// ws (f32): [0]=zn_re (later x_re), [1]=zn_im (later x_im), [2]=cliff_re,
//           [3]=cliff_im, [4]=freq_re (pre-K3: zn bf16 [tok][64]),
//           [5]=freq_im (pre-K3: conv_w bf16 [kk][oc][ic])  -> 96 MB.

#define EPS_ 1e-5f
#define PI_  3.14159265358979323846f
#define ND_  4194304ull

typedef __attribute__((ext_vector_type(8))) short bf16x8;   // 8 bf16 (4 VGPRs)
typedef __attribute__((ext_vector_type(4))) float f32x4;    // MFMA C/D

__device__ __forceinline__ short f2bf(float f) {
  unsigned u = __float_as_uint(f);
  unsigned r = (u + 0x7fffu + ((u >> 16) & 1u)) >> 16;  // RNE
  return (short)r;
}

// ---------------- K0: one-time conv weight transpose+convert ----------------
// wgt [kk][ic][oc] f32 -> wb [kk][oc][ic] bf16 (36864 elems)
__global__ __launch_bounds__(256) void k0_prepw(
    const float* __restrict__ wgt, unsigned short* __restrict__ wb) {
  int j = blockIdx.x * 256 + threadIdx.x;   // grid 144*256 = 36864
  int kk = j >> 12;
  int rem = j & 4095;
  int oc = rem >> 6;
  int ic = rem & 63;
  wb[j] = (unsigned short)f2bf(wgt[((size_t)kk * 64 + ic) * 64 + oc]);
}

// ---------------- K1: input transpose + spatial cnorm (+ bf16 zn copy) ----------------
__global__ __launch_bounds__(256) void k1_cnorm_spatial(
    const float* __restrict__ xr, const float* __restrict__ xi,
    const float* __restrict__ g, const float* __restrict__ b,
    float* __restrict__ znr, float* __restrict__ zni,
    unsigned short* __restrict__ znb) {
  int tok = blockIdx.x * 256 + threadIdx.x;      // (bt,h,w)
  int bt = tok >> 12;
  int hw = tok & 4095;
  const float* pr = xr + (size_t)bt * 131072 + hw;   // bt*D*HW
  const float* pi = xi + (size_t)bt * 131072 + hw;
  float r[32], q[32];
  float s = 0.f;
#pragma unroll
  for (int d = 0; d < 32; d++) {
    r[d] = pr[(size_t)d * 4096];
    q[d] = pi[(size_t)d * 4096];
    s += r[d] + q[d];
  }
  float mu = s * 0.015625f;
  float v = 0.f;
#pragma unroll
  for (int d = 0; d < 32; d++) {
    float a = r[d] - mu, c = q[d] - mu;
    v += a * a + c * c;
  }
  float rstd = rsqrtf(v * 0.015625f + EPS_);
#pragma unroll
  for (int d = 0; d < 32; d++) {
    r[d] = (r[d] - mu) * rstd * g[d] + b[d];
    q[d] = (q[d] - mu) * rstd * g[32 + d] + b[32 + d];
  }
  float4* outr = (float4*)(znr + (size_t)tok * 32);
  float4* outi = (float4*)(zni + (size_t)tok * 32);
#pragma unroll
  for (int j = 0; j < 8; j++) {
    outr[j] = make_float4(r[4 * j], r[4 * j + 1], r[4 * j + 2], r[4 * j + 3]);
    outi[j] = make_float4(q[4 * j], q[4 * j + 1], q[4 * j + 2], q[4 * j + 3]);
  }
  // bf16 copy [tok][64]: ch 0..31 = re, 32..63 = im (same values k2 used before)
  short* zb = (short*)(znb + (size_t)tok * 64);
#pragma unroll
  for (int j = 0; j < 4; j++) {
    bf16x8 vr, vq;
#pragma unroll
    for (int k = 0; k < 8; k++) {
      vr[k] = f2bf(r[8 * j + k]);
      vq[k] = f2bf(q[8 * j + k]);
    }
    *(bf16x8*)(zb + 8 * j) = vr;
    *(bf16x8*)(zb + 32 + 8 * j) = vq;
  }
}

// ---------------- K2: 3x3 SAME conv via bf16 MFMA implicit GEMM ----------------
// Block = one (bt,h) output row: M=64 tokens(w) x N=64 oc, K=9*64.
// sA: bf16 activations [3 rows][66 wpos][64 ic] stride 88 (staged once, ushort8).
// sW: double-buffered weight chunk [oc][ic] stride 72; chunk kk+1 prefetched
// while kk is MFMAed; ONE barrier per kk. Bias preloaded in C; f32 epilogue.
__global__ __launch_bounds__(256) void k2_conv(
    const unsigned short* __restrict__ znb, const unsigned short* __restrict__ wb,
    const float* __restrict__ bias,
    float* __restrict__ clr, float* __restrict__ cli) {
  __shared__ __align__(16) short sA[3 * 66 * 88];   // 34.8 KB
  __shared__ __align__(16) short sW[2][64 * 72];    // 18.4 KB
  int h = blockIdx.x, bt = blockIdx.y;
  // stage activations (3 rows, w in [-1,64], 64 ch) as ushort8 copies
  for (int v = threadIdx.x; v < 1584; v += 256) {   // 198 rows * 8 vecs
    int c0 = (v & 7) * 8;
    int row = v >> 3;           // 0..197 = rr*66 + wp
    int wp = row % 66;
    int rr = row / 66;
    int hh = h + rr - 1;
    int w = wp - 1;
    bf16x8 val = {0, 0, 0, 0, 0, 0, 0, 0};
    if ((unsigned)hh < 64u && (unsigned)w < 64u) {
      int tok = (bt * 64 + hh) * 64 + w;
      val = *(const bf16x8*)(znb + (size_t)tok * 64 + c0);
    }
    *(bf16x8*)(&sA[(rr * 66 + wp) * 88 + c0]) = val;
  }
  // stage weight chunk 0 into buffer 0
  for (int v = threadIdx.x; v < 512; v += 256) {
    int oc = v >> 3, ic0 = (v & 7) * 8;
    *(bf16x8*)(&sW[0][oc * 72 + ic0]) = *(const bf16x8*)(wb + v * 8);
  }
  int lane = threadIdx.x & 63;
  int wv = threadIdx.x >> 6;
  int m0 = wv * 16;          // this wave's 16-token strip
  int lr = lane & 15;        // A-row / B-col / D-col
  int quad = lane >> 4;      // k-chunk selector; D-row group
  f32x4 acc[4];
#pragma unroll
  for (int nt = 0; nt < 4; nt++) {
    float bz = bias[nt * 16 + lr];
    acc[nt][0] = bz; acc[nt][1] = bz; acc[nt][2] = bz; acc[nt][3] = bz;
  }
  __syncthreads();
  for (int kk = 0; kk < 9; kk++) {
    int cur = kk & 1;
    if (kk < 8) {  // prefetch next chunk into the other buffer
      const unsigned short* src = wb + (size_t)(kk + 1) * 4096;
      for (int v = threadIdx.x; v < 512; v += 256) {
        int oc = v >> 3, ic0 = (v & 7) * 8;
        *(bf16x8*)(&sW[cur ^ 1][oc * 72 + ic0]) = *(const bf16x8*)(src + v * 8);
      }
    }
    int kh = kk / 3, kw = kk - kh * 3;
    // A row for this lane: w_in = (m0+lr) + kw - 1  -> wpos = m0+lr+kw
    const short* arow = &sA[((size_t)kh * 66 + (m0 + lr + kw)) * 88 + quad * 8];
#pragma unroll
    for (int ks = 0; ks < 2; ks++) {
      bf16x8 afrag = *(const bf16x8*)(arow + ks * 32);
#pragma unroll
      for (int nt = 0; nt < 4; nt++) {
        bf16x8 bfrag = *(const bf16x8*)&sW[cur][(size_t)(nt * 16 + lr) * 72 + ks * 32 + quad * 8];
        acc[nt] = __builtin_amdgcn_mfma_f32_16x16x32_bf16(afrag, bfrag, acc[nt], 0, 0, 0);
      }
    }
    __syncthreads();  // next buf written; cur free for overwrite at kk+1
  }
  // epilogue: D[row=quad*4+reg][col=lr] per n-tile -> clr/cli (f32)
  int tokbase = (bt * 64 + h) * 64 + m0;
#pragma unroll
  for (int nt = 0; nt < 4; nt++) {
    int oc = nt * 16 + lr;
    float* dst = (oc < 32) ? (clr + oc) : (cli + (oc - 32));
#pragma unroll
    for (int reg = 0; reg < 4; reg++) {
      int m = quad * 4 + reg;
      dst[(size_t)(tokbase + m) * 32] = acc[nt][reg];
    }
  }
}

// ---------------- K3: forward DFT along W ----------------
__global__ __launch_bounds__(256) void k3_dftw(
    const float* __restrict__ znr, const float* __restrict__ zni,
    float* __restrict__ fqr, float* __restrict__ fqi) {
  __shared__ float sr[2048], si[2048];
  __shared__ float twr[64], twi[64];
  int h = blockIdx.x, bt = blockIdx.y;
  size_t base = (size_t)((bt * 64 + h) * 64) * 32;
  if (threadIdx.x < 64) {
    float ang = -2.f * PI_ * (float)threadIdx.x * (1.f / 64.f);
    twr[threadIdx.x] = cosf(ang);
    twi[threadIdx.x] = sinf(ang);
  }
  for (int i = threadIdx.x; i < 2048; i += 256) {
    sr[i] = znr[base + i];
    si[i] = zni[base + i];
  }
  __syncthreads();
  int k = threadIdx.x & 63;
  int dbase = (threadIdx.x >> 6) * 8;
  float ar[8] = {0, 0, 0, 0, 0, 0, 0, 0}, ai[8] = {0, 0, 0, 0, 0, 0, 0, 0};
  for (int w = 0; w < 64; w++) {
    int idx = (w * k) & 63;
    float tr = twr[idx], ti = twi[idx];
    const float4* pr4 = (const float4*)&sr[w * 32 + dbase];
    const float4* pi4 = (const float4*)&si[w * 32 + dbase];
    float4 a0 = pr4[0], a1 = pr4[1], b0 = pi4[0], b1 = pi4[1];
    float rr[8] = {a0.x, a0.y, a0.z, a0.w, a1.x, a1.y, a1.z, a1.w};
    float ii[8] = {b0.x, b0.y, b0.z, b0.w, b1.x, b1.y, b1.z, b1.w};
#pragma unroll
    for (int j = 0; j < 8; j++) {
      ar[j] += rr[j] * tr - ii[j] * ti;
      ai[j] += rr[j] * ti + ii[j] * tr;
    }
  }
  __syncthreads();
#pragma unroll
  for (int j = 0; j < 8; j++) {
    sr[k * 32 + dbase + j] = ar[j];
    si[k * 32 + dbase + j] = ai[j];
  }
  __syncthreads();
  for (int i = threadIdx.x; i < 2048; i += 256) {
    fqr[base + i] = sr[i];
    fqi[base + i] = si[i];
  }
}

// ---------------- K4: fwd DFT along H, * filt, inv DFT along H (in place) ----------------
__global__ __launch_bounds__(256) void k4_dfth(
    float* __restrict__ fqr, float* __restrict__ fqi,
    const float* __restrict__ flr, const float* __restrict__ fli) {
  __shared__ float sr[2048], si[2048], Fr[2048], Fi[2048];
  __shared__ float twr[64], twi[64];
  int kw = blockIdx.x, bt = blockIdx.y;
  if (threadIdx.x < 64) {
    float ang = -2.f * PI_ * (float)threadIdx.x * (1.f / 64.f);
    twr[threadIdx.x] = cosf(ang);
    twi[threadIdx.x] = sinf(ang);
  }
  for (int i = threadIdx.x; i < 2048; i += 256) {
    int hh = i >> 5, d = i & 31;
    size_t ga = (size_t)((bt * 64 + hh) * 64 + kw) * 32 + d;
    sr[i] = fqr[ga];
    si[i] = fqi[ga];
  }
  __syncthreads();
  int kh = threadIdx.x & 63;
  int dbase = (threadIdx.x >> 6) * 8;
  {
    float ar[8] = {0, 0, 0, 0, 0, 0, 0, 0}, ai[8] = {0, 0, 0, 0, 0, 0, 0, 0};
    for (int hh = 0; hh < 64; hh++) {
      int idx = (hh * kh) & 63;
      float tr = twr[idx], ti = twi[idx];
      const float4* pr4 = (const float4*)&sr[hh * 32 + dbase];
      const float4* pi4 = (const float4*)&si[hh * 32 + dbase];
      float4 a0 = pr4[0], a1 = pr4[1], b0 = pi4[0], b1 = pi4[1];
      float rr[8] = {a0.x, a0.y, a0.z, a0.w, a1.x, a1.y, a1.z, a1.w};
      float ii[8] = {b0.x, b0.y, b0.z, b0.w, b1.x, b1.y, b1.z, b1.w};
#pragma unroll
      for (int j = 0; j < 8; j++) {
        ar[j] += rr[j] * tr - ii[j] * ti;
        ai[j] += rr[j] * ti + ii[j] * tr;
      }
    }
    // multiply by filt[kh][kw][d]
    const float4* fr4 = (const float4*)&flr[(size_t)(kh * 64 + kw) * 32 + dbase];
    const float4* fi4 = (const float4*)&fli[(size_t)(kh * 64 + kw) * 32 + dbase];
    float4 f0 = fr4[0], f1 = fr4[1], g0 = fi4[0], g1 = fi4[1];
    float fre[8] = {f0.x, f0.y, f0.z, f0.w, f1.x, f1.y, f1.z, f1.w};
    float fim[8] = {g0.x, g0.y, g0.z, g0.w, g1.x, g1.y, g1.z, g1.w};
#pragma unroll
    for (int j = 0; j < 8; j++) {
      float pr = ar[j] * fre[j] - ai[j] * fim[j];
      float pi = ar[j] * fim[j] + ai[j] * fre[j];
      Fr[kh * 32 + dbase + j] = pr;
      Fi[kh * 32 + dbase + j] = pi;
    }
  }
  __syncthreads();
  int hh2 = threadIdx.x & 63;
  {
    float ar[8] = {0, 0, 0, 0, 0, 0, 0, 0}, ai[8] = {0, 0, 0, 0, 0, 0, 0, 0};
    for (int k2 = 0; k2 < 64; k2++) {
      int idx = (hh2 * k2) & 63;
      float tr = twr[idx], ti = -twi[idx];  // conj -> inverse
      const float4* pr4 = (const float4*)&Fr[k2 * 32 + dbase];
      const float4* pi4 = (const float4*)&Fi[k2 * 32 + dbase];
      float4 a0 = pr4[0], a1 = pr4[1], b0 = pi4[0], b1 = pi4[1];
      float rr[8] = {a0.x, a0.y, a0.z, a0.w, a1.x, a1.y, a1.z, a1.w};
      float ii[8] = {b0.x, b0.y, b0.z, b0.w, b1.x, b1.y, b1.z, b1.w};
#pragma unroll
      for (int j = 0; j < 8; j++) {
        ar[j] += rr[j] * tr - ii[j] * ti;
        ai[j] += rr[j] * ti + ii[j] * tr;
      }
    }
#pragma unroll
    for (int j = 0; j < 8; j++) {
      sr[hh2 * 32 + dbase + j] = ar[j] * 0.015625f;  // 1/64 (H-inverse)
      si[hh2 * 32 + dbase + j] = ai[j] * 0.015625f;
    }
  }
  __syncthreads();
  for (int i = threadIdx.x; i < 2048; i += 256) {
    int hh = i >> 5, d = i & 31;
    size_t ga = (size_t)((bt * 64 + hh) * 64 + kw) * 32 + d;
    fqr[ga] = sr[i];
    fqi[ga] = si[i];
  }
}

// ---------------- K5: inv DFT along W + gate combine + residual -> x ----------------
__global__ __launch_bounds__(256) void k5_idftw_combine(
    const float* __restrict__ fqr, const float* __restrict__ fqi,
    const float* __restrict__ clr, const float* __restrict__ cli,
    const float* __restrict__ xr_in, const float* __restrict__ xi_in,
    const float* __restrict__ gate,
    float* __restrict__ xr, float* __restrict__ xi) {
  __shared__ float sr[2048], si[2048];
  __shared__ float twr[64], twi[64];
  int h = blockIdx.x, bt = blockIdx.y;
  size_t base = (size_t)((bt * 64 + h) * 64) * 32;
  if (threadIdx.x < 64) {
    float ang = -2.f * PI_ * (float)threadIdx.x * (1.f / 64.f);
    twr[threadIdx.x] = cosf(ang);
    twi[threadIdx.x] = sinf(ang);
  }
  for (int i = threadIdx.x; i < 2048; i += 256) {
    sr[i] = fqr[base + i];
    si[i] = fqi[base + i];
  }
  __syncthreads();
  int w = threadIdx.x & 63;
  int dbase = (threadIdx.x >> 6) * 8;
  float ar[8] = {0, 0, 0, 0, 0, 0, 0, 0}, ai[8] = {0, 0, 0, 0, 0, 0, 0, 0};
  for (int kw = 0; kw < 64; kw++) {
    int idx = (w * kw) & 63;
    float tr = twr[idx], ti = -twi[idx];
    const float4* pr4 = (const float4*)&sr[kw * 32 + dbase];
    const float4* pi4 = (const float4*)&si[kw * 32 + dbase];
    float4 a0 = pr4[0], a1 = pr4[1], b0 = pi4[0], b1 = pi4[1];
    float rr[8] = {a0.x, a0.y, a0.z, a0.w, a1.x, a1.y, a1.z, a1.w};
    float ii[8] = {b0.x, b0.y, b0.z, b0.w, b1.x, b1.y, b1.z, b1.w};
#pragma unroll
    for (int j = 0; j < 8; j++) {
      ar[j] += rr[j] * tr - ii[j] * ti;
      ai[j] += rr[j] * ti + ii[j] * tr;
    }
  }
  float g = gate[0];
  float gi = 1.f - g;
  const float4* c4r = (const float4*)&clr[base + w * 32 + dbase];
  const float4* c4i = (const float4*)&cli[base + w * 32 + dbase];
  float4 cr0 = c4r[0], cr1 = c4r[1], ci0 = c4i[0], ci1 = c4i[1];
  float cre[8] = {cr0.x, cr0.y, cr0.z, cr0.w, cr1.x, cr1.y, cr1.z, cr1.w};
  float cim[8] = {ci0.x, ci0.y, ci0.z, ci0.w, ci1.x, ci1.y, ci1.z, ci1.w};
  float orr[8], oii[8];
#pragma unroll
  for (int j = 0; j < 8; j++) {
    int d = dbase + j;
    size_t ga = (size_t)(bt * 32 + d) * 4096 + h * 64 + w;  // input [B,T,D,H,W]
    orr[j] = g * cre[j] + gi * (ar[j] * 0.015625f) + xr_in[ga];
    oii[j] = g * cim[j] + gi * (ai[j] * 0.015625f) + xi_in[ga];
  }
  __syncthreads();
#pragma unroll
  for (int j = 0; j < 8; j++) {
    sr[w * 32 + dbase + j] = orr[j];
    si[w * 32 + dbase + j] = oii[j];
  }
  __syncthreads();
  for (int i = threadIdx.x; i < 2048; i += 256) {
    xr[base + i] = sr[i];
    xi[base + i] = si[i];
  }
}

// ---------------- K6: temporal cnorm + eigen encode + decay scan + decode ----------------
__global__ __launch_bounds__(256) void k6_temporal(
    float* __restrict__ xr, float* __restrict__ xi,
    const float* __restrict__ lamr, const float* __restrict__ lami,
    const float* __restrict__ Er, const float* __restrict__ Ei,
    const float* __restrict__ Dmr, const float* __restrict__ Dmi,
    const float* __restrict__ lg, const float* __restrict__ lb,
    const float* __restrict__ dtp) {
  __shared__ float sEr[1024], sEi[1024], sDr[1024], sDi[1024];
  __shared__ float htr[128 * 33], hti[128 * 33];  // xt, then h (overwritten per t)
  int n0 = blockIdx.x * 8;
  for (int i = threadIdx.x; i < 1024; i += 256) {
    sEr[i] = Er[i];
    sEi[i] = Ei[i];
    sDr[i] = Dmr[i];
    sDi[i] = Dmi[i];
  }
  if (threadIdx.x < 128) {
    int sI = threadIdx.x >> 4;
    int t = threadIdx.x & 15;
    int n = n0 + sI;
    int bb = n >> 12;
    int hw = n & 4095;
    size_t tokb = ((size_t)(bb * 16 + t)) * 4096 + hw;
    const float4* pr = (const float4*)(xr + tokb * 32);
    const float4* pi = (const float4*)(xi + tokb * 32);
    float rv[32], iv[32];
    float s = 0.f;
#pragma unroll
    for (int j = 0; j < 8; j++) {
      float4 a = pr[j];
      float4 c = pi[j];
      rv[4 * j] = a.x; rv[4 * j + 1] = a.y; rv[4 * j + 2] = a.z; rv[4 * j + 3] = a.w;
      iv[4 * j] = c.x; iv[4 * j + 1] = c.y; iv[4 * j + 2] = c.z; iv[4 * j + 3] = c.w;
      s += a.x + a.y + a.z + a.w + c.x + c.y + c.z + c.w;
    }
    float mu = s * 0.015625f;
    float v = 0.f;
#pragma unroll
    for (int d = 0; d < 32; d++) {
      float a = rv[d] - mu, c = iv[d] - mu;
      v += a * a + c * c;
    }
    float rstd = rsqrtf(v * 0.015625f + EPS_);
    int row = threadIdx.x * 33;
#pragma unroll
    for (int d = 0; d < 32; d++) {
      htr[row + d] = (rv[d] - mu) * rstd * lg[d] + lb[d];
      hti[row + d] = (iv[d] - mu) * rstd * lg[32 + d] + lb[32 + d];
    }
  }
  __syncthreads();
  int sI = threadIdx.x >> 5;
  int e = threadIdx.x & 31;
  float dts = dtp[0];
  float lr = lamr[e], li = lami[e];
  float ex = expf(lr * dts);
  float dcr = ex * cosf(li * dts);
  float dci = ex * sinf(li * dts);
  float nr = dcr - 1.f, ni = dci;
  float invden = 1.f / (lr * lr + li * li);
  float fr = (nr * lr + ni * li) * invden;
  float fi = (ni * lr - nr * li) * invden;
  float hr = 0.f, hi = 0.f;
  for (int t = 0; t < 16; t++) {
    int row = (sI * 16 + t) * 33;
    float xer = 0.f, xei = 0.f;
#pragma unroll
    for (int d = 0; d < 32; d++) {
      float a = htr[row + d], c = hti[row + d];
      float er_ = sEr[d * 32 + e], ei_ = sEi[d * 32 + e];
      xer += a * er_ - c * ei_;
      xei += a * ei_ + c * er_;
    }
    float ur = xer * fr - xei * fi;
    float ui = xer * fi + xei * fr;
    float t1 = dcr * hr - dci * hi + ur;
    hi = dcr * hi + dci * hr + ui;
    hr = t1;
    __syncthreads();
    htr[row + e] = hr;
    hti[row + e] = hi;
    __syncthreads();
  }
  for (int t = 0; t < 16; t++) {
    int row = (sI * 16 + t) * 33;
    float acc = 0.f;
#pragma unroll
    for (int d = 0; d < 32; d++) {
      acc += htr[row + d] * sDr[d * 32 + e] - hti[row + d] * sDi[d * 32 + e];
    }
    int n = n0 + sI;
    int bb = n >> 12;
    int hw = n & 4095;
    size_t tokb = ((size_t)(bb * 16 + t)) * 4096 + hw;
    xr[tokb * 32 + e] += acc;  // drift is real-only
  }
}

// ---------------- K7: para pool MLP via bf16 MFMA + residual + output (F32 PLANAR) ----------------
__global__ __launch_bounds__(256) void k7_pool(
    const float* __restrict__ xr, const float* __restrict__ xi,
    const float* __restrict__ pw1, const float* __restrict__ pb1,
    const float* __restrict__ pw2, const float* __restrict__ pb2,
    float* __restrict__ out, long long out_n) {
  __shared__ __align__(16) short sXh[64 * 72];  // xp hi bf16 [tok][c]   9.2 KB
  __shared__ __align__(16) short sXl[64 * 72];  // xp lo bf16            9.2 KB
  __shared__ __align__(16) short sW[64 * 72];   // weight chunk [n][k]   9.2 KB
  __shared__ __align__(16) float sH[64 * 68];   // hidden f32 [tok][el] 17.4 KB
  int tok0 = blockIdx.x * 64;
  // stage xp as hi/lo bf16 pair: x = hi + lo to ~16 mantissa bits
  for (int i = threadIdx.x; i < 4096; i += 256) {
    int t = i >> 6, c = i & 63;
    float v = (c < 32) ? xr[(size_t)(tok0 + t) * 32 + c]
                       : xi[(size_t)(tok0 + t) * 32 + c - 32];
    short hb = f2bf(v);
    float hf = __uint_as_float(((unsigned)(unsigned short)hb) << 16);
    sXh[t * 72 + c] = hb;
    sXl[t * 72 + c] = f2bf(v - hf);
  }
  int lane = threadIdx.x & 63;
  int wv = threadIdx.x >> 6;
  int lr = lane & 15;
  int quad = lane >> 4;
  int m0 = wv * 16;          // this wave's 16-token strip
  f32x4 acc2[4];             // persistent GEMM2 accumulator, bias preloaded
#pragma unroll
  for (int nt = 0; nt < 4; nt++) {
    float bz = pb2[nt * 16 + lr];
    acc2[nt][0] = bz; acc2[nt][1] = bz; acc2[nt][2] = bz; acc2[nt][3] = bz;
  }
  for (int ec = 0; ec < 4; ec++) {
    __syncthreads();  // prev GEMM2 done with sW/sH; xp staged (ec=0)
    // stage w1 chunk: sW[el][c] = w1[ec*64+el][c]  (already B^T layout)
    for (int i = threadIdx.x; i < 4096; i += 256) {
      int el = i >> 6, c = i & 63;
      sW[el * 72 + c] = f2bf(pw1[(size_t)(ec * 64 + el) * 64 + c]);
    }
    __syncthreads();
    f32x4 acc1[4];
#pragma unroll
    for (int nt = 0; nt < 4; nt++) {
      float bz = pb1[ec * 64 + nt * 16 + lr];
      acc1[nt][0] = bz; acc1[nt][1] = bz; acc1[nt][2] = bz; acc1[nt][3] = bz;
    }
    const short* arh = &sXh[(size_t)(m0 + lr) * 72 + quad * 8];
    const short* arl = &sXl[(size_t)(m0 + lr) * 72 + quad * 8];
#pragma unroll
    for (int ks = 0; ks < 2; ks++) {
      bf16x8 ah = *(const bf16x8*)(arh + ks * 32);
      bf16x8 al = *(const bf16x8*)(arl + ks * 32);
#pragma unroll
      for (int nt = 0; nt < 4; nt++) {
        bf16x8 bfrag = *(const bf16x8*)&sW[(size_t)(nt * 16 + lr) * 72 + ks * 32 + quad * 8];
        acc1[nt] = __builtin_amdgcn_mfma_f32_16x16x32_bf16(ah, bfrag, acc1[nt], 0, 0, 0);
        acc1[nt] = __builtin_amdgcn_mfma_f32_16x16x32_bf16(al, bfrag, acc1[nt], 0, 0, 0);
      }
    }
    // gelu (tanh approx, jax default) -> sH[tok][e_local] (f32, 2-way banks = free)
#pragma unroll
    for (int nt = 0; nt < 4; nt++) {
#pragma unroll
      for (int reg = 0; reg < 4; reg++) {
        float x = acc1[nt][reg];
        float u = 0.7978845608f * (x + 0.044715f * x * x * x);
        float e2 = __expf(2.f * u);
        float th = 1.f - 2.f / (e2 + 1.f);
        sH[(m0 + quad * 4 + reg) * 68 + nt * 16 + lr] = 0.5f * x * (1.f + th);
      }
    }
    __syncthreads();  // GEMM1 reads of sW done, sH writes done
    // stage w2 chunk: sW[oc][el] = w2[oc][ec*64+el]
    for (int i = threadIdx.x; i < 4096; i += 256) {
      int oc = i >> 6, el = i & 63;
      sW[oc * 72 + el] = f2bf(pw2[(size_t)oc * 256 + ec * 64 + el]);
    }
    __syncthreads();
    // GEMM2: A = gelu(hidden) converted bf16 on the fly, accumulate into acc2
    const float* hrow = &sH[(size_t)(m0 + lr) * 68 + quad * 8];
#pragma unroll
    for (int ks = 0; ks < 2; ks++) {
      float4 h0 = *(const float4*)(hrow + ks * 32);
      float4 h1 = *(const float4*)(hrow + ks * 32 + 4);
      bf16x8 af;
      af[0] = f2bf(h0.x); af[1] = f2bf(h0.y); af[2] = f2bf(h0.z); af[3] = f2bf(h0.w);
      af[4] = f2bf(h1.x); af[5] = f2bf(h1.y); af[6] = f2bf(h1.z); af[7] = f2bf(h1.w);
#pragma unroll
      for (int nt = 0; nt < 4; nt++) {
        bf16x8 bfrag = *(const bf16x8*)&sW[(size_t)(nt * 16 + lr) * 72 + ks * 32 + quad * 8];
        acc2[nt] = __builtin_amdgcn_mfma_f32_16x16x32_bf16(af, bfrag, acc2[nt], 0, 0, 0);
      }
    }
  }
  // epilogue: D[row=quad*4+reg][col=lr] -> + residual -> planar f32 out
#pragma unroll
  for (int nt = 0; nt < 4; nt++) {
    int oc = nt * 16 + lr;
#pragma unroll
    for (int reg = 0; reg < 4; reg++) {
      int t = tok0 + m0 + quad * 4 + reg;
      float resid = (oc < 32) ? xr[(size_t)t * 32 + oc] : xi[(size_t)t * 32 + oc - 32];
      float val = acc2[nt][reg] + resid;
      int bt = t >> 12;
      int hw = t & 4095;
      int d = (oc < 32) ? oc : oc - 32;
      size_t cidx = (size_t)(bt * 32 + d) * 4096 + hw;  // [B,T,D,H,W] index
      long long pos = (long long)cidx + ((oc < 32) ? 0ll : (long long)ND_);
      if (pos < out_n) out[pos] = val;
    }
  }
}

// ---------------- launch ----------------
extern "C" void kernel_launch(void* const* d_in, const int* in_sizes, int n_in,
                              void* d_out, int out_size, void* d_ws, size_t ws_size,
                              hipStream_t stream) {
  (void)in_sizes; (void)n_in;
  const float* xr_in = (const float*)d_in[0];
  const float* xi_in = (const float*)d_in[1];
  const float* dt = (const float*)d_in[2];
  const float* ln_s_g = (const float*)d_in[3];
  const float* ln_s_b = (const float*)d_in[4];
  const float* conv_w = (const float*)d_in[5];
  const float* conv_b = (const float*)d_in[6];
  const float* spec_fr = (const float*)d_in[7];
  const float* spec_fi = (const float*)d_in[8];
  const float* lam_r = (const float*)d_in[9];
  const float* lam_i = (const float*)d_in[10];
  const float* E_r = (const float*)d_in[11];
  const float* E_i = (const float*)d_in[12];
  const float* Dm_r = (const float*)d_in[13];
  const float* Dm_i = (const float*)d_in[14];
  const float* ln_t_g = (const float*)d_in[15];
  const float* ln_t_b = (const float*)d_in[16];
  const float* pw1 = (const float*)d_in[17];
  const float* pb1 = (const float*)d_in[18];
  const float* pw2 = (const float*)d_in[19];
  const float* pb2 = (const float*)d_in[20];
  const float* gate = (const float*)d_in[21];

  if (ws_size < 6ull * ND_ * 4ull) return;  // need 96 MB f32 scratch

  float* ws = (float*)d_ws;
  float* znr = ws;                 // -> becomes x_re after K5
  float* zni = ws + ND_;           // -> becomes x_im after K5
  float* clr = ws + 2 * ND_;
  float* cli = ws + 3 * ND_;
  float* fqr = ws + 4 * ND_;
  float* fqi = ws + 5 * ND_;
  float* out = (float*)d_out;
  // pre-K3 scratch aliases (consumed by K2 before K3/K4 overwrite them)
  unsigned short* znb = (unsigned short*)fqr;  // zn bf16 [tok][64], exactly ND_*4 B
  unsigned short* wb = (unsigned short*)fqi;   // conv_w bf16 [kk][oc][ic], 73 KB

  k0_prepw<<<144, 256, 0, stream>>>(conv_w, wb);
  k1_cnorm_spatial<<<512, 256, 0, stream>>>(xr_in, xi_in, ln_s_g, ln_s_b, znr, zni, znb);
  k2_conv<<<dim3(64, 32), 256, 0, stream>>>(znb, wb, conv_b, clr, cli);
  k3_dftw<<<dim3(64, 32), 256, 0, stream>>>(znr, zni, fqr, fqi);
  k4_dfth<<<dim3(64, 32), 256, 0, stream>>>(fqr, fqi, spec_fr, spec_fi);
  k5_idftw_combine<<<dim3(64, 32), 256, 0, stream>>>(fqr, fqi, clr, cli, xr_in, xi_in,
                                                     gate, znr, zni);
  k6_temporal<<<1024, 256, 0, stream>>>(znr, zni, lam_r, lam_i, E_r, E_i, Dm_r, Dm_i,
                                        ln_t_g, ln_t_b, dt);
  k7_pool<<<2048, 256, 0, stream>>>(znr, zni, pw1, pb1, pw2, pb2, out, (long long)out_size);
}

// Round 3
// 425.693 us; speedup vs baseline: 1.7052x; 1.1129x over previous
//
#include <hip/hip_runtime.h>
#include <cstddef>

// UniPhyBlock on gfx950 — f32 inputs, f32 internal pipeline, F32 PLANAR OUTPUT.
// Round 14: k6_temporal restructured. Was 94us, LDS-issue bound: 4 scalar
// ds_read_b32 per (d,t) in encode/decode (~16K wave-LDS-instr/block) plus 32
// block-wide barriers in the scan whose dependency is wave-internal. Now: xt
// stored transposed [d][tok] (stride 132) -> encode/decode read 16 t-values as
// 4 broadcast ds_read_b128 with E/D coefficients hoisted (1 read per d);
// scan fully in registers (no barriers); h written back transposed.
// Per-output f32 accumulation order over d unchanged -> same numerics.
// Output: PLANAR f32 — out[cidx]=real, out[ND+cidx]=imag, cidx over [B,T,D,H,W].
// ws (f32): [0]=zn_re (later x_re), [1]=zn_im (later x_im), [2]=cliff_re,
//           [3]=cliff_im, [4]=freq_re (pre-K3: zn bf16 [tok][64]),
//           [5]=freq_im (pre-K3: conv_w bf16 [kk][oc][ic])  -> 96 MB.

#define EPS_ 1e-5f
#define PI_  3.14159265358979323846f
#define ND_  4194304ull

typedef __attribute__((ext_vector_type(8))) short bf16x8;   // 8 bf16 (4 VGPRs)
typedef __attribute__((ext_vector_type(4))) float f32x4;    // MFMA C/D

__device__ __forceinline__ short f2bf(float f) {
  unsigned u = __float_as_uint(f);
  unsigned r = (u + 0x7fffu + ((u >> 16) & 1u)) >> 16;  // RNE
  return (short)r;
}

// ---------------- K0: one-time conv weight transpose+convert ----------------
// wgt [kk][ic][oc] f32 -> wb [kk][oc][ic] bf16 (36864 elems)
__global__ __launch_bounds__(256) void k0_prepw(
    const float* __restrict__ wgt, unsigned short* __restrict__ wb) {
  int j = blockIdx.x * 256 + threadIdx.x;   // grid 144*256 = 36864
  int kk = j >> 12;
  int rem = j & 4095;
  int oc = rem >> 6;
  int ic = rem & 63;
  wb[j] = (unsigned short)f2bf(wgt[((size_t)kk * 64 + ic) * 64 + oc]);
}

// ---------------- K1: input transpose + spatial cnorm (+ bf16 zn copy) ----------------
__global__ __launch_bounds__(256) void k1_cnorm_spatial(
    const float* __restrict__ xr, const float* __restrict__ xi,
    const float* __restrict__ g, const float* __restrict__ b,
    float* __restrict__ znr, float* __restrict__ zni,
    unsigned short* __restrict__ znb) {
  int tok = blockIdx.x * 256 + threadIdx.x;      // (bt,h,w)
  int bt = tok >> 12;
  int hw = tok & 4095;
  const float* pr = xr + (size_t)bt * 131072 + hw;   // bt*D*HW
  const float* pi = xi + (size_t)bt * 131072 + hw;
  float r[32], q[32];
  float s = 0.f;
#pragma unroll
  for (int d = 0; d < 32; d++) {
    r[d] = pr[(size_t)d * 4096];
    q[d] = pi[(size_t)d * 4096];
    s += r[d] + q[d];
  }
  float mu = s * 0.015625f;
  float v = 0.f;
#pragma unroll
  for (int d = 0; d < 32; d++) {
    float a = r[d] - mu, c = q[d] - mu;
    v += a * a + c * c;
  }
  float rstd = rsqrtf(v * 0.015625f + EPS_);
#pragma unroll
  for (int d = 0; d < 32; d++) {
    r[d] = (r[d] - mu) * rstd * g[d] + b[d];
    q[d] = (q[d] - mu) * rstd * g[32 + d] + b[32 + d];
  }
  float4* outr = (float4*)(znr + (size_t)tok * 32);
  float4* outi = (float4*)(zni + (size_t)tok * 32);
#pragma unroll
  for (int j = 0; j < 8; j++) {
    outr[j] = make_float4(r[4 * j], r[4 * j + 1], r[4 * j + 2], r[4 * j + 3]);
    outi[j] = make_float4(q[4 * j], q[4 * j + 1], q[4 * j + 2], q[4 * j + 3]);
  }
  // bf16 copy [tok][64]: ch 0..31 = re, 32..63 = im (same values k2 used before)
  short* zb = (short*)(znb + (size_t)tok * 64);
#pragma unroll
  for (int j = 0; j < 4; j++) {
    bf16x8 vr, vq;
#pragma unroll
    for (int k = 0; k < 8; k++) {
      vr[k] = f2bf(r[8 * j + k]);
      vq[k] = f2bf(q[8 * j + k]);
    }
    *(bf16x8*)(zb + 8 * j) = vr;
    *(bf16x8*)(zb + 32 + 8 * j) = vq;
  }
}

// ---------------- K2: 3x3 SAME conv via bf16 MFMA implicit GEMM ----------------
// Block = one (bt,h) output row: M=64 tokens(w) x N=64 oc, K=9*64.
// sA: bf16 activations [3 rows][66 wpos][64 ic] stride 88 (staged once, ushort8).
// sW: double-buffered weight chunk [oc][ic] stride 72; chunk kk+1 prefetched
// while kk is MFMAed; ONE barrier per kk. Bias preloaded in C; f32 epilogue.
__global__ __launch_bounds__(256) void k2_conv(
    const unsigned short* __restrict__ znb, const unsigned short* __restrict__ wb,
    const float* __restrict__ bias,
    float* __restrict__ clr, float* __restrict__ cli) {
  __shared__ __align__(16) short sA[3 * 66 * 88];   // 34.8 KB
  __shared__ __align__(16) short sW[2][64 * 72];    // 18.4 KB
  int h = blockIdx.x, bt = blockIdx.y;
  // stage activations (3 rows, w in [-1,64], 64 ch) as ushort8 copies
  for (int v = threadIdx.x; v < 1584; v += 256) {   // 198 rows * 8 vecs
    int c0 = (v & 7) * 8;
    int row = v >> 3;           // 0..197 = rr*66 + wp
    int wp = row % 66;
    int rr = row / 66;
    int hh = h + rr - 1;
    int w = wp - 1;
    bf16x8 val = {0, 0, 0, 0, 0, 0, 0, 0};
    if ((unsigned)hh < 64u && (unsigned)w < 64u) {
      int tok = (bt * 64 + hh) * 64 + w;
      val = *(const bf16x8*)(znb + (size_t)tok * 64 + c0);
    }
    *(bf16x8*)(&sA[(rr * 66 + wp) * 88 + c0]) = val;
  }
  // stage weight chunk 0 into buffer 0
  for (int v = threadIdx.x; v < 512; v += 256) {
    int oc = v >> 3, ic0 = (v & 7) * 8;
    *(bf16x8*)(&sW[0][oc * 72 + ic0]) = *(const bf16x8*)(wb + v * 8);
  }
  int lane = threadIdx.x & 63;
  int wv = threadIdx.x >> 6;
  int m0 = wv * 16;          // this wave's 16-token strip
  int lr = lane & 15;        // A-row / B-col / D-col
  int quad = lane >> 4;      // k-chunk selector; D-row group
  f32x4 acc[4];
#pragma unroll
  for (int nt = 0; nt < 4; nt++) {
    float bz = bias[nt * 16 + lr];
    acc[nt][0] = bz; acc[nt][1] = bz; acc[nt][2] = bz; acc[nt][3] = bz;
  }
  __syncthreads();
  for (int kk = 0; kk < 9; kk++) {
    int cur = kk & 1;
    if (kk < 8) {  // prefetch next chunk into the other buffer
      const unsigned short* src = wb + (size_t)(kk + 1) * 4096;
      for (int v = threadIdx.x; v < 512; v += 256) {
        int oc = v >> 3, ic0 = (v & 7) * 8;
        *(bf16x8*)(&sW[cur ^ 1][oc * 72 + ic0]) = *(const bf16x8*)(src + v * 8);
      }
    }
    int kh = kk / 3, kw = kk - kh * 3;
    // A row for this lane: w_in = (m0+lr) + kw - 1  -> wpos = m0+lr+kw
    const short* arow = &sA[((size_t)kh * 66 + (m0 + lr + kw)) * 88 + quad * 8];
#pragma unroll
    for (int ks = 0; ks < 2; ks++) {
      bf16x8 afrag = *(const bf16x8*)(arow + ks * 32);
#pragma unroll
      for (int nt = 0; nt < 4; nt++) {
        bf16x8 bfrag = *(const bf16x8*)&sW[cur][(size_t)(nt * 16 + lr) * 72 + ks * 32 + quad * 8];
        acc[nt] = __builtin_amdgcn_mfma_f32_16x16x32_bf16(afrag, bfrag, acc[nt], 0, 0, 0);
      }
    }
    __syncthreads();  // next buf written; cur free for overwrite at kk+1
  }
  // epilogue: D[row=quad*4+reg][col=lr] per n-tile -> clr/cli (f32)
  int tokbase = (bt * 64 + h) * 64 + m0;
#pragma unroll
  for (int nt = 0; nt < 4; nt++) {
    int oc = nt * 16 + lr;
    float* dst = (oc < 32) ? (clr + oc) : (cli + (oc - 32));
#pragma unroll
    for (int reg = 0; reg < 4; reg++) {
      int m = quad * 4 + reg;
      dst[(size_t)(tokbase + m) * 32] = acc[nt][reg];
    }
  }
}

// ---------------- K3: forward DFT along W ----------------
__global__ __launch_bounds__(256) void k3_dftw(
    const float* __restrict__ znr, const float* __restrict__ zni,
    float* __restrict__ fqr, float* __restrict__ fqi) {
  __shared__ float sr[2048], si[2048];
  __shared__ float twr[64], twi[64];
  int h = blockIdx.x, bt = blockIdx.y;
  size_t base = (size_t)((bt * 64 + h) * 64) * 32;
  if (threadIdx.x < 64) {
    float ang = -2.f * PI_ * (float)threadIdx.x * (1.f / 64.f);
    twr[threadIdx.x] = cosf(ang);
    twi[threadIdx.x] = sinf(ang);
  }
  for (int i = threadIdx.x; i < 2048; i += 256) {
    sr[i] = znr[base + i];
    si[i] = zni[base + i];
  }
  __syncthreads();
  int k = threadIdx.x & 63;
  int dbase = (threadIdx.x >> 6) * 8;
  float ar[8] = {0, 0, 0, 0, 0, 0, 0, 0}, ai[8] = {0, 0, 0, 0, 0, 0, 0, 0};
  for (int w = 0; w < 64; w++) {
    int idx = (w * k) & 63;
    float tr = twr[idx], ti = twi[idx];
    const float4* pr4 = (const float4*)&sr[w * 32 + dbase];
    const float4* pi4 = (const float4*)&si[w * 32 + dbase];
    float4 a0 = pr4[0], a1 = pr4[1], b0 = pi4[0], b1 = pi4[1];
    float rr[8] = {a0.x, a0.y, a0.z, a0.w, a1.x, a1.y, a1.z, a1.w};
    float ii[8] = {b0.x, b0.y, b0.z, b0.w, b1.x, b1.y, b1.z, b1.w};
#pragma unroll
    for (int j = 0; j < 8; j++) {
      ar[j] += rr[j] * tr - ii[j] * ti;
      ai[j] += rr[j] * ti + ii[j] * tr;
    }
  }
  __syncthreads();
#pragma unroll
  for (int j = 0; j < 8; j++) {
    sr[k * 32 + dbase + j] = ar[j];
    si[k * 32 + dbase + j] = ai[j];
  }
  __syncthreads();
  for (int i = threadIdx.x; i < 2048; i += 256) {
    fqr[base + i] = sr[i];
    fqi[base + i] = si[i];
  }
}

// ---------------- K4: fwd DFT along H, * filt, inv DFT along H (in place) ----------------
__global__ __launch_bounds__(256) void k4_dfth(
    float* __restrict__ fqr, float* __restrict__ fqi,
    const float* __restrict__ flr, const float* __restrict__ fli) {
  __shared__ float sr[2048], si[2048], Fr[2048], Fi[2048];
  __shared__ float twr[64], twi[64];
  int kw = blockIdx.x, bt = blockIdx.y;
  if (threadIdx.x < 64) {
    float ang = -2.f * PI_ * (float)threadIdx.x * (1.f / 64.f);
    twr[threadIdx.x] = cosf(ang);
    twi[threadIdx.x] = sinf(ang);
  }
  for (int i = threadIdx.x; i < 2048; i += 256) {
    int hh = i >> 5, d = i & 31;
    size_t ga = (size_t)((bt * 64 + hh) * 64 + kw) * 32 + d;
    sr[i] = fqr[ga];
    si[i] = fqi[ga];
  }
  __syncthreads();
  int kh = threadIdx.x & 63;
  int dbase = (threadIdx.x >> 6) * 8;
  {
    float ar[8] = {0, 0, 0, 0, 0, 0, 0, 0}, ai[8] = {0, 0, 0, 0, 0, 0, 0, 0};
    for (int hh = 0; hh < 64; hh++) {
      int idx = (hh * kh) & 63;
      float tr = twr[idx], ti = twi[idx];
      const float4* pr4 = (const float4*)&sr[hh * 32 + dbase];
      const float4* pi4 = (const float4*)&si[hh * 32 + dbase];
      float4 a0 = pr4[0], a1 = pr4[1], b0 = pi4[0], b1 = pi4[1];
      float rr[8] = {a0.x, a0.y, a0.z, a0.w, a1.x, a1.y, a1.z, a1.w};
      float ii[8] = {b0.x, b0.y, b0.z, b0.w, b1.x, b1.y, b1.z, b1.w};
#pragma unroll
      for (int j = 0; j < 8; j++) {
        ar[j] += rr[j] * tr - ii[j] * ti;
        ai[j] += rr[j] * ti + ii[j] * tr;
      }
    }
    // multiply by filt[kh][kw][d]
    const float4* fr4 = (const float4*)&flr[(size_t)(kh * 64 + kw) * 32 + dbase];
    const float4* fi4 = (const float4*)&fli[(size_t)(kh * 64 + kw) * 32 + dbase];
    float4 f0 = fr4[0], f1 = fr4[1], g0 = fi4[0], g1 = fi4[1];
    float fre[8] = {f0.x, f0.y, f0.z, f0.w, f1.x, f1.y, f1.z, f1.w};
    float fim[8] = {g0.x, g0.y, g0.z, g0.w, g1.x, g1.y, g1.z, g1.w};
#pragma unroll
    for (int j = 0; j < 8; j++) {
      float pr = ar[j] * fre[j] - ai[j] * fim[j];
      float pi = ar[j] * fim[j] + ai[j] * fre[j];
      Fr[kh * 32 + dbase + j] = pr;
      Fi[kh * 32 + dbase + j] = pi;
    }
  }
  __syncthreads();
  int hh2 = threadIdx.x & 63;
  {
    float ar[8] = {0, 0, 0, 0, 0, 0, 0, 0}, ai[8] = {0, 0, 0, 0, 0, 0, 0, 0};
    for (int k2 = 0; k2 < 64; k2++) {
      int idx = (hh2 * k2) & 63;
      float tr = twr[idx], ti = -twi[idx];  // conj -> inverse
      const float4* pr4 = (const float4*)&Fr[k2 * 32 + dbase];
      const float4* pi4 = (const float4*)&Fi[k2 * 32 + dbase];
      float4 a0 = pr4[0], a1 = pr4[1], b0 = pi4[0], b1 = pi4[1];
      float rr[8] = {a0.x, a0.y, a0.z, a0.w, a1.x, a1.y, a1.z, a1.w};
      float ii[8] = {b0.x, b0.y, b0.z, b0.w, b1.x, b1.y, b1.z, b1.w};
#pragma unroll
      for (int j = 0; j < 8; j++) {
        ar[j] += rr[j] * tr - ii[j] * ti;
        ai[j] += rr[j] * ti + ii[j] * tr;
      }
    }
#pragma unroll
    for (int j = 0; j < 8; j++) {
      sr[hh2 * 32 + dbase + j] = ar[j] * 0.015625f;  // 1/64 (H-inverse)
      si[hh2 * 32 + dbase + j] = ai[j] * 0.015625f;
    }
  }
  __syncthreads();
  for (int i = threadIdx.x; i < 2048; i += 256) {
    int hh = i >> 5, d = i & 31;
    size_t ga = (size_t)((bt * 64 + hh) * 64 + kw) * 32 + d;
    fqr[ga] = sr[i];
    fqi[ga] = si[i];
  }
}

// ---------------- K5: inv DFT along W + gate combine + residual -> x ----------------
__global__ __launch_bounds__(256) void k5_idftw_combine(
    const float* __restrict__ fqr, const float* __restrict__ fqi,
    const float* __restrict__ clr, const float* __restrict__ cli,
    const float* __restrict__ xr_in, const float* __restrict__ xi_in,
    const float* __restrict__ gate,
    float* __restrict__ xr, float* __restrict__ xi) {
  __shared__ float sr[2048], si[2048];
  __shared__ float twr[64], twi[64];
  int h = blockIdx.x, bt = blockIdx.y;
  size_t base = (size_t)((bt * 64 + h) * 64) * 32;
  if (threadIdx.x < 64) {
    float ang = -2.f * PI_ * (float)threadIdx.x * (1.f / 64.f);
    twr[threadIdx.x] = cosf(ang);
    twi[threadIdx.x] = sinf(ang);
  }
  for (int i = threadIdx.x; i < 2048; i += 256) {
    sr[i] = fqr[base + i];
    si[i] = fqi[base + i];
  }
  __syncthreads();
  int w = threadIdx.x & 63;
  int dbase = (threadIdx.x >> 6) * 8;
  float ar[8] = {0, 0, 0, 0, 0, 0, 0, 0}, ai[8] = {0, 0, 0, 0, 0, 0, 0, 0};
  for (int kw = 0; kw < 64; kw++) {
    int idx = (w * kw) & 63;
    float tr = twr[idx], ti = -twi[idx];
    const float4* pr4 = (const float4*)&sr[kw * 32 + dbase];
    const float4* pi4 = (const float4*)&si[kw * 32 + dbase];
    float4 a0 = pr4[0], a1 = pr4[1], b0 = pi4[0], b1 = pi4[1];
    float rr[8] = {a0.x, a0.y, a0.z, a0.w, a1.x, a1.y, a1.z, a1.w};
    float ii[8] = {b0.x, b0.y, b0.z, b0.w, b1.x, b1.y, b1.z, b1.w};
#pragma unroll
    for (int j = 0; j < 8; j++) {
      ar[j] += rr[j] * tr - ii[j] * ti;
      ai[j] += rr[j] * ti + ii[j] * tr;
    }
  }
  float g = gate[0];
  float gi = 1.f - g;
  const float4* c4r = (const float4*)&clr[base + w * 32 + dbase];
  const float4* c4i = (const float4*)&cli[base + w * 32 + dbase];
  float4 cr0 = c4r[0], cr1 = c4r[1], ci0 = c4i[0], ci1 = c4i[1];
  float cre[8] = {cr0.x, cr0.y, cr0.z, cr0.w, cr1.x, cr1.y, cr1.z, cr1.w};
  float cim[8] = {ci0.x, ci0.y, ci0.z, ci0.w, ci1.x, ci1.y, ci1.z, ci1.w};
  float orr[8], oii[8];
#pragma unroll
  for (int j = 0; j < 8; j++) {
    int d = dbase + j;
    size_t ga = (size_t)(bt * 32 + d) * 4096 + h * 64 + w;  // input [B,T,D,H,W]
    orr[j] = g * cre[j] + gi * (ar[j] * 0.015625f) + xr_in[ga];
    oii[j] = g * cim[j] + gi * (ai[j] * 0.015625f) + xi_in[ga];
  }
  __syncthreads();
#pragma unroll
  for (int j = 0; j < 8; j++) {
    sr[w * 32 + dbase + j] = orr[j];
    si[w * 32 + dbase + j] = oii[j];
  }
  __syncthreads();
  for (int i = threadIdx.x; i < 2048; i += 256) {
    xr[base + i] = sr[i];
    xi[base + i] = si[i];
  }
}

// ---------------- K6: temporal cnorm + eigen encode + decay scan + decode ----------------
// 8 tokens/block. xt stored transposed sX*[d][tok] (stride 132) so the 16
// t-values per (sI,d) are 4 broadcast float4 reads; E/D coeffs read once per d;
// scan in registers; h written back transposed (columns sI-disjoint).
__global__ __launch_bounds__(256) void k6_temporal(
    float* __restrict__ xr, float* __restrict__ xi,
    const float* __restrict__ lamr, const float* __restrict__ lami,
    const float* __restrict__ Er, const float* __restrict__ Ei,
    const float* __restrict__ Dmr, const float* __restrict__ Dmi,
    const float* __restrict__ lg, const float* __restrict__ lb,
    const float* __restrict__ dtp) {
  __shared__ float sEr[1024], sEi[1024], sDr[1024], sDi[1024];
  __shared__ __align__(16) float sXr[32 * 132];  // xt^T [d][tok], later h^T
  __shared__ __align__(16) float sXi[32 * 132];
  int n0 = blockIdx.x * 8;
  for (int i = threadIdx.x; i < 1024; i += 256) {
    sEr[i] = Er[i];
    sEi[i] = Ei[i];
    sDr[i] = Dmr[i];
    sDi[i] = Dmi[i];
  }
  if (threadIdx.x < 128) {
    int sIc = threadIdx.x >> 4;
    int t = threadIdx.x & 15;
    int n = n0 + sIc;
    int bb = n >> 12;
    int hw = n & 4095;
    size_t tokb = ((size_t)(bb * 16 + t)) * 4096 + hw;
    const float4* pr = (const float4*)(xr + tokb * 32);
    const float4* pi = (const float4*)(xi + tokb * 32);
    float rv[32], iv[32];
    float s = 0.f;
#pragma unroll
    for (int j = 0; j < 8; j++) {
      float4 a = pr[j];
      float4 c = pi[j];
      rv[4 * j] = a.x; rv[4 * j + 1] = a.y; rv[4 * j + 2] = a.z; rv[4 * j + 3] = a.w;
      iv[4 * j] = c.x; iv[4 * j + 1] = c.y; iv[4 * j + 2] = c.z; iv[4 * j + 3] = c.w;
      s += a.x + a.y + a.z + a.w + c.x + c.y + c.z + c.w;
    }
    float mu = s * 0.015625f;
    float v = 0.f;
#pragma unroll
    for (int d = 0; d < 32; d++) {
      float a = rv[d] - mu, c = iv[d] - mu;
      v += a * a + c * c;
    }
    float rstd = rsqrtf(v * 0.015625f + EPS_);
    int col = threadIdx.x;   // sIc*16 + t
#pragma unroll
    for (int d = 0; d < 32; d++) {
      sXr[d * 132 + col] = (rv[d] - mu) * rstd * lg[d] + lb[d];
      sXi[d * 132 + col] = (iv[d] - mu) * rstd * lg[32 + d] + lb[32 + d];
    }
  }
  __syncthreads();
  int sI = threadIdx.x >> 5;
  int e = threadIdx.x & 31;
  int tok0 = sI * 16;
  float dts = dtp[0];
  float lr = lamr[e], li = lami[e];
  float ex = expf(lr * dts);
  float dcr = ex * cosf(li * dts);
  float dci = ex * sinf(li * dts);
  float nr = dcr - 1.f, ni = dci;
  float invden = 1.f / (lr * lr + li * li);
  float fr = (nr * lr + ni * li) * invden;
  float fi = (ni * lr - nr * li) * invden;
  // ---- encode: xer/xei[t] = sum_d xt[t][d] * E[d][e] (complex), d-order kept ----
  float xer[16], xei[16];
#pragma unroll
  for (int t = 0; t < 16; t++) { xer[t] = 0.f; xei[t] = 0.f; }
  for (int d = 0; d < 32; d++) {
    float er_ = sEr[d * 32 + e], ei_ = sEi[d * 32 + e];
    const float4* rb = (const float4*)&sXr[d * 132 + tok0];
    const float4* ib = (const float4*)&sXi[d * 132 + tok0];
#pragma unroll
    for (int j = 0; j < 4; j++) {
      float4 a4 = rb[j], c4 = ib[j];
      float av[4] = {a4.x, a4.y, a4.z, a4.w};
      float cv[4] = {c4.x, c4.y, c4.z, c4.w};
#pragma unroll
      for (int k = 0; k < 4; k++) {
        int t = 4 * j + k;
        xer[t] += av[k] * er_ - cv[k] * ei_;
        xei[t] += av[k] * ei_ + cv[k] * er_;
      }
    }
  }
  // ---- scan in registers; write h transposed (own-sI columns only) ----
  float hr = 0.f, hi = 0.f;
#pragma unroll
  for (int t = 0; t < 16; t++) {
    float ur = xer[t] * fr - xei[t] * fi;
    float ui = xer[t] * fi + xei[t] * fr;
    float t1 = dcr * hr - dci * hi + ur;
    hi = dcr * hi + dci * hr + ui;
    hr = t1;
    sXr[e * 132 + tok0 + t] = hr;
    sXi[e * 132 + tok0 + t] = hi;
  }
  __syncthreads();  // safety (deps are wave-internal: columns partition by sI)
  // ---- decode: out[t][e] = sum_d h[t][d]*Dr[d][e] - hIm[t][d]*Di[d][e] ----
  float oacc[16];
#pragma unroll
  for (int t = 0; t < 16; t++) oacc[t] = 0.f;
  for (int d = 0; d < 32; d++) {
    float dr_ = sDr[d * 32 + e], di_ = sDi[d * 32 + e];
    const float4* rb = (const float4*)&sXr[d * 132 + tok0];
    const float4* ib = (const float4*)&sXi[d * 132 + tok0];
#pragma unroll
    for (int j = 0; j < 4; j++) {
      float4 a4 = rb[j], c4 = ib[j];
      float av[4] = {a4.x, a4.y, a4.z, a4.w};
      float cv[4] = {c4.x, c4.y, c4.z, c4.w};
#pragma unroll
      for (int k = 0; k < 4; k++) {
        int t = 4 * j + k;
        oacc[t] += av[k] * dr_ - cv[k] * di_;
      }
    }
  }
  int n = n0 + sI;
  int bb = n >> 12;
  int hw = n & 4095;
#pragma unroll
  for (int t = 0; t < 16; t++) {
    size_t tokb = ((size_t)(bb * 16 + t)) * 4096 + hw;
    xr[tokb * 32 + e] += oacc[t];  // drift is real-only
  }
}

// ---------------- K7: para pool MLP via bf16 MFMA + residual + output (F32 PLANAR) ----------------
__global__ __launch_bounds__(256) void k7_pool(
    const float* __restrict__ xr, const float* __restrict__ xi,
    const float* __restrict__ pw1, const float* __restrict__ pb1,
    const float* __restrict__ pw2, const float* __restrict__ pb2,
    float* __restrict__ out, long long out_n) {
  __shared__ __align__(16) short sXh[64 * 72];  // xp hi bf16 [tok][c]   9.2 KB
  __shared__ __align__(16) short sXl[64 * 72];  // xp lo bf16            9.2 KB
  __shared__ __align__(16) short sW[64 * 72];   // weight chunk [n][k]   9.2 KB
  __shared__ __align__(16) float sH[64 * 68];   // hidden f32 [tok][el] 17.4 KB
  int tok0 = blockIdx.x * 64;
  // stage xp as hi/lo bf16 pair: x = hi + lo to ~16 mantissa bits
  for (int i = threadIdx.x; i < 4096; i += 256) {
    int t = i >> 6, c = i & 63;
    float v = (c < 32) ? xr[(size_t)(tok0 + t) * 32 + c]
                       : xi[(size_t)(tok0 + t) * 32 + c - 32];
    short hb = f2bf(v);
    float hf = __uint_as_float(((unsigned)(unsigned short)hb) << 16);
    sXh[t * 72 + c] = hb;
    sXl[t * 72 + c] = f2bf(v - hf);
  }
  int lane = threadIdx.x & 63;
  int wv = threadIdx.x >> 6;
  int lr = lane & 15;
  int quad = lane >> 4;
  int m0 = wv * 16;          // this wave's 16-token strip
  f32x4 acc2[4];             // persistent GEMM2 accumulator, bias preloaded
#pragma unroll
  for (int nt = 0; nt < 4; nt++) {
    float bz = pb2[nt * 16 + lr];
    acc2[nt][0] = bz; acc2[nt][1] = bz; acc2[nt][2] = bz; acc2[nt][3] = bz;
  }
  for (int ec = 0; ec < 4; ec++) {
    __syncthreads();  // prev GEMM2 done with sW/sH; xp staged (ec=0)
    // stage w1 chunk: sW[el][c] = w1[ec*64+el][c]  (already B^T layout)
    for (int i = threadIdx.x; i < 4096; i += 256) {
      int el = i >> 6, c = i & 63;
      sW[el * 72 + c] = f2bf(pw1[(size_t)(ec * 64 + el) * 64 + c]);
    }
    __syncthreads();
    f32x4 acc1[4];
#pragma unroll
    for (int nt = 0; nt < 4; nt++) {
      float bz = pb1[ec * 64 + nt * 16 + lr];
      acc1[nt][0] = bz; acc1[nt][1] = bz; acc1[nt][2] = bz; acc1[nt][3] = bz;
    }
    const short* arh = &sXh[(size_t)(m0 + lr) * 72 + quad * 8];
    const short* arl = &sXl[(size_t)(m0 + lr) * 72 + quad * 8];
#pragma unroll
    for (int ks = 0; ks < 2; ks++) {
      bf16x8 ah = *(const bf16x8*)(arh + ks * 32);
      bf16x8 al = *(const bf16x8*)(arl + ks * 32);
#pragma unroll
      for (int nt = 0; nt < 4; nt++) {
        bf16x8 bfrag = *(const bf16x8*)&sW[(size_t)(nt * 16 + lr) * 72 + ks * 32 + quad * 8];
        acc1[nt] = __builtin_amdgcn_mfma_f32_16x16x32_bf16(ah, bfrag, acc1[nt], 0, 0, 0);
        acc1[nt] = __builtin_amdgcn_mfma_f32_16x16x32_bf16(al, bfrag, acc1[nt], 0, 0, 0);
      }
    }
    // gelu (tanh approx, jax default) -> sH[tok][e_local] (f32, 2-way banks = free)
#pragma unroll
    for (int nt = 0; nt < 4; nt++) {
#pragma unroll
      for (int reg = 0; reg < 4; reg++) {
        float x = acc1[nt][reg];
        float u = 0.7978845608f * (x + 0.044715f * x * x * x);
        float e2 = __expf(2.f * u);
        float th = 1.f - 2.f / (e2 + 1.f);
        sH[(m0 + quad * 4 + reg) * 68 + nt * 16 + lr] = 0.5f * x * (1.f + th);
      }
    }
    __syncthreads();  // GEMM1 reads of sW done, sH writes done
    // stage w2 chunk: sW[oc][el] = w2[oc][ec*64+el]
    for (int i = threadIdx.x; i < 4096; i += 256) {
      int oc = i >> 6, el = i & 63;
      sW[oc * 72 + el] = f2bf(pw2[(size_t)oc * 256 + ec * 64 + el]);
    }
    __syncthreads();
    // GEMM2: A = gelu(hidden) converted bf16 on the fly, accumulate into acc2
    const float* hrow = &sH[(size_t)(m0 + lr) * 68 + quad * 8];
#pragma unroll
    for (int ks = 0; ks < 2; ks++) {
      float4 h0 = *(const float4*)(hrow + ks * 32);
      float4 h1 = *(const float4*)(hrow + ks * 32 + 4);
      bf16x8 af;
      af[0] = f2bf(h0.x); af[1] = f2bf(h0.y); af[2] = f2bf(h0.z); af[3] = f2bf(h0.w);
      af[4] = f2bf(h1.x); af[5] = f2bf(h1.y); af[6] = f2bf(h1.z); af[7] = f2bf(h1.w);
#pragma unroll
      for (int nt = 0; nt < 4; nt++) {
        bf16x8 bfrag = *(const bf16x8*)&sW[(size_t)(nt * 16 + lr) * 72 + ks * 32 + quad * 8];
        acc2[nt] = __builtin_amdgcn_mfma_f32_16x16x32_bf16(af, bfrag, acc2[nt], 0, 0, 0);
      }
    }
  }
  // epilogue: D[row=quad*4+reg][col=lr] -> + residual -> planar f32 out
#pragma unroll
  for (int nt = 0; nt < 4; nt++) {
    int oc = nt * 16 + lr;
#pragma unroll
    for (int reg = 0; reg < 4; reg++) {
      int t = tok0 + m0 + quad * 4 + reg;
      float resid = (oc < 32) ? xr[(size_t)t * 32 + oc] : xi[(size_t)t * 32 + oc - 32];
      float val = acc2[nt][reg] + resid;
      int bt = t >> 12;
      int hw = t & 4095;
      int d = (oc < 32) ? oc : oc - 32;
      size_t cidx = (size_t)(bt * 32 + d) * 4096 + hw;  // [B,T,D,H,W] index
      long long pos = (long long)cidx + ((oc < 32) ? 0ll : (long long)ND_);
      if (pos < out_n) out[pos] = val;
    }
  }
}

// ---------------- launch ----------------
extern "C" void kernel_launch(void* const* d_in, const int* in_sizes, int n_in,
                              void* d_out, int out_size, void* d_ws, size_t ws_size,
                              hipStream_t stream) {
  (void)in_sizes; (void)n_in;
  const float* xr_in = (const float*)d_in[0];
  const float* xi_in = (const float*)d_in[1];
  const float* dt = (const float*)d_in[2];
  const float* ln_s_g = (const float*)d_in[3];
  const float* ln_s_b = (const float*)d_in[4];
  const float* conv_w = (const float*)d_in[5];
  const float* conv_b = (const float*)d_in[6];
  const float* spec_fr = (const float*)d_in[7];
  const float* spec_fi = (const float*)d_in[8];
  const float* lam_r = (const float*)d_in[9];
  const float* lam_i = (const float*)d_in[10];
  const float* E_r = (const float*)d_in[11];
  const float* E_i = (const float*)d_in[12];
  const float* Dm_r = (const float*)d_in[13];
  const float* Dm_i = (const float*)d_in[14];
  const float* ln_t_g = (const float*)d_in[15];
  const float* ln_t_b = (const float*)d_in[16];
  const float* pw1 = (const float*)d_in[17];
  const float* pb1 = (const float*)d_in[18];
  const float* pw2 = (const float*)d_in[19];
  const float* pb2 = (const float*)d_in[20];
  const float* gate = (const float*)d_in[21];

  if (ws_size < 6ull * ND_ * 4ull) return;  // need 96 MB f32 scratch

  float* ws = (float*)d_ws;
  float* znr = ws;                 // -> becomes x_re after K5
  float* zni = ws + ND_;           // -> becomes x_im after K5
  float* clr = ws + 2 * ND_;
  float* cli = ws + 3 * ND_;
  float* fqr = ws + 4 * ND_;
  float* fqi = ws + 5 * ND_;
  float* out = (float*)d_out;
  // pre-K3 scratch aliases (consumed by K2 before K3/K4 overwrite them)
  unsigned short* znb = (unsigned short*)fqr;  // zn bf16 [tok][64], exactly ND_*4 B
  unsigned short* wb = (unsigned short*)fqi;   // conv_w bf16 [kk][oc][ic], 73 KB

  k0_prepw<<<144, 256, 0, stream>>>(conv_w, wb);
  k1_cnorm_spatial<<<512, 256, 0, stream>>>(xr_in, xi_in, ln_s_g, ln_s_b, znr, zni, znb);
  k2_conv<<<dim3(64, 32), 256, 0, stream>>>(znb, wb, conv_b, clr, cli);
  k3_dftw<<<dim3(64, 32), 256, 0, stream>>>(znr, zni, fqr, fqi);
  k4_dfth<<<dim3(64, 32), 256, 0, stream>>>(fqr, fqi, spec_fr, spec_fi);
  k5_idftw_combine<<<dim3(64, 32), 256, 0, stream>>>(fqr, fqi, clr, cli, xr_in, xi_in,
                                                     gate, znr, zni);
  k6_temporal<<<1024, 256, 0, stream>>>(znr, zni, lam_r, lam_i, E_r, E_i, Dm_r, Dm_i,
                                        ln_t_g, ln_t_b, dt);
  k7_pool<<<2048, 256, 0, stream>>>(znr, zni, pw1, pb1, pw2, pb2, out, (long long)out_size);
}

// Round 4
// 410.228 us; speedup vs baseline: 1.7695x; 1.0377x over previous
//
#include <hip/hip_runtime.h>
#include <cstddef>

// UniPhyBlock on gfx950 — f32 inputs, f32 internal pipeline, F32 PLANAR OUTPUT.
// Round 15: (a) k7_pool weight staging de-scalarized — pw1/pw2 pre-converted
// to bf16 once (k8_pool_prepw, into fqr plane which is dead after k5), staged
// via ushort8 copies (was 128 scalar loads + 128 f2bf per thread per block;
// VALUBusy=58%, MfmaUtil=6%). (b) k3/k4/k5 DFT-output LDS rows padded to
// stride 36 (was 32): write banks (4k+db+j)%32 -> 8-way instead of 32-way
// (5.7M conflict cycles in k4). Both changes are bit-identical numerics.
// Output: PLANAR f32 — out[cidx]=real, out[ND+cidx]=imag, cidx over [B,T,D,H,W].
// ws (f32): [0]=zn_re (later x_re), [1]=zn_im (later x_im), [2]=cliff_re,
//           [3]=cliff_im, [4]=freq_re (pre-K3: zn bf16; post-K5: pool w bf16),
//           [5]=freq_im (pre-K3: conv_w bf16 [kk][oc][ic])  -> 96 MB.

#define EPS_ 1e-5f
#define PI_  3.14159265358979323846f
#define ND_  4194304ull
#define DST_ 36   // padded DFT row stride (f32 words)

typedef __attribute__((ext_vector_type(8))) short bf16x8;   // 8 bf16 (4 VGPRs)
typedef __attribute__((ext_vector_type(4))) float f32x4;    // MFMA C/D

__device__ __forceinline__ short f2bf(float f) {
  unsigned u = __float_as_uint(f);
  unsigned r = (u + 0x7fffu + ((u >> 16) & 1u)) >> 16;  // RNE
  return (short)r;
}

// ---------------- K0: one-time conv weight transpose+convert ----------------
// wgt [kk][ic][oc] f32 -> wb [kk][oc][ic] bf16 (36864 elems)
__global__ __launch_bounds__(256) void k0_prepw(
    const float* __restrict__ wgt, unsigned short* __restrict__ wb) {
  int j = blockIdx.x * 256 + threadIdx.x;   // grid 144*256 = 36864
  int kk = j >> 12;
  int rem = j & 4095;
  int oc = rem >> 6;
  int ic = rem & 63;
  wb[j] = (unsigned short)f2bf(wgt[((size_t)kk * 64 + ic) * 64 + oc]);
}

// ---------------- K8: one-time pool weight convert (runs after K5) ----------------
// pwb1[j] = bf16(pw1[j])            ([e][c] layout, direct)
// pwb2[ec*4096+oc*64+el] = bf16(pw2[oc*256+ec*64+el])
__global__ __launch_bounds__(256) void k8_pool_prepw(
    const float* __restrict__ pw1, const float* __restrict__ pw2,
    unsigned short* __restrict__ pwb1, unsigned short* __restrict__ pwb2) {
  int j = blockIdx.x * 256 + threadIdx.x;   // grid 128*256 = 32768
  if (j < 16384) {
    pwb1[j] = (unsigned short)f2bf(pw1[j]);
  } else {
    int j2 = j - 16384;
    int ec = j2 >> 12;
    int rem = j2 & 4095;
    int oc = rem >> 6;
    int el = rem & 63;
    pwb2[j2] = (unsigned short)f2bf(pw2[(size_t)oc * 256 + ec * 64 + el]);
  }
}

// ---------------- K1: input transpose + spatial cnorm (+ bf16 zn copy) ----------------
__global__ __launch_bounds__(256) void k1_cnorm_spatial(
    const float* __restrict__ xr, const float* __restrict__ xi,
    const float* __restrict__ g, const float* __restrict__ b,
    float* __restrict__ znr, float* __restrict__ zni,
    unsigned short* __restrict__ znb) {
  int tok = blockIdx.x * 256 + threadIdx.x;      // (bt,h,w)
  int bt = tok >> 12;
  int hw = tok & 4095;
  const float* pr = xr + (size_t)bt * 131072 + hw;   // bt*D*HW
  const float* pi = xi + (size_t)bt * 131072 + hw;
  float r[32], q[32];
  float s = 0.f;
#pragma unroll
  for (int d = 0; d < 32; d++) {
    r[d] = pr[(size_t)d * 4096];
    q[d] = pi[(size_t)d * 4096];
    s += r[d] + q[d];
  }
  float mu = s * 0.015625f;
  float v = 0.f;
#pragma unroll
  for (int d = 0; d < 32; d++) {
    float a = r[d] - mu, c = q[d] - mu;
    v += a * a + c * c;
  }
  float rstd = rsqrtf(v * 0.015625f + EPS_);
#pragma unroll
  for (int d = 0; d < 32; d++) {
    r[d] = (r[d] - mu) * rstd * g[d] + b[d];
    q[d] = (q[d] - mu) * rstd * g[32 + d] + b[32 + d];
  }
  float4* outr = (float4*)(znr + (size_t)tok * 32);
  float4* outi = (float4*)(zni + (size_t)tok * 32);
#pragma unroll
  for (int j = 0; j < 8; j++) {
    outr[j] = make_float4(r[4 * j], r[4 * j + 1], r[4 * j + 2], r[4 * j + 3]);
    outi[j] = make_float4(q[4 * j], q[4 * j + 1], q[4 * j + 2], q[4 * j + 3]);
  }
  // bf16 copy [tok][64]: ch 0..31 = re, 32..63 = im (same values k2 used before)
  short* zb = (short*)(znb + (size_t)tok * 64);
#pragma unroll
  for (int j = 0; j < 4; j++) {
    bf16x8 vr, vq;
#pragma unroll
    for (int k = 0; k < 8; k++) {
      vr[k] = f2bf(r[8 * j + k]);
      vq[k] = f2bf(q[8 * j + k]);
    }
    *(bf16x8*)(zb + 8 * j) = vr;
    *(bf16x8*)(zb + 32 + 8 * j) = vq;
  }
}

// ---------------- K2: 3x3 SAME conv via bf16 MFMA implicit GEMM ----------------
__global__ __launch_bounds__(256) void k2_conv(
    const unsigned short* __restrict__ znb, const unsigned short* __restrict__ wb,
    const float* __restrict__ bias,
    float* __restrict__ clr, float* __restrict__ cli) {
  __shared__ __align__(16) short sA[3 * 66 * 88];   // 34.8 KB
  __shared__ __align__(16) short sW[2][64 * 72];    // 18.4 KB
  int h = blockIdx.x, bt = blockIdx.y;
  // stage activations (3 rows, w in [-1,64], 64 ch) as ushort8 copies
  for (int v = threadIdx.x; v < 1584; v += 256) {   // 198 rows * 8 vecs
    int c0 = (v & 7) * 8;
    int row = v >> 3;           // 0..197 = rr*66 + wp
    int wp = row % 66;
    int rr = row / 66;
    int hh = h + rr - 1;
    int w = wp - 1;
    bf16x8 val = {0, 0, 0, 0, 0, 0, 0, 0};
    if ((unsigned)hh < 64u && (unsigned)w < 64u) {
      int tok = (bt * 64 + hh) * 64 + w;
      val = *(const bf16x8*)(znb + (size_t)tok * 64 + c0);
    }
    *(bf16x8*)(&sA[(rr * 66 + wp) * 88 + c0]) = val;
  }
  // stage weight chunk 0 into buffer 0
  for (int v = threadIdx.x; v < 512; v += 256) {
    int oc = v >> 3, ic0 = (v & 7) * 8;
    *(bf16x8*)(&sW[0][oc * 72 + ic0]) = *(const bf16x8*)(wb + v * 8);
  }
  int lane = threadIdx.x & 63;
  int wv = threadIdx.x >> 6;
  int m0 = wv * 16;          // this wave's 16-token strip
  int lr = lane & 15;        // A-row / B-col / D-col
  int quad = lane >> 4;      // k-chunk selector; D-row group
  f32x4 acc[4];
#pragma unroll
  for (int nt = 0; nt < 4; nt++) {
    float bz = bias[nt * 16 + lr];
    acc[nt][0] = bz; acc[nt][1] = bz; acc[nt][2] = bz; acc[nt][3] = bz;
  }
  __syncthreads();
  for (int kk = 0; kk < 9; kk++) {
    int cur = kk & 1;
    if (kk < 8) {  // prefetch next chunk into the other buffer
      const unsigned short* src = wb + (size_t)(kk + 1) * 4096;
      for (int v = threadIdx.x; v < 512; v += 256) {
        int oc = v >> 3, ic0 = (v & 7) * 8;
        *(bf16x8*)(&sW[cur ^ 1][oc * 72 + ic0]) = *(const bf16x8*)(src + v * 8);
      }
    }
    int kh = kk / 3, kw = kk - kh * 3;
    const short* arow = &sA[((size_t)kh * 66 + (m0 + lr + kw)) * 88 + quad * 8];
#pragma unroll
    for (int ks = 0; ks < 2; ks++) {
      bf16x8 afrag = *(const bf16x8*)(arow + ks * 32);
#pragma unroll
      for (int nt = 0; nt < 4; nt++) {
        bf16x8 bfrag = *(const bf16x8*)&sW[cur][(size_t)(nt * 16 + lr) * 72 + ks * 32 + quad * 8];
        acc[nt] = __builtin_amdgcn_mfma_f32_16x16x32_bf16(afrag, bfrag, acc[nt], 0, 0, 0);
      }
    }
    __syncthreads();  // next buf written; cur free for overwrite at kk+1
  }
  // epilogue: D[row=quad*4+reg][col=lr] per n-tile -> clr/cli (f32)
  int tokbase = (bt * 64 + h) * 64 + m0;
#pragma unroll
  for (int nt = 0; nt < 4; nt++) {
    int oc = nt * 16 + lr;
    float* dst = (oc < 32) ? (clr + oc) : (cli + (oc - 32));
#pragma unroll
    for (int reg = 0; reg < 4; reg++) {
      int m = quad * 4 + reg;
      dst[(size_t)(tokbase + m) * 32] = acc[nt][reg];
    }
  }
}

// ---------------- K3: forward DFT along W ----------------
__global__ __launch_bounds__(256) void k3_dftw(
    const float* __restrict__ znr, const float* __restrict__ zni,
    float* __restrict__ fqr, float* __restrict__ fqi) {
  __shared__ __align__(16) float sr[64 * DST_], si[64 * DST_];
  __shared__ float twr[64], twi[64];
  int h = blockIdx.x, bt = blockIdx.y;
  size_t base = (size_t)((bt * 64 + h) * 64) * 32;
  if (threadIdx.x < 64) {
    float ang = -2.f * PI_ * (float)threadIdx.x * (1.f / 64.f);
    twr[threadIdx.x] = cosf(ang);
    twi[threadIdx.x] = sinf(ang);
  }
  for (int i = threadIdx.x; i < 2048; i += 256) {
    int row = i >> 5, col = i & 31;
    sr[row * DST_ + col] = znr[base + i];
    si[row * DST_ + col] = zni[base + i];
  }
  __syncthreads();
  int k = threadIdx.x & 63;
  int dbase = (threadIdx.x >> 6) * 8;
  float ar[8] = {0, 0, 0, 0, 0, 0, 0, 0}, ai[8] = {0, 0, 0, 0, 0, 0, 0, 0};
  for (int w = 0; w < 64; w++) {
    int idx = (w * k) & 63;
    float tr = twr[idx], ti = twi[idx];
    const float4* pr4 = (const float4*)&sr[w * DST_ + dbase];
    const float4* pi4 = (const float4*)&si[w * DST_ + dbase];
    float4 a0 = pr4[0], a1 = pr4[1], b0 = pi4[0], b1 = pi4[1];
    float rr[8] = {a0.x, a0.y, a0.z, a0.w, a1.x, a1.y, a1.z, a1.w};
    float ii[8] = {b0.x, b0.y, b0.z, b0.w, b1.x, b1.y, b1.z, b1.w};
#pragma unroll
    for (int j = 0; j < 8; j++) {
      ar[j] += rr[j] * tr - ii[j] * ti;
      ai[j] += rr[j] * ti + ii[j] * tr;
    }
  }
  __syncthreads();
#pragma unroll
  for (int j = 0; j < 8; j++) {
    sr[k * DST_ + dbase + j] = ar[j];
    si[k * DST_ + dbase + j] = ai[j];
  }
  __syncthreads();
  for (int i = threadIdx.x; i < 2048; i += 256) {
    int row = i >> 5, col = i & 31;
    fqr[base + i] = sr[row * DST_ + col];
    fqi[base + i] = si[row * DST_ + col];
  }
}

// ---------------- K4: fwd DFT along H, * filt, inv DFT along H (in place) ----------------
__global__ __launch_bounds__(256) void k4_dfth(
    float* __restrict__ fqr, float* __restrict__ fqi,
    const float* __restrict__ flr, const float* __restrict__ fli) {
  __shared__ __align__(16) float sr[64 * DST_], si[64 * DST_];
  __shared__ __align__(16) float Fr[64 * DST_], Fi[64 * DST_];
  __shared__ float twr[64], twi[64];
  int kw = blockIdx.x, bt = blockIdx.y;
  if (threadIdx.x < 64) {
    float ang = -2.f * PI_ * (float)threadIdx.x * (1.f / 64.f);
    twr[threadIdx.x] = cosf(ang);
    twi[threadIdx.x] = sinf(ang);
  }
  for (int i = threadIdx.x; i < 2048; i += 256) {
    int hh = i >> 5, d = i & 31;
    size_t ga = (size_t)((bt * 64 + hh) * 64 + kw) * 32 + d;
    sr[hh * DST_ + d] = fqr[ga];
    si[hh * DST_ + d] = fqi[ga];
  }
  __syncthreads();
  int kh = threadIdx.x & 63;
  int dbase = (threadIdx.x >> 6) * 8;
  {
    float ar[8] = {0, 0, 0, 0, 0, 0, 0, 0}, ai[8] = {0, 0, 0, 0, 0, 0, 0, 0};
    for (int hh = 0; hh < 64; hh++) {
      int idx = (hh * kh) & 63;
      float tr = twr[idx], ti = twi[idx];
      const float4* pr4 = (const float4*)&sr[hh * DST_ + dbase];
      const float4* pi4 = (const float4*)&si[hh * DST_ + dbase];
      float4 a0 = pr4[0], a1 = pr4[1], b0 = pi4[0], b1 = pi4[1];
      float rr[8] = {a0.x, a0.y, a0.z, a0.w, a1.x, a1.y, a1.z, a1.w};
      float ii[8] = {b0.x, b0.y, b0.z, b0.w, b1.x, b1.y, b1.z, b1.w};
#pragma unroll
      for (int j = 0; j < 8; j++) {
        ar[j] += rr[j] * tr - ii[j] * ti;
        ai[j] += rr[j] * ti + ii[j] * tr;
      }
    }
    // multiply by filt[kh][kw][d]
    const float4* fr4 = (const float4*)&flr[(size_t)(kh * 64 + kw) * 32 + dbase];
    const float4* fi4 = (const float4*)&fli[(size_t)(kh * 64 + kw) * 32 + dbase];
    float4 f0 = fr4[0], f1 = fr4[1], g0 = fi4[0], g1 = fi4[1];
    float fre[8] = {f0.x, f0.y, f0.z, f0.w, f1.x, f1.y, f1.z, f1.w};
    float fim[8] = {g0.x, g0.y, g0.z, g0.w, g1.x, g1.y, g1.z, g1.w};
#pragma unroll
    for (int j = 0; j < 8; j++) {
      float pr = ar[j] * fre[j] - ai[j] * fim[j];
      float pi = ar[j] * fim[j] + ai[j] * fre[j];
      Fr[kh * DST_ + dbase + j] = pr;
      Fi[kh * DST_ + dbase + j] = pi;
    }
  }
  __syncthreads();
  int hh2 = threadIdx.x & 63;
  {
    float ar[8] = {0, 0, 0, 0, 0, 0, 0, 0}, ai[8] = {0, 0, 0, 0, 0, 0, 0, 0};
    for (int k2 = 0; k2 < 64; k2++) {
      int idx = (hh2 * k2) & 63;
      float tr = twr[idx], ti = -twi[idx];  // conj -> inverse
      const float4* pr4 = (const float4*)&Fr[k2 * DST_ + dbase];
      const float4* pi4 = (const float4*)&Fi[k2 * DST_ + dbase];
      float4 a0 = pr4[0], a1 = pr4[1], b0 = pi4[0], b1 = pi4[1];
      float rr[8] = {a0.x, a0.y, a0.z, a0.w, a1.x, a1.y, a1.z, a1.w};
      float ii[8] = {b0.x, b0.y, b0.z, b0.w, b1.x, b1.y, b1.z, b1.w};
#pragma unroll
      for (int j = 0; j < 8; j++) {
        ar[j] += rr[j] * tr - ii[j] * ti;
        ai[j] += rr[j] * ti + ii[j] * tr;
      }
    }
#pragma unroll
    for (int j = 0; j < 8; j++) {
      sr[hh2 * DST_ + dbase + j] = ar[j] * 0.015625f;  // 1/64 (H-inverse)
      si[hh2 * DST_ + dbase + j] = ai[j] * 0.015625f;
    }
  }
  __syncthreads();
  for (int i = threadIdx.x; i < 2048; i += 256) {
    int hh = i >> 5, d = i & 31;
    size_t ga = (size_t)((bt * 64 + hh) * 64 + kw) * 32 + d;
    fqr[ga] = sr[hh * DST_ + d];
    fqi[ga] = si[hh * DST_ + d];
  }
}

// ---------------- K5: inv DFT along W + gate combine + residual -> x ----------------
__global__ __launch_bounds__(256) void k5_idftw_combine(
    const float* __restrict__ fqr, const float* __restrict__ fqi,
    const float* __restrict__ clr, const float* __restrict__ cli,
    const float* __restrict__ xr_in, const float* __restrict__ xi_in,
    const float* __restrict__ gate,
    float* __restrict__ xr, float* __restrict__ xi) {
  __shared__ __align__(16) float sr[64 * DST_], si[64 * DST_];
  __shared__ float twr[64], twi[64];
  int h = blockIdx.x, bt = blockIdx.y;
  size_t base = (size_t)((bt * 64 + h) * 64) * 32;
  if (threadIdx.x < 64) {
    float ang = -2.f * PI_ * (float)threadIdx.x * (1.f / 64.f);
    twr[threadIdx.x] = cosf(ang);
    twi[threadIdx.x] = sinf(ang);
  }
  for (int i = threadIdx.x; i < 2048; i += 256) {
    int row = i >> 5, col = i & 31;
    sr[row * DST_ + col] = fqr[base + i];
    si[row * DST_ + col] = fqi[base + i];
  }
  __syncthreads();
  int w = threadIdx.x & 63;
  int dbase = (threadIdx.x >> 6) * 8;
  float ar[8] = {0, 0, 0, 0, 0, 0, 0, 0}, ai[8] = {0, 0, 0, 0, 0, 0, 0, 0};
  for (int kw = 0; kw < 64; kw++) {
    int idx = (w * kw) & 63;
    float tr = twr[idx], ti = -twi[idx];
    const float4* pr4 = (const float4*)&sr[kw * DST_ + dbase];
    const float4* pi4 = (const float4*)&si[kw * DST_ + dbase];
    float4 a0 = pr4[0], a1 = pr4[1], b0 = pi4[0], b1 = pi4[1];
    float rr[8] = {a0.x, a0.y, a0.z, a0.w, a1.x, a1.y, a1.z, a1.w};
    float ii[8] = {b0.x, b0.y, b0.z, b0.w, b1.x, b1.y, b1.z, b1.w};
#pragma unroll
    for (int j = 0; j < 8; j++) {
      ar[j] += rr[j] * tr - ii[j] * ti;
      ai[j] += rr[j] * ti + ii[j] * tr;
    }
  }
  float g = gate[0];
  float gi = 1.f - g;
  const float4* c4r = (const float4*)&clr[base + w * 32 + dbase];
  const float4* c4i = (const float4*)&cli[base + w * 32 + dbase];
  float4 cr0 = c4r[0], cr1 = c4r[1], ci0 = c4i[0], ci1 = c4i[1];
  float cre[8] = {cr0.x, cr0.y, cr0.z, cr0.w, cr1.x, cr1.y, cr1.z, cr1.w};
  float cim[8] = {ci0.x, ci0.y, ci0.z, ci0.w, ci1.x, ci1.y, ci1.z, ci1.w};
  float orr[8], oii[8];
#pragma unroll
  for (int j = 0; j < 8; j++) {
    int d = dbase + j;
    size_t ga = (size_t)(bt * 32 + d) * 4096 + h * 64 + w;  // input [B,T,D,H,W]
    orr[j] = g * cre[j] + gi * (ar[j] * 0.015625f) + xr_in[ga];
    oii[j] = g * cim[j] + gi * (ai[j] * 0.015625f) + xi_in[ga];
  }
  __syncthreads();
#pragma unroll
  for (int j = 0; j < 8; j++) {
    sr[w * DST_ + dbase + j] = orr[j];
    si[w * DST_ + dbase + j] = oii[j];
  }
  __syncthreads();
  for (int i = threadIdx.x; i < 2048; i += 256) {
    int row = i >> 5, col = i & 31;
    xr[base + i] = sr[row * DST_ + col];
    xi[base + i] = si[row * DST_ + col];
  }
}

// ---------------- K6: temporal cnorm + eigen encode + decay scan + decode ----------------
__global__ __launch_bounds__(256) void k6_temporal(
    float* __restrict__ xr, float* __restrict__ xi,
    const float* __restrict__ lamr, const float* __restrict__ lami,
    const float* __restrict__ Er, const float* __restrict__ Ei,
    const float* __restrict__ Dmr, const float* __restrict__ Dmi,
    const float* __restrict__ lg, const float* __restrict__ lb,
    const float* __restrict__ dtp) {
  __shared__ float sEr[1024], sEi[1024], sDr[1024], sDi[1024];
  __shared__ __align__(16) float sXr[32 * 132];  // xt^T [d][tok], later h^T
  __shared__ __align__(16) float sXi[32 * 132];
  int n0 = blockIdx.x * 8;
  for (int i = threadIdx.x; i < 1024; i += 256) {
    sEr[i] = Er[i];
    sEi[i] = Ei[i];
    sDr[i] = Dmr[i];
    sDi[i] = Dmi[i];
  }
  if (threadIdx.x < 128) {
    int sIc = threadIdx.x >> 4;
    int t = threadIdx.x & 15;
    int n = n0 + sIc;
    int bb = n >> 12;
    int hw = n & 4095;
    size_t tokb = ((size_t)(bb * 16 + t)) * 4096 + hw;
    const float4* pr = (const float4*)(xr + tokb * 32);
    const float4* pi = (const float4*)(xi + tokb * 32);
    float rv[32], iv[32];
    float s = 0.f;
#pragma unroll
    for (int j = 0; j < 8; j++) {
      float4 a = pr[j];
      float4 c = pi[j];
      rv[4 * j] = a.x; rv[4 * j + 1] = a.y; rv[4 * j + 2] = a.z; rv[4 * j + 3] = a.w;
      iv[4 * j] = c.x; iv[4 * j + 1] = c.y; iv[4 * j + 2] = c.z; iv[4 * j + 3] = c.w;
      s += a.x + a.y + a.z + a.w + c.x + c.y + c.z + c.w;
    }
    float mu = s * 0.015625f;
    float v = 0.f;
#pragma unroll
    for (int d = 0; d < 32; d++) {
      float a = rv[d] - mu, c = iv[d] - mu;
      v += a * a + c * c;
    }
    float rstd = rsqrtf(v * 0.015625f + EPS_);
    int col = threadIdx.x;   // sIc*16 + t
#pragma unroll
    for (int d = 0; d < 32; d++) {
      sXr[d * 132 + col] = (rv[d] - mu) * rstd * lg[d] + lb[d];
      sXi[d * 132 + col] = (iv[d] - mu) * rstd * lg[32 + d] + lb[32 + d];
    }
  }
  __syncthreads();
  int sI = threadIdx.x >> 5;
  int e = threadIdx.x & 31;
  int tok0 = sI * 16;
  float dts = dtp[0];
  float lr = lamr[e], li = lami[e];
  float ex = expf(lr * dts);
  float dcr = ex * cosf(li * dts);
  float dci = ex * sinf(li * dts);
  float nr = dcr - 1.f, ni = dci;
  float invden = 1.f / (lr * lr + li * li);
  float fr = (nr * lr + ni * li) * invden;
  float fi = (ni * lr - nr * li) * invden;
  // ---- encode: xer/xei[t] = sum_d xt[t][d] * E[d][e] (complex), d-order kept ----
  float xer[16], xei[16];
#pragma unroll
  for (int t = 0; t < 16; t++) { xer[t] = 0.f; xei[t] = 0.f; }
  for (int d = 0; d < 32; d++) {
    float er_ = sEr[d * 32 + e], ei_ = sEi[d * 32 + e];
    const float4* rb = (const float4*)&sXr[d * 132 + tok0];
    const float4* ib = (const float4*)&sXi[d * 132 + tok0];
#pragma unroll
    for (int j = 0; j < 4; j++) {
      float4 a4 = rb[j], c4 = ib[j];
      float av[4] = {a4.x, a4.y, a4.z, a4.w};
      float cv[4] = {c4.x, c4.y, c4.z, c4.w};
#pragma unroll
      for (int k = 0; k < 4; k++) {
        int t = 4 * j + k;
        xer[t] += av[k] * er_ - cv[k] * ei_;
        xei[t] += av[k] * ei_ + cv[k] * er_;
      }
    }
  }
  // ---- scan in registers; write h transposed (own-sI columns only) ----
  float hr = 0.f, hi = 0.f;
#pragma unroll
  for (int t = 0; t < 16; t++) {
    float ur = xer[t] * fr - xei[t] * fi;
    float ui = xer[t] * fi + xei[t] * fr;
    float t1 = dcr * hr - dci * hi + ur;
    hi = dcr * hi + dci * hr + ui;
    hr = t1;
    sXr[e * 132 + tok0 + t] = hr;
    sXi[e * 132 + tok0 + t] = hi;
  }
  __syncthreads();  // safety (deps are wave-internal: columns partition by sI)
  // ---- decode: out[t][e] = sum_d h[t][d]*Dr[d][e] - hIm[t][d]*Di[d][e] ----
  float oacc[16];
#pragma unroll
  for (int t = 0; t < 16; t++) oacc[t] = 0.f;
  for (int d = 0; d < 32; d++) {
    float dr_ = sDr[d * 32 + e], di_ = sDi[d * 32 + e];
    const float4* rb = (const float4*)&sXr[d * 132 + tok0];
    const float4* ib = (const float4*)&sXi[d * 132 + tok0];
#pragma unroll
    for (int j = 0; j < 4; j++) {
      float4 a4 = rb[j], c4 = ib[j];
      float av[4] = {a4.x, a4.y, a4.z, a4.w};
      float cv[4] = {c4.x, c4.y, c4.z, c4.w};
#pragma unroll
      for (int k = 0; k < 4; k++) {
        int t = 4 * j + k;
        oacc[t] += av[k] * dr_ - cv[k] * di_;
      }
    }
  }
  int n = n0 + sI;
  int bb = n >> 12;
  int hw = n & 4095;
#pragma unroll
  for (int t = 0; t < 16; t++) {
    size_t tokb = ((size_t)(bb * 16 + t)) * 4096 + hw;
    xr[tokb * 32 + e] += oacc[t];  // drift is real-only
  }
}

// ---------------- K7: para pool MLP via bf16 MFMA + residual + output (F32 PLANAR) ----------------
// Weights pre-converted to bf16 by k8_pool_prepw -> staging is ushort8 copies.
__global__ __launch_bounds__(256) void k7_pool(
    const float* __restrict__ xr, const float* __restrict__ xi,
    const unsigned short* __restrict__ pwb1, const float* __restrict__ pb1,
    const unsigned short* __restrict__ pwb2, const float* __restrict__ pb2,
    float* __restrict__ out, long long out_n) {
  __shared__ __align__(16) short sXh[64 * 72];  // xp hi bf16 [tok][c]   9.2 KB
  __shared__ __align__(16) short sXl[64 * 72];  // xp lo bf16            9.2 KB
  __shared__ __align__(16) short sW[64 * 72];   // weight chunk [n][k]   9.2 KB
  __shared__ __align__(16) float sH[64 * 68];   // hidden f32 [tok][el] 17.4 KB
  int tok0 = blockIdx.x * 64;
  // stage xp as hi/lo bf16 pair: x = hi + lo to ~16 mantissa bits
  for (int i = threadIdx.x; i < 4096; i += 256) {
    int t = i >> 6, c = i & 63;
    float v = (c < 32) ? xr[(size_t)(tok0 + t) * 32 + c]
                       : xi[(size_t)(tok0 + t) * 32 + c - 32];
    short hb = f2bf(v);
    float hf = __uint_as_float(((unsigned)(unsigned short)hb) << 16);
    sXh[t * 72 + c] = hb;
    sXl[t * 72 + c] = f2bf(v - hf);
  }
  int lane = threadIdx.x & 63;
  int wv = threadIdx.x >> 6;
  int lr = lane & 15;
  int quad = lane >> 4;
  int m0 = wv * 16;          // this wave's 16-token strip
  f32x4 acc2[4];             // persistent GEMM2 accumulator, bias preloaded
#pragma unroll
  for (int nt = 0; nt < 4; nt++) {
    float bz = pb2[nt * 16 + lr];
    acc2[nt][0] = bz; acc2[nt][1] = bz; acc2[nt][2] = bz; acc2[nt][3] = bz;
  }
  for (int ec = 0; ec < 4; ec++) {
    __syncthreads();  // prev GEMM2 done with sW/sH; xp staged (ec=0)
    // stage w1 chunk: sW[el][c] = pwb1[ec*4096 + el*64 + c] (ushort8 copies)
    {
      const unsigned short* src = pwb1 + (size_t)ec * 4096;
      for (int v = threadIdx.x; v < 512; v += 256) {
        int el = v >> 3, c0 = (v & 7) * 8;
        *(bf16x8*)(&sW[el * 72 + c0]) = *(const bf16x8*)(src + v * 8);
      }
    }
    __syncthreads();
    f32x4 acc1[4];
#pragma unroll
    for (int nt = 0; nt < 4; nt++) {
      float bz = pb1[ec * 64 + nt * 16 + lr];
      acc1[nt][0] = bz; acc1[nt][1] = bz; acc1[nt][2] = bz; acc1[nt][3] = bz;
    }
    const short* arh = &sXh[(size_t)(m0 + lr) * 72 + quad * 8];
    const short* arl = &sXl[(size_t)(m0 + lr) * 72 + quad * 8];
#pragma unroll
    for (int ks = 0; ks < 2; ks++) {
      bf16x8 ah = *(const bf16x8*)(arh + ks * 32);
      bf16x8 al = *(const bf16x8*)(arl + ks * 32);
#pragma unroll
      for (int nt = 0; nt < 4; nt++) {
        bf16x8 bfrag = *(const bf16x8*)&sW[(size_t)(nt * 16 + lr) * 72 + ks * 32 + quad * 8];
        acc1[nt] = __builtin_amdgcn_mfma_f32_16x16x32_bf16(ah, bfrag, acc1[nt], 0, 0, 0);
        acc1[nt] = __builtin_amdgcn_mfma_f32_16x16x32_bf16(al, bfrag, acc1[nt], 0, 0, 0);
      }
    }
    // gelu (tanh approx, jax default) -> sH[tok][e_local] (f32, 2-way banks = free)
#pragma unroll
    for (int nt = 0; nt < 4; nt++) {
#pragma unroll
      for (int reg = 0; reg < 4; reg++) {
        float x = acc1[nt][reg];
        float u = 0.7978845608f * (x + 0.044715f * x * x * x);
        float e2 = __expf(2.f * u);
        float th = 1.f - 2.f / (e2 + 1.f);
        sH[(m0 + quad * 4 + reg) * 68 + nt * 16 + lr] = 0.5f * x * (1.f + th);
      }
    }
    __syncthreads();  // GEMM1 reads of sW done, sH writes done
    // stage w2 chunk: sW[oc][el] = pwb2[ec*4096 + oc*64 + el] (ushort8 copies)
    {
      const unsigned short* src = pwb2 + (size_t)ec * 4096;
      for (int v = threadIdx.x; v < 512; v += 256) {
        int oc = v >> 3, el0 = (v & 7) * 8;
        *(bf16x8*)(&sW[oc * 72 + el0]) = *(const bf16x8*)(src + v * 8);
      }
    }
    __syncthreads();
    // GEMM2: A = gelu(hidden) converted bf16 on the fly, accumulate into acc2
    const float* hrow = &sH[(size_t)(m0 + lr) * 68 + quad * 8];
#pragma unroll
    for (int ks = 0; ks < 2; ks++) {
      float4 h0 = *(const float4*)(hrow + ks * 32);
      float4 h1 = *(const float4*)(hrow + ks * 32 + 4);
      bf16x8 af;
      af[0] = f2bf(h0.x); af[1] = f2bf(h0.y); af[2] = f2bf(h0.z); af[3] = f2bf(h0.w);
      af[4] = f2bf(h1.x); af[5] = f2bf(h1.y); af[6] = f2bf(h1.z); af[7] = f2bf(h1.w);
#pragma unroll
      for (int nt = 0; nt < 4; nt++) {
        bf16x8 bfrag = *(const bf16x8*)&sW[(size_t)(nt * 16 + lr) * 72 + ks * 32 + quad * 8];
        acc2[nt] = __builtin_amdgcn_mfma_f32_16x16x32_bf16(af, bfrag, acc2[nt], 0, 0, 0);
      }
    }
  }
  // epilogue: D[row=quad*4+reg][col=lr] -> + residual -> planar f32 out
#pragma unroll
  for (int nt = 0; nt < 4; nt++) {
    int oc = nt * 16 + lr;
#pragma unroll
    for (int reg = 0; reg < 4; reg++) {
      int t = tok0 + m0 + quad * 4 + reg;
      float resid = (oc < 32) ? xr[(size_t)t * 32 + oc] : xi[(size_t)t * 32 + oc - 32];
      float val = acc2[nt][reg] + resid;
      int bt = t >> 12;
      int hw = t & 4095;
      int d = (oc < 32) ? oc : oc - 32;
      size_t cidx = (size_t)(bt * 32 + d) * 4096 + hw;  // [B,T,D,H,W] index
      long long pos = (long long)cidx + ((oc < 32) ? 0ll : (long long)ND_);
      if (pos < out_n) out[pos] = val;
    }
  }
}

// ---------------- launch ----------------
extern "C" void kernel_launch(void* const* d_in, const int* in_sizes, int n_in,
                              void* d_out, int out_size, void* d_ws, size_t ws_size,
                              hipStream_t stream) {
  (void)in_sizes; (void)n_in;
  const float* xr_in = (const float*)d_in[0];
  const float* xi_in = (const float*)d_in[1];
  const float* dt = (const float*)d_in[2];
  const float* ln_s_g = (const float*)d_in[3];
  const float* ln_s_b = (const float*)d_in[4];
  const float* conv_w = (const float*)d_in[5];
  const float* conv_b = (const float*)d_in[6];
  const float* spec_fr = (const float*)d_in[7];
  const float* spec_fi = (const float*)d_in[8];
  const float* lam_r = (const float*)d_in[9];
  const float* lam_i = (const float*)d_in[10];
  const float* E_r = (const float*)d_in[11];
  const float* E_i = (const float*)d_in[12];
  const float* Dm_r = (const float*)d_in[13];
  const float* Dm_i = (const float*)d_in[14];
  const float* ln_t_g = (const float*)d_in[15];
  const float* ln_t_b = (const float*)d_in[16];
  const float* pw1 = (const float*)d_in[17];
  const float* pb1 = (const float*)d_in[18];
  const float* pw2 = (const float*)d_in[19];
  const float* pb2 = (const float*)d_in[20];
  const float* gate = (const float*)d_in[21];

  if (ws_size < 6ull * ND_ * 4ull) return;  // need 96 MB f32 scratch

  float* ws = (float*)d_ws;
  float* znr = ws;                 // -> becomes x_re after K5
  float* zni = ws + ND_;           // -> becomes x_im after K5
  float* clr = ws + 2 * ND_;
  float* cli = ws + 3 * ND_;
  float* fqr = ws + 4 * ND_;
  float* fqi = ws + 5 * ND_;
  float* out = (float*)d_out;
  // pre-K3 scratch aliases (consumed by K2 before K3/K4 overwrite them)
  unsigned short* znb = (unsigned short*)fqr;  // zn bf16 [tok][64], exactly ND_*4 B
  unsigned short* wb = (unsigned short*)fqi;   // conv_w bf16 [kk][oc][ic], 73 KB
  // post-K5 scratch aliases (fqr plane is dead after K5)
  unsigned short* pwb1 = (unsigned short*)fqr;       // pool w1 bf16, 32 KB
  unsigned short* pwb2 = pwb1 + 16384;               // pool w2 bf16 [ec][oc][el], 32 KB

  k0_prepw<<<144, 256, 0, stream>>>(conv_w, wb);
  k1_cnorm_spatial<<<512, 256, 0, stream>>>(xr_in, xi_in, ln_s_g, ln_s_b, znr, zni, znb);
  k2_conv<<<dim3(64, 32), 256, 0, stream>>>(znb, wb, conv_b, clr, cli);
  k3_dftw<<<dim3(64, 32), 256, 0, stream>>>(znr, zni, fqr, fqi);
  k4_dfth<<<dim3(64, 32), 256, 0, stream>>>(fqr, fqi, spec_fr, spec_fi);
  k5_idftw_combine<<<dim3(64, 32), 256, 0, stream>>>(fqr, fqi, clr, cli, xr_in, xi_in,
                                                     gate, znr, zni);
  k8_pool_prepw<<<128, 256, 0, stream>>>(pw1, pw2, pwb1, pwb2);
  k6_temporal<<<1024, 256, 0, stream>>>(znr, zni, lam_r, lam_i, E_r, E_i, Dm_r, Dm_i,
                                        ln_t_g, ln_t_b, dt);
  k7_pool<<<2048, 256, 0, stream>>>(znr, zni, pwb1, pb1, pwb2, pb2, out, (long long)out_size);
}

// Round 5
// 374.584 us; speedup vs baseline: 1.9379x; 1.0952x over previous
//
#include <hip/hip_runtime.h>
#include <cstddef>

// UniPhyBlock on gfx950 — f32 inputs, f32 internal pipeline, F32 PLANAR OUTPUT.
// Round 16: k4_dfth rewritten as bf16-MFMA complex GEMM (was 78us VALU-issue
// bound direct DFT: VALUBusy=70%, MfmaUtil=0, 2048 FMA/thread/pass).
// DFT-H = matmul: Out[kh][d] = sum_hh T[kh][hh] X[hh][d], K=64. Packed re/im
// as 64 N-cols; P1=Tr*X, P2=Ti*X; combine in epilogue (conj + 1/64 for the
// inverse pass). X staged transposed hi/lo bf16 (f32-accurate); twiddles
// single bf16 (~0.2%/pass systematic, gate-weighted -> ~5e-3 abs, within
// budget). Twiddle tables generated in-LDS per block. k3/k5 unchanged (port
// next round). Everything else identical to round 15.
// Output: PLANAR f32 — out[cidx]=real, out[ND+cidx]=imag, cidx over [B,T,D,H,W].
// ws (f32): [0]=zn_re (later x_re), [1]=zn_im (later x_im), [2]=cliff_re,
//           [3]=cliff_im, [4]=freq_re (pre-K3: zn bf16; post-K5: pool w bf16),
//           [5]=freq_im (pre-K3: conv_w bf16 [kk][oc][ic])  -> 96 MB.

#define EPS_ 1e-5f
#define PI_  3.14159265358979323846f
#define ND_  4194304ull
#define DST_ 36   // padded DFT row stride (f32 words) for k3/k5

typedef __attribute__((ext_vector_type(8))) short bf16x8;   // 8 bf16 (4 VGPRs)
typedef __attribute__((ext_vector_type(4))) float f32x4;    // MFMA C/D

__device__ __forceinline__ short f2bf(float f) {
  unsigned u = __float_as_uint(f);
  unsigned r = (u + 0x7fffu + ((u >> 16) & 1u)) >> 16;  // RNE
  return (short)r;
}
__device__ __forceinline__ float bf2f(short h) {
  return __uint_as_float(((unsigned)(unsigned short)h) << 16);
}

// ---------------- K0: one-time conv weight transpose+convert ----------------
// wgt [kk][ic][oc] f32 -> wb [kk][oc][ic] bf16 (36864 elems)
__global__ __launch_bounds__(256) void k0_prepw(
    const float* __restrict__ wgt, unsigned short* __restrict__ wb) {
  int j = blockIdx.x * 256 + threadIdx.x;   // grid 144*256 = 36864
  int kk = j >> 12;
  int rem = j & 4095;
  int oc = rem >> 6;
  int ic = rem & 63;
  wb[j] = (unsigned short)f2bf(wgt[((size_t)kk * 64 + ic) * 64 + oc]);
}

// ---------------- K8: one-time pool weight convert (runs after K5) ----------------
__global__ __launch_bounds__(256) void k8_pool_prepw(
    const float* __restrict__ pw1, const float* __restrict__ pw2,
    unsigned short* __restrict__ pwb1, unsigned short* __restrict__ pwb2) {
  int j = blockIdx.x * 256 + threadIdx.x;   // grid 128*256 = 32768
  if (j < 16384) {
    pwb1[j] = (unsigned short)f2bf(pw1[j]);
  } else {
    int j2 = j - 16384;
    int ec = j2 >> 12;
    int rem = j2 & 4095;
    int oc = rem >> 6;
    int el = rem & 63;
    pwb2[j2] = (unsigned short)f2bf(pw2[(size_t)oc * 256 + ec * 64 + el]);
  }
}

// ---------------- K1: input transpose + spatial cnorm (+ bf16 zn copy) ----------------
__global__ __launch_bounds__(256) void k1_cnorm_spatial(
    const float* __restrict__ xr, const float* __restrict__ xi,
    const float* __restrict__ g, const float* __restrict__ b,
    float* __restrict__ znr, float* __restrict__ zni,
    unsigned short* __restrict__ znb) {
  int tok = blockIdx.x * 256 + threadIdx.x;      // (bt,h,w)
  int bt = tok >> 12;
  int hw = tok & 4095;
  const float* pr = xr + (size_t)bt * 131072 + hw;   // bt*D*HW
  const float* pi = xi + (size_t)bt * 131072 + hw;
  float r[32], q[32];
  float s = 0.f;
#pragma unroll
  for (int d = 0; d < 32; d++) {
    r[d] = pr[(size_t)d * 4096];
    q[d] = pi[(size_t)d * 4096];
    s += r[d] + q[d];
  }
  float mu = s * 0.015625f;
  float v = 0.f;
#pragma unroll
  for (int d = 0; d < 32; d++) {
    float a = r[d] - mu, c = q[d] - mu;
    v += a * a + c * c;
  }
  float rstd = rsqrtf(v * 0.015625f + EPS_);
#pragma unroll
  for (int d = 0; d < 32; d++) {
    r[d] = (r[d] - mu) * rstd * g[d] + b[d];
    q[d] = (q[d] - mu) * rstd * g[32 + d] + b[32 + d];
  }
  float4* outr = (float4*)(znr + (size_t)tok * 32);
  float4* outi = (float4*)(zni + (size_t)tok * 32);
#pragma unroll
  for (int j = 0; j < 8; j++) {
    outr[j] = make_float4(r[4 * j], r[4 * j + 1], r[4 * j + 2], r[4 * j + 3]);
    outi[j] = make_float4(q[4 * j], q[4 * j + 1], q[4 * j + 2], q[4 * j + 3]);
  }
  // bf16 copy [tok][64]: ch 0..31 = re, 32..63 = im (same values k2 used before)
  short* zb = (short*)(znb + (size_t)tok * 64);
#pragma unroll
  for (int j = 0; j < 4; j++) {
    bf16x8 vr, vq;
#pragma unroll
    for (int k = 0; k < 8; k++) {
      vr[k] = f2bf(r[8 * j + k]);
      vq[k] = f2bf(q[8 * j + k]);
    }
    *(bf16x8*)(zb + 8 * j) = vr;
    *(bf16x8*)(zb + 32 + 8 * j) = vq;
  }
}

// ---------------- K2: 3x3 SAME conv via bf16 MFMA implicit GEMM ----------------
__global__ __launch_bounds__(256) void k2_conv(
    const unsigned short* __restrict__ znb, const unsigned short* __restrict__ wb,
    const float* __restrict__ bias,
    float* __restrict__ clr, float* __restrict__ cli) {
  __shared__ __align__(16) short sA[3 * 66 * 88];   // 34.8 KB
  __shared__ __align__(16) short sW[2][64 * 72];    // 18.4 KB
  int h = blockIdx.x, bt = blockIdx.y;
  // stage activations (3 rows, w in [-1,64], 64 ch) as ushort8 copies
  for (int v = threadIdx.x; v < 1584; v += 256) {   // 198 rows * 8 vecs
    int c0 = (v & 7) * 8;
    int row = v >> 3;           // 0..197 = rr*66 + wp
    int wp = row % 66;
    int rr = row / 66;
    int hh = h + rr - 1;
    int w = wp - 1;
    bf16x8 val = {0, 0, 0, 0, 0, 0, 0, 0};
    if ((unsigned)hh < 64u && (unsigned)w < 64u) {
      int tok = (bt * 64 + hh) * 64 + w;
      val = *(const bf16x8*)(znb + (size_t)tok * 64 + c0);
    }
    *(bf16x8*)(&sA[(rr * 66 + wp) * 88 + c0]) = val;
  }
  // stage weight chunk 0 into buffer 0
  for (int v = threadIdx.x; v < 512; v += 256) {
    int oc = v >> 3, ic0 = (v & 7) * 8;
    *(bf16x8*)(&sW[0][oc * 72 + ic0]) = *(const bf16x8*)(wb + v * 8);
  }
  int lane = threadIdx.x & 63;
  int wv = threadIdx.x >> 6;
  int m0 = wv * 16;          // this wave's 16-token strip
  int lr = lane & 15;        // A-row / B-col / D-col
  int quad = lane >> 4;      // k-chunk selector; D-row group
  f32x4 acc[4];
#pragma unroll
  for (int nt = 0; nt < 4; nt++) {
    float bz = bias[nt * 16 + lr];
    acc[nt][0] = bz; acc[nt][1] = bz; acc[nt][2] = bz; acc[nt][3] = bz;
  }
  __syncthreads();
  for (int kk = 0; kk < 9; kk++) {
    int cur = kk & 1;
    if (kk < 8) {  // prefetch next chunk into the other buffer
      const unsigned short* src = wb + (size_t)(kk + 1) * 4096;
      for (int v = threadIdx.x; v < 512; v += 256) {
        int oc = v >> 3, ic0 = (v & 7) * 8;
        *(bf16x8*)(&sW[cur ^ 1][oc * 72 + ic0]) = *(const bf16x8*)(src + v * 8);
      }
    }
    int kh = kk / 3, kw = kk - kh * 3;
    const short* arow = &sA[((size_t)kh * 66 + (m0 + lr + kw)) * 88 + quad * 8];
#pragma unroll
    for (int ks = 0; ks < 2; ks++) {
      bf16x8 afrag = *(const bf16x8*)(arow + ks * 32);
#pragma unroll
      for (int nt = 0; nt < 4; nt++) {
        bf16x8 bfrag = *(const bf16x8*)&sW[cur][(size_t)(nt * 16 + lr) * 72 + ks * 32 + quad * 8];
        acc[nt] = __builtin_amdgcn_mfma_f32_16x16x32_bf16(afrag, bfrag, acc[nt], 0, 0, 0);
      }
    }
    __syncthreads();  // next buf written; cur free for overwrite at kk+1
  }
  // epilogue: D[row=quad*4+reg][col=lr] per n-tile -> clr/cli (f32)
  int tokbase = (bt * 64 + h) * 64 + m0;
#pragma unroll
  for (int nt = 0; nt < 4; nt++) {
    int oc = nt * 16 + lr;
    float* dst = (oc < 32) ? (clr + oc) : (cli + (oc - 32));
#pragma unroll
    for (int reg = 0; reg < 4; reg++) {
      int m = quad * 4 + reg;
      dst[(size_t)(tokbase + m) * 32] = acc[nt][reg];
    }
  }
}

// ---------------- K3: forward DFT along W ----------------
__global__ __launch_bounds__(256) void k3_dftw(
    const float* __restrict__ znr, const float* __restrict__ zni,
    float* __restrict__ fqr, float* __restrict__ fqi) {
  __shared__ __align__(16) float sr[64 * DST_], si[64 * DST_];
  __shared__ float twr[64], twi[64];
  int h = blockIdx.x, bt = blockIdx.y;
  size_t base = (size_t)((bt * 64 + h) * 64) * 32;
  if (threadIdx.x < 64) {
    float ang = -2.f * PI_ * (float)threadIdx.x * (1.f / 64.f);
    twr[threadIdx.x] = cosf(ang);
    twi[threadIdx.x] = sinf(ang);
  }
  for (int i = threadIdx.x; i < 2048; i += 256) {
    int row = i >> 5, col = i & 31;
    sr[row * DST_ + col] = znr[base + i];
    si[row * DST_ + col] = zni[base + i];
  }
  __syncthreads();
  int k = threadIdx.x & 63;
  int dbase = (threadIdx.x >> 6) * 8;
  float ar[8] = {0, 0, 0, 0, 0, 0, 0, 0}, ai[8] = {0, 0, 0, 0, 0, 0, 0, 0};
  for (int w = 0; w < 64; w++) {
    int idx = (w * k) & 63;
    float tr = twr[idx], ti = twi[idx];
    const float4* pr4 = (const float4*)&sr[w * DST_ + dbase];
    const float4* pi4 = (const float4*)&si[w * DST_ + dbase];
    float4 a0 = pr4[0], a1 = pr4[1], b0 = pi4[0], b1 = pi4[1];
    float rr[8] = {a0.x, a0.y, a0.z, a0.w, a1.x, a1.y, a1.z, a1.w};
    float ii[8] = {b0.x, b0.y, b0.z, b0.w, b1.x, b1.y, b1.z, b1.w};
#pragma unroll
    for (int j = 0; j < 8; j++) {
      ar[j] += rr[j] * tr - ii[j] * ti;
      ai[j] += rr[j] * ti + ii[j] * tr;
    }
  }
  __syncthreads();
#pragma unroll
  for (int j = 0; j < 8; j++) {
    sr[k * DST_ + dbase + j] = ar[j];
    si[k * DST_ + dbase + j] = ai[j];
  }
  __syncthreads();
  for (int i = threadIdx.x; i < 2048; i += 256) {
    int row = i >> 5, col = i & 31;
    fqr[base + i] = sr[row * DST_ + col];
    fqi[base + i] = si[row * DST_ + col];
  }
}

// ---------------- K4: fwd DFT along H, * filt, inv DFT along H via bf16 MFMA ----------------
// Block = (kw, bt). GEMM: Out[kh][dcol] = sum_hh T[kh][hh] * X[hh][dcol],
// dcol in [0,64): 0-31 = re(d), 32-63 = im(d). P1 = Tr*X, P2 = Ti*X.
// Pass 1 (fwd):  Or = P1r - P2i, Oi = P1i + P2r; * filt; write F^T to sX.
// Pass 2 (inv):  Or = P1r + P2i, Oi = P1i - P2r; * 1/64; write global.
// X/F staged transposed [dcol][hh] as hi/lo bf16 (stride 72); twiddles single
// bf16 [kh][hh]. 4 waves x 4 n-tiles; 32 MFMA/wave/pass.
__global__ __launch_bounds__(256) void k4_dfth(
    float* __restrict__ fqr, float* __restrict__ fqi,
    const float* __restrict__ flr, const float* __restrict__ fli) {
  __shared__ __align__(16) short sXh[64 * 72];    // X^T / F^T hi  9.2 KB
  __shared__ __align__(16) short sXl[64 * 72];    // lo            9.2 KB
  __shared__ __align__(16) short sT[2][64 * 72];  // [0]=Tr,[1]=Ti 18.4 KB
  __shared__ float twr[64], twi[64];
  int kw = blockIdx.x, bt = blockIdx.y;
  if (threadIdx.x < 64) {
    float ang = -2.f * PI_ * (float)threadIdx.x * (1.f / 64.f);
    twr[threadIdx.x] = cosf(ang);
    twi[threadIdx.x] = sinf(ang);
  }
  // stage X^T hi/lo (global loads issued early; independent of twr)
  for (int i = threadIdx.x; i < 2048; i += 256) {
    int hh = i >> 5, d = i & 31;
    size_t ga = (size_t)((bt * 64 + hh) * 64 + kw) * 32 + d;
    float vr = fqr[ga], vi = fqi[ga];
    short rh = f2bf(vr), ih = f2bf(vi);
    sXh[d * 72 + hh] = rh;
    sXl[d * 72 + hh] = f2bf(vr - bf2f(rh));
    sXh[(d + 32) * 72 + hh] = ih;
    sXl[(d + 32) * 72 + hh] = f2bf(vi - bf2f(ih));
  }
  __syncthreads();  // twr/twi ready
  // twiddle tables T[kh][hh] = tw[(kh*hh)&63]
  for (int i = threadIdx.x; i < 4096; i += 256) {
    int kh = i >> 6, hh = i & 63;
    int idx = (kh * hh) & 63;
    sT[0][kh * 72 + hh] = f2bf(twr[idx]);
    sT[1][kh * 72 + hh] = f2bf(twi[idx]);
  }
  __syncthreads();  // sT + sX ready
  int lane = threadIdx.x & 63;
  int wv = threadIdx.x >> 6;
  int m0 = wv * 16;
  int lr = lane & 15;
  int quad = lane >> 4;
  const short* a_r = &sT[0][(size_t)(m0 + lr) * 72 + quad * 8];
  const short* a_i = &sT[1][(size_t)(m0 + lr) * 72 + quad * 8];
  f32x4 p1[4], p2[4];
#pragma unroll
  for (int nt = 0; nt < 4; nt++) {
    p1[nt][0] = 0.f; p1[nt][1] = 0.f; p1[nt][2] = 0.f; p1[nt][3] = 0.f;
    p2[nt][0] = 0.f; p2[nt][1] = 0.f; p2[nt][2] = 0.f; p2[nt][3] = 0.f;
  }
  // ---- pass 1 MFMAs ----
#pragma unroll
  for (int ks = 0; ks < 2; ks++) {
    bf16x8 tr = *(const bf16x8*)(a_r + ks * 32);
    bf16x8 ti = *(const bf16x8*)(a_i + ks * 32);
#pragma unroll
    for (int nt = 0; nt < 4; nt++) {
      bf16x8 xh = *(const bf16x8*)&sXh[(size_t)(nt * 16 + lr) * 72 + ks * 32 + quad * 8];
      bf16x8 xl = *(const bf16x8*)&sXl[(size_t)(nt * 16 + lr) * 72 + ks * 32 + quad * 8];
      p1[nt] = __builtin_amdgcn_mfma_f32_16x16x32_bf16(tr, xh, p1[nt], 0, 0, 0);
      p1[nt] = __builtin_amdgcn_mfma_f32_16x16x32_bf16(tr, xl, p1[nt], 0, 0, 0);
      p2[nt] = __builtin_amdgcn_mfma_f32_16x16x32_bf16(ti, xh, p2[nt], 0, 0, 0);
      p2[nt] = __builtin_amdgcn_mfma_f32_16x16x32_bf16(ti, xl, p2[nt], 0, 0, 0);
    }
  }
  __syncthreads();  // all pass-1 reads of sX done
  // ---- epilogue 1: combine, apply filter, write F^T back (hi/lo) ----
#pragma unroll
  for (int nt = 0; nt < 2; nt++) {
#pragma unroll
    for (int reg = 0; reg < 4; reg++) {
      int kh = m0 + quad * 4 + reg;
      int d = nt * 16 + lr;
      float Or = p1[nt][reg] - p2[nt + 2][reg];
      float Oi = p1[nt + 2][reg] + p2[nt][reg];
      size_t fa = (size_t)(kh * 64 + kw) * 32 + d;
      float fr = flr[fa], fi = fli[fa];
      float pr = Or * fr - Oi * fi;
      float pi = Or * fi + Oi * fr;
      short ph = f2bf(pr);
      sXh[d * 72 + kh] = ph;
      sXl[d * 72 + kh] = f2bf(pr - bf2f(ph));
      short qh = f2bf(pi);
      sXh[(d + 32) * 72 + kh] = qh;
      sXl[(d + 32) * 72 + kh] = f2bf(pi - bf2f(qh));
    }
  }
  __syncthreads();  // F ready
  // ---- pass 2 MFMAs (inverse, same T; conj handled in combine) ----
#pragma unroll
  for (int nt = 0; nt < 4; nt++) {
    p1[nt][0] = 0.f; p1[nt][1] = 0.f; p1[nt][2] = 0.f; p1[nt][3] = 0.f;
    p2[nt][0] = 0.f; p2[nt][1] = 0.f; p2[nt][2] = 0.f; p2[nt][3] = 0.f;
  }
#pragma unroll
  for (int ks = 0; ks < 2; ks++) {
    bf16x8 tr = *(const bf16x8*)(a_r + ks * 32);
    bf16x8 ti = *(const bf16x8*)(a_i + ks * 32);
#pragma unroll
    for (int nt = 0; nt < 4; nt++) {
      bf16x8 xh = *(const bf16x8*)&sXh[(size_t)(nt * 16 + lr) * 72 + ks * 32 + quad * 8];
      bf16x8 xl = *(const bf16x8*)&sXl[(size_t)(nt * 16 + lr) * 72 + ks * 32 + quad * 8];
      p1[nt] = __builtin_amdgcn_mfma_f32_16x16x32_bf16(tr, xh, p1[nt], 0, 0, 0);
      p1[nt] = __builtin_amdgcn_mfma_f32_16x16x32_bf16(tr, xl, p1[nt], 0, 0, 0);
      p2[nt] = __builtin_amdgcn_mfma_f32_16x16x32_bf16(ti, xh, p2[nt], 0, 0, 0);
      p2[nt] = __builtin_amdgcn_mfma_f32_16x16x32_bf16(ti, xl, p2[nt], 0, 0, 0);
    }
  }
  // ---- epilogue 2: conj combine, *1/64, write global ----
#pragma unroll
  for (int nt = 0; nt < 2; nt++) {
#pragma unroll
    for (int reg = 0; reg < 4; reg++) {
      int hh = m0 + quad * 4 + reg;
      int d = nt * 16 + lr;
      float Or = (p1[nt][reg] + p2[nt + 2][reg]) * 0.015625f;
      float Oi = (p1[nt + 2][reg] - p2[nt][reg]) * 0.015625f;
      size_t ga = (size_t)((bt * 64 + hh) * 64 + kw) * 32 + d;
      fqr[ga] = Or;
      fqi[ga] = Oi;
    }
  }
}

// ---------------- K5: inv DFT along W + gate combine + residual -> x ----------------
__global__ __launch_bounds__(256) void k5_idftw_combine(
    const float* __restrict__ fqr, const float* __restrict__ fqi,
    const float* __restrict__ clr, const float* __restrict__ cli,
    const float* __restrict__ xr_in, const float* __restrict__ xi_in,
    const float* __restrict__ gate,
    float* __restrict__ xr, float* __restrict__ xi) {
  __shared__ __align__(16) float sr[64 * DST_], si[64 * DST_];
  __shared__ float twr[64], twi[64];
  int h = blockIdx.x, bt = blockIdx.y;
  size_t base = (size_t)((bt * 64 + h) * 64) * 32;
  if (threadIdx.x < 64) {
    float ang = -2.f * PI_ * (float)threadIdx.x * (1.f / 64.f);
    twr[threadIdx.x] = cosf(ang);
    twi[threadIdx.x] = sinf(ang);
  }
  for (int i = threadIdx.x; i < 2048; i += 256) {
    int row = i >> 5, col = i & 31;
    sr[row * DST_ + col] = fqr[base + i];
    si[row * DST_ + col] = fqi[base + i];
  }
  __syncthreads();
  int w = threadIdx.x & 63;
  int dbase = (threadIdx.x >> 6) * 8;
  float ar[8] = {0, 0, 0, 0, 0, 0, 0, 0}, ai[8] = {0, 0, 0, 0, 0, 0, 0, 0};
  for (int kw = 0; kw < 64; kw++) {
    int idx = (w * kw) & 63;
    float tr = twr[idx], ti = -twi[idx];
    const float4* pr4 = (const float4*)&sr[kw * DST_ + dbase];
    const float4* pi4 = (const float4*)&si[kw * DST_ + dbase];
    float4 a0 = pr4[0], a1 = pr4[1], b0 = pi4[0], b1 = pi4[1];
    float rr[8] = {a0.x, a0.y, a0.z, a0.w, a1.x, a1.y, a1.z, a1.w};
    float ii[8] = {b0.x, b0.y, b0.z, b0.w, b1.x, b1.y, b1.z, b1.w};
#pragma unroll
    for (int j = 0; j < 8; j++) {
      ar[j] += rr[j] * tr - ii[j] * ti;
      ai[j] += rr[j] * ti + ii[j] * tr;
    }
  }
  float g = gate[0];
  float gi = 1.f - g;
  const float4* c4r = (const float4*)&clr[base + w * 32 + dbase];
  const float4* c4i = (const float4*)&cli[base + w * 32 + dbase];
  float4 cr0 = c4r[0], cr1 = c4r[1], ci0 = c4i[0], ci1 = c4i[1];
  float cre[8] = {cr0.x, cr0.y, cr0.z, cr0.w, cr1.x, cr1.y, cr1.z, cr1.w};
  float cim[8] = {ci0.x, ci0.y, ci0.z, ci0.w, ci1.x, ci1.y, ci1.z, ci1.w};
  float orr[8], oii[8];
#pragma unroll
  for (int j = 0; j < 8; j++) {
    int d = dbase + j;
    size_t ga = (size_t)(bt * 32 + d) * 4096 + h * 64 + w;  // input [B,T,D,H,W]
    orr[j] = g * cre[j] + gi * (ar[j] * 0.015625f) + xr_in[ga];
    oii[j] = g * cim[j] + gi * (ai[j] * 0.015625f) + xi_in[ga];
  }
  __syncthreads();
#pragma unroll
  for (int j = 0; j < 8; j++) {
    sr[w * DST_ + dbase + j] = orr[j];
    si[w * DST_ + dbase + j] = oii[j];
  }
  __syncthreads();
  for (int i = threadIdx.x; i < 2048; i += 256) {
    int row = i >> 5, col = i & 31;
    xr[base + i] = sr[row * DST_ + col];
    xi[base + i] = si[row * DST_ + col];
  }
}

// ---------------- K6: temporal cnorm + eigen encode + decay scan + decode ----------------
__global__ __launch_bounds__(256) void k6_temporal(
    float* __restrict__ xr, float* __restrict__ xi,
    const float* __restrict__ lamr, const float* __restrict__ lami,
    const float* __restrict__ Er, const float* __restrict__ Ei,
    const float* __restrict__ Dmr, const float* __restrict__ Dmi,
    const float* __restrict__ lg, const float* __restrict__ lb,
    const float* __restrict__ dtp) {
  __shared__ float sEr[1024], sEi[1024], sDr[1024], sDi[1024];
  __shared__ __align__(16) float sXr[32 * 132];  // xt^T [d][tok], later h^T
  __shared__ __align__(16) float sXi[32 * 132];
  int n0 = blockIdx.x * 8;
  for (int i = threadIdx.x; i < 1024; i += 256) {
    sEr[i] = Er[i];
    sEi[i] = Ei[i];
    sDr[i] = Dmr[i];
    sDi[i] = Dmi[i];
  }
  if (threadIdx.x < 128) {
    int sIc = threadIdx.x >> 4;
    int t = threadIdx.x & 15;
    int n = n0 + sIc;
    int bb = n >> 12;
    int hw = n & 4095;
    size_t tokb = ((size_t)(bb * 16 + t)) * 4096 + hw;
    const float4* pr = (const float4*)(xr + tokb * 32);
    const float4* pi = (const float4*)(xi + tokb * 32);
    float rv[32], iv[32];
    float s = 0.f;
#pragma unroll
    for (int j = 0; j < 8; j++) {
      float4 a = pr[j];
      float4 c = pi[j];
      rv[4 * j] = a.x; rv[4 * j + 1] = a.y; rv[4 * j + 2] = a.z; rv[4 * j + 3] = a.w;
      iv[4 * j] = c.x; iv[4 * j + 1] = c.y; iv[4 * j + 2] = c.z; iv[4 * j + 3] = c.w;
      s += a.x + a.y + a.z + a.w + c.x + c.y + c.z + c.w;
    }
    float mu = s * 0.015625f;
    float v = 0.f;
#pragma unroll
    for (int d = 0; d < 32; d++) {
      float a = rv[d] - mu, c = iv[d] - mu;
      v += a * a + c * c;
    }
    float rstd = rsqrtf(v * 0.015625f + EPS_);
    int col = threadIdx.x;   // sIc*16 + t
#pragma unroll
    for (int d = 0; d < 32; d++) {
      sXr[d * 132 + col] = (rv[d] - mu) * rstd * lg[d] + lb[d];
      sXi[d * 132 + col] = (iv[d] - mu) * rstd * lg[32 + d] + lb[32 + d];
    }
  }
  __syncthreads();
  int sI = threadIdx.x >> 5;
  int e = threadIdx.x & 31;
  int tok0 = sI * 16;
  float dts = dtp[0];
  float lr = lamr[e], li = lami[e];
  float ex = expf(lr * dts);
  float dcr = ex * cosf(li * dts);
  float dci = ex * sinf(li * dts);
  float nr = dcr - 1.f, ni = dci;
  float invden = 1.f / (lr * lr + li * li);
  float fr = (nr * lr + ni * li) * invden;
  float fi = (ni * lr - nr * li) * invden;
  // ---- encode ----
  float xer[16], xei[16];
#pragma unroll
  for (int t = 0; t < 16; t++) { xer[t] = 0.f; xei[t] = 0.f; }
  for (int d = 0; d < 32; d++) {
    float er_ = sEr[d * 32 + e], ei_ = sEi[d * 32 + e];
    const float4* rb = (const float4*)&sXr[d * 132 + tok0];
    const float4* ib = (const float4*)&sXi[d * 132 + tok0];
#pragma unroll
    for (int j = 0; j < 4; j++) {
      float4 a4 = rb[j], c4 = ib[j];
      float av[4] = {a4.x, a4.y, a4.z, a4.w};
      float cv[4] = {c4.x, c4.y, c4.z, c4.w};
#pragma unroll
      for (int k = 0; k < 4; k++) {
        int t = 4 * j + k;
        xer[t] += av[k] * er_ - cv[k] * ei_;
        xei[t] += av[k] * ei_ + cv[k] * er_;
      }
    }
  }
  // ---- scan in registers ----
  float hr = 0.f, hi = 0.f;
#pragma unroll
  for (int t = 0; t < 16; t++) {
    float ur = xer[t] * fr - xei[t] * fi;
    float ui = xer[t] * fi + xei[t] * fr;
    float t1 = dcr * hr - dci * hi + ur;
    hi = dcr * hi + dci * hr + ui;
    hr = t1;
    sXr[e * 132 + tok0 + t] = hr;
    sXi[e * 132 + tok0 + t] = hi;
  }
  __syncthreads();
  // ---- decode ----
  float oacc[16];
#pragma unroll
  for (int t = 0; t < 16; t++) oacc[t] = 0.f;
  for (int d = 0; d < 32; d++) {
    float dr_ = sDr[d * 32 + e], di_ = sDi[d * 32 + e];
    const float4* rb = (const float4*)&sXr[d * 132 + tok0];
    const float4* ib = (const float4*)&sXi[d * 132 + tok0];
#pragma unroll
    for (int j = 0; j < 4; j++) {
      float4 a4 = rb[j], c4 = ib[j];
      float av[4] = {a4.x, a4.y, a4.z, a4.w};
      float cv[4] = {c4.x, c4.y, c4.z, c4.w};
#pragma unroll
      for (int k = 0; k < 4; k++) {
        int t = 4 * j + k;
        oacc[t] += av[k] * dr_ - cv[k] * di_;
      }
    }
  }
  int n = n0 + sI;
  int bb = n >> 12;
  int hw = n & 4095;
#pragma unroll
  for (int t = 0; t < 16; t++) {
    size_t tokb = ((size_t)(bb * 16 + t)) * 4096 + hw;
    xr[tokb * 32 + e] += oacc[t];  // drift is real-only
  }
}

// ---------------- K7: para pool MLP via bf16 MFMA + residual + output (F32 PLANAR) ----------------
__global__ __launch_bounds__(256) void k7_pool(
    const float* __restrict__ xr, const float* __restrict__ xi,
    const unsigned short* __restrict__ pwb1, const float* __restrict__ pb1,
    const unsigned short* __restrict__ pwb2, const float* __restrict__ pb2,
    float* __restrict__ out, long long out_n) {
  __shared__ __align__(16) short sXh[64 * 72];  // xp hi bf16 [tok][c]   9.2 KB
  __shared__ __align__(16) short sXl[64 * 72];  // xp lo bf16            9.2 KB
  __shared__ __align__(16) short sW[64 * 72];   // weight chunk [n][k]   9.2 KB
  __shared__ __align__(16) float sH[64 * 68];   // hidden f32 [tok][el] 17.4 KB
  int tok0 = blockIdx.x * 64;
  // stage xp as hi/lo bf16 pair: x = hi + lo to ~16 mantissa bits
  for (int i = threadIdx.x; i < 4096; i += 256) {
    int t = i >> 6, c = i & 63;
    float v = (c < 32) ? xr[(size_t)(tok0 + t) * 32 + c]
                       : xi[(size_t)(tok0 + t) * 32 + c - 32];
    short hb = f2bf(v);
    sXh[t * 72 + c] = hb;
    sXl[t * 72 + c] = f2bf(v - bf2f(hb));
  }
  int lane = threadIdx.x & 63;
  int wv = threadIdx.x >> 6;
  int lr = lane & 15;
  int quad = lane >> 4;
  int m0 = wv * 16;          // this wave's 16-token strip
  f32x4 acc2[4];             // persistent GEMM2 accumulator, bias preloaded
#pragma unroll
  for (int nt = 0; nt < 4; nt++) {
    float bz = pb2[nt * 16 + lr];
    acc2[nt][0] = bz; acc2[nt][1] = bz; acc2[nt][2] = bz; acc2[nt][3] = bz;
  }
  for (int ec = 0; ec < 4; ec++) {
    __syncthreads();  // prev GEMM2 done with sW/sH; xp staged (ec=0)
    // stage w1 chunk: sW[el][c] = pwb1[ec*4096 + el*64 + c] (ushort8 copies)
    {
      const unsigned short* src = pwb1 + (size_t)ec * 4096;
      for (int v = threadIdx.x; v < 512; v += 256) {
        int el = v >> 3, c0 = (v & 7) * 8;
        *(bf16x8*)(&sW[el * 72 + c0]) = *(const bf16x8*)(src + v * 8);
      }
    }
    __syncthreads();
    f32x4 acc1[4];
#pragma unroll
    for (int nt = 0; nt < 4; nt++) {
      float bz = pb1[ec * 64 + nt * 16 + lr];
      acc1[nt][0] = bz; acc1[nt][1] = bz; acc1[nt][2] = bz; acc1[nt][3] = bz;
    }
    const short* arh = &sXh[(size_t)(m0 + lr) * 72 + quad * 8];
    const short* arl = &sXl[(size_t)(m0 + lr) * 72 + quad * 8];
#pragma unroll
    for (int ks = 0; ks < 2; ks++) {
      bf16x8 ah = *(const bf16x8*)(arh + ks * 32);
      bf16x8 al = *(const bf16x8*)(arl + ks * 32);
#pragma unroll
      for (int nt = 0; nt < 4; nt++) {
        bf16x8 bfrag = *(const bf16x8*)&sW[(size_t)(nt * 16 + lr) * 72 + ks * 32 + quad * 8];
        acc1[nt] = __builtin_amdgcn_mfma_f32_16x16x32_bf16(ah, bfrag, acc1[nt], 0, 0, 0);
        acc1[nt] = __builtin_amdgcn_mfma_f32_16x16x32_bf16(al, bfrag, acc1[nt], 0, 0, 0);
      }
    }
    // gelu (tanh approx, jax default) -> sH[tok][e_local] (f32, 2-way banks = free)
#pragma unroll
    for (int nt = 0; nt < 4; nt++) {
#pragma unroll
      for (int reg = 0; reg < 4; reg++) {
        float x = acc1[nt][reg];
        float u = 0.7978845608f * (x + 0.044715f * x * x * x);
        float e2 = __expf(2.f * u);
        float th = 1.f - 2.f / (e2 + 1.f);
        sH[(m0 + quad * 4 + reg) * 68 + nt * 16 + lr] = 0.5f * x * (1.f + th);
      }
    }
    __syncthreads();  // GEMM1 reads of sW done, sH writes done
    // stage w2 chunk: sW[oc][el] = pwb2[ec*4096 + oc*64 + el] (ushort8 copies)
    {
      const unsigned short* src = pwb2 + (size_t)ec * 4096;
      for (int v = threadIdx.x; v < 512; v += 256) {
        int oc = v >> 3, el0 = (v & 7) * 8;
        *(bf16x8*)(&sW[oc * 72 + el0]) = *(const bf16x8*)(src + v * 8);
      }
    }
    __syncthreads();
    // GEMM2: A = gelu(hidden) converted bf16 on the fly, accumulate into acc2
    const float* hrow = &sH[(size_t)(m0 + lr) * 68 + quad * 8];
#pragma unroll
    for (int ks = 0; ks < 2; ks++) {
      float4 h0 = *(const float4*)(hrow + ks * 32);
      float4 h1 = *(const float4*)(hrow + ks * 32 + 4);
      bf16x8 af;
      af[0] = f2bf(h0.x); af[1] = f2bf(h0.y); af[2] = f2bf(h0.z); af[3] = f2bf(h0.w);
      af[4] = f2bf(h1.x); af[5] = f2bf(h1.y); af[6] = f2bf(h1.z); af[7] = f2bf(h1.w);
#pragma unroll
      for (int nt = 0; nt < 4; nt++) {
        bf16x8 bfrag = *(const bf16x8*)&sW[(size_t)(nt * 16 + lr) * 72 + ks * 32 + quad * 8];
        acc2[nt] = __builtin_amdgcn_mfma_f32_16x16x32_bf16(af, bfrag, acc2[nt], 0, 0, 0);
      }
    }
  }
  // epilogue: D[row=quad*4+reg][col=lr] -> + residual -> planar f32 out
#pragma unroll
  for (int nt = 0; nt < 4; nt++) {
    int oc = nt * 16 + lr;
#pragma unroll
    for (int reg = 0; reg < 4; reg++) {
      int t = tok0 + m0 + quad * 4 + reg;
      float resid = (oc < 32) ? xr[(size_t)t * 32 + oc] : xi[(size_t)t * 32 + oc - 32];
      float val = acc2[nt][reg] + resid;
      int bt = t >> 12;
      int hw = t & 4095;
      int d = (oc < 32) ? oc : oc - 32;
      size_t cidx = (size_t)(bt * 32 + d) * 4096 + hw;  // [B,T,D,H,W] index
      long long pos = (long long)cidx + ((oc < 32) ? 0ll : (long long)ND_);
      if (pos < out_n) out[pos] = val;
    }
  }
}

// ---------------- launch ----------------
extern "C" void kernel_launch(void* const* d_in, const int* in_sizes, int n_in,
                              void* d_out, int out_size, void* d_ws, size_t ws_size,
                              hipStream_t stream) {
  (void)in_sizes; (void)n_in;
  const float* xr_in = (const float*)d_in[0];
  const float* xi_in = (const float*)d_in[1];
  const float* dt = (const float*)d_in[2];
  const float* ln_s_g = (const float*)d_in[3];
  const float* ln_s_b = (const float*)d_in[4];
  const float* conv_w = (const float*)d_in[5];
  const float* conv_b = (const float*)d_in[6];
  const float* spec_fr = (const float*)d_in[7];
  const float* spec_fi = (const float*)d_in[8];
  const float* lam_r = (const float*)d_in[9];
  const float* lam_i = (const float*)d_in[10];
  const float* E_r = (const float*)d_in[11];
  const float* E_i = (const float*)d_in[12];
  const float* Dm_r = (const float*)d_in[13];
  const float* Dm_i = (const float*)d_in[14];
  const float* ln_t_g = (const float*)d_in[15];
  const float* ln_t_b = (const float*)d_in[16];
  const float* pw1 = (const float*)d_in[17];
  const float* pb1 = (const float*)d_in[18];
  const float* pw2 = (const float*)d_in[19];
  const float* pb2 = (const float*)d_in[20];
  const float* gate = (const float*)d_in[21];

  if (ws_size < 6ull * ND_ * 4ull) return;  // need 96 MB f32 scratch

  float* ws = (float*)d_ws;
  float* znr = ws;                 // -> becomes x_re after K5
  float* zni = ws + ND_;           // -> becomes x_im after K5
  float* clr = ws + 2 * ND_;
  float* cli = ws + 3 * ND_;
  float* fqr = ws + 4 * ND_;
  float* fqi = ws + 5 * ND_;
  float* out = (float*)d_out;
  // pre-K3 scratch aliases (consumed by K2 before K3/K4 overwrite them)
  unsigned short* znb = (unsigned short*)fqr;  // zn bf16 [tok][64], exactly ND_*4 B
  unsigned short* wb = (unsigned short*)fqi;   // conv_w bf16 [kk][oc][ic], 73 KB
  // post-K5 scratch aliases (fqr plane is dead after K5)
  unsigned short* pwb1 = (unsigned short*)fqr;       // pool w1 bf16, 32 KB
  unsigned short* pwb2 = pwb1 + 16384;               // pool w2 bf16 [ec][oc][el], 32 KB

  k0_prepw<<<144, 256, 0, stream>>>(conv_w, wb);
  k1_cnorm_spatial<<<512, 256, 0, stream>>>(xr_in, xi_in, ln_s_g, ln_s_b, znr, zni, znb);
  k2_conv<<<dim3(64, 32), 256, 0, stream>>>(znb, wb, conv_b, clr, cli);
  k3_dftw<<<dim3(64, 32), 256, 0, stream>>>(znr, zni, fqr, fqi);
  k4_dfth<<<dim3(64, 32), 256, 0, stream>>>(fqr, fqi, spec_fr, spec_fi);
  k5_idftw_combine<<<dim3(64, 32), 256, 0, stream>>>(fqr, fqi, clr, cli, xr_in, xi_in,
                                                     gate, znr, zni);
  k8_pool_prepw<<<128, 256, 0, stream>>>(pw1, pw2, pwb1, pwb2);
  k6_temporal<<<1024, 256, 0, stream>>>(znr, zni, lam_r, lam_i, E_r, E_i, Dm_r, Dm_i,
                                        ln_t_g, ln_t_b, dt);
  k7_pool<<<2048, 256, 0, stream>>>(znr, zni, pwb1, pb1, pwb2, pb2, out, (long long)out_size);
}

// Round 6
// 328.643 us; speedup vs baseline: 2.2087x; 1.1398x over previous
//
#include <hip/hip_runtime.h>
#include <cstddef>

// UniPhyBlock on gfx950 — f32 inputs, f32 internal pipeline, F32 PLANAR OUTPUT.
// Round 17: (a) k3/k5 ported to the k4 bf16-MFMA DFT-GEMM template (were
// VALU-issue-bound direct DFTs); k5 keeps gate/cliff/residual in its epilogue.
// (b) k7 hidden layer now written to LDS directly as bf16 [tok][el] (was f32
// round-trip + re-convert: deletes 64 f2bf/thread, LDS 45->37KB -> 4 blk/CU).
// k7 numerics bit-identical; k3/k5 follow k4's verified precision pattern
// (hi/lo bf16 activations ~f32, single-bf16 twiddles).
// Output: PLANAR f32 — out[cidx]=real, out[ND+cidx]=imag, cidx over [B,T,D,H,W].
// ws (f32): [0]=zn_re (later x_re), [1]=zn_im (later x_im), [2]=cliff_re,
//           [3]=cliff_im, [4]=freq_re (pre-K3: zn bf16; post-K5: pool w bf16),
//           [5]=freq_im (pre-K3: conv_w bf16 [kk][oc][ic])  -> 96 MB.

#define EPS_ 1e-5f
#define PI_  3.14159265358979323846f
#define ND_  4194304ull

typedef __attribute__((ext_vector_type(8))) short bf16x8;   // 8 bf16 (4 VGPRs)
typedef __attribute__((ext_vector_type(4))) float f32x4;    // MFMA C/D

__device__ __forceinline__ short f2bf(float f) {
  unsigned u = __float_as_uint(f);
  unsigned r = (u + 0x7fffu + ((u >> 16) & 1u)) >> 16;  // RNE
  return (short)r;
}
__device__ __forceinline__ float bf2f(short h) {
  return __uint_as_float(((unsigned)(unsigned short)h) << 16);
}

// ---------------- K0: one-time conv weight transpose+convert ----------------
// wgt [kk][ic][oc] f32 -> wb [kk][oc][ic] bf16 (36864 elems)
__global__ __launch_bounds__(256) void k0_prepw(
    const float* __restrict__ wgt, unsigned short* __restrict__ wb) {
  int j = blockIdx.x * 256 + threadIdx.x;   // grid 144*256 = 36864
  int kk = j >> 12;
  int rem = j & 4095;
  int oc = rem >> 6;
  int ic = rem & 63;
  wb[j] = (unsigned short)f2bf(wgt[((size_t)kk * 64 + ic) * 64 + oc]);
}

// ---------------- K8: one-time pool weight convert (runs after K5) ----------------
__global__ __launch_bounds__(256) void k8_pool_prepw(
    const float* __restrict__ pw1, const float* __restrict__ pw2,
    unsigned short* __restrict__ pwb1, unsigned short* __restrict__ pwb2) {
  int j = blockIdx.x * 256 + threadIdx.x;   // grid 128*256 = 32768
  if (j < 16384) {
    pwb1[j] = (unsigned short)f2bf(pw1[j]);
  } else {
    int j2 = j - 16384;
    int ec = j2 >> 12;
    int rem = j2 & 4095;
    int oc = rem >> 6;
    int el = rem & 63;
    pwb2[j2] = (unsigned short)f2bf(pw2[(size_t)oc * 256 + ec * 64 + el]);
  }
}

// ---------------- K1: input transpose + spatial cnorm (+ bf16 zn copy) ----------------
__global__ __launch_bounds__(256) void k1_cnorm_spatial(
    const float* __restrict__ xr, const float* __restrict__ xi,
    const float* __restrict__ g, const float* __restrict__ b,
    float* __restrict__ znr, float* __restrict__ zni,
    unsigned short* __restrict__ znb) {
  int tok = blockIdx.x * 256 + threadIdx.x;      // (bt,h,w)
  int bt = tok >> 12;
  int hw = tok & 4095;
  const float* pr = xr + (size_t)bt * 131072 + hw;   // bt*D*HW
  const float* pi = xi + (size_t)bt * 131072 + hw;
  float r[32], q[32];
  float s = 0.f;
#pragma unroll
  for (int d = 0; d < 32; d++) {
    r[d] = pr[(size_t)d * 4096];
    q[d] = pi[(size_t)d * 4096];
    s += r[d] + q[d];
  }
  float mu = s * 0.015625f;
  float v = 0.f;
#pragma unroll
  for (int d = 0; d < 32; d++) {
    float a = r[d] - mu, c = q[d] - mu;
    v += a * a + c * c;
  }
  float rstd = rsqrtf(v * 0.015625f + EPS_);
#pragma unroll
  for (int d = 0; d < 32; d++) {
    r[d] = (r[d] - mu) * rstd * g[d] + b[d];
    q[d] = (q[d] - mu) * rstd * g[32 + d] + b[32 + d];
  }
  float4* outr = (float4*)(znr + (size_t)tok * 32);
  float4* outi = (float4*)(zni + (size_t)tok * 32);
#pragma unroll
  for (int j = 0; j < 8; j++) {
    outr[j] = make_float4(r[4 * j], r[4 * j + 1], r[4 * j + 2], r[4 * j + 3]);
    outi[j] = make_float4(q[4 * j], q[4 * j + 1], q[4 * j + 2], q[4 * j + 3]);
  }
  // bf16 copy [tok][64]: ch 0..31 = re, 32..63 = im
  short* zb = (short*)(znb + (size_t)tok * 64);
#pragma unroll
  for (int j = 0; j < 4; j++) {
    bf16x8 vr, vq;
#pragma unroll
    for (int k = 0; k < 8; k++) {
      vr[k] = f2bf(r[8 * j + k]);
      vq[k] = f2bf(q[8 * j + k]);
    }
    *(bf16x8*)(zb + 8 * j) = vr;
    *(bf16x8*)(zb + 32 + 8 * j) = vq;
  }
}

// ---------------- K2: 3x3 SAME conv via bf16 MFMA implicit GEMM ----------------
__global__ __launch_bounds__(256) void k2_conv(
    const unsigned short* __restrict__ znb, const unsigned short* __restrict__ wb,
    const float* __restrict__ bias,
    float* __restrict__ clr, float* __restrict__ cli) {
  __shared__ __align__(16) short sA[3 * 66 * 88];   // 34.8 KB
  __shared__ __align__(16) short sW[2][64 * 72];    // 18.4 KB
  int h = blockIdx.x, bt = blockIdx.y;
  for (int v = threadIdx.x; v < 1584; v += 256) {   // 198 rows * 8 vecs
    int c0 = (v & 7) * 8;
    int row = v >> 3;           // 0..197 = rr*66 + wp
    int wp = row % 66;
    int rr = row / 66;
    int hh = h + rr - 1;
    int w = wp - 1;
    bf16x8 val = {0, 0, 0, 0, 0, 0, 0, 0};
    if ((unsigned)hh < 64u && (unsigned)w < 64u) {
      int tok = (bt * 64 + hh) * 64 + w;
      val = *(const bf16x8*)(znb + (size_t)tok * 64 + c0);
    }
    *(bf16x8*)(&sA[(rr * 66 + wp) * 88 + c0]) = val;
  }
  for (int v = threadIdx.x; v < 512; v += 256) {
    int oc = v >> 3, ic0 = (v & 7) * 8;
    *(bf16x8*)(&sW[0][oc * 72 + ic0]) = *(const bf16x8*)(wb + v * 8);
  }
  int lane = threadIdx.x & 63;
  int wv = threadIdx.x >> 6;
  int m0 = wv * 16;
  int lr = lane & 15;
  int quad = lane >> 4;
  f32x4 acc[4];
#pragma unroll
  for (int nt = 0; nt < 4; nt++) {
    float bz = bias[nt * 16 + lr];
    acc[nt][0] = bz; acc[nt][1] = bz; acc[nt][2] = bz; acc[nt][3] = bz;
  }
  __syncthreads();
  for (int kk = 0; kk < 9; kk++) {
    int cur = kk & 1;
    if (kk < 8) {
      const unsigned short* src = wb + (size_t)(kk + 1) * 4096;
      for (int v = threadIdx.x; v < 512; v += 256) {
        int oc = v >> 3, ic0 = (v & 7) * 8;
        *(bf16x8*)(&sW[cur ^ 1][oc * 72 + ic0]) = *(const bf16x8*)(src + v * 8);
      }
    }
    int kh = kk / 3, kw = kk - kh * 3;
    const short* arow = &sA[((size_t)kh * 66 + (m0 + lr + kw)) * 88 + quad * 8];
#pragma unroll
    for (int ks = 0; ks < 2; ks++) {
      bf16x8 afrag = *(const bf16x8*)(arow + ks * 32);
#pragma unroll
      for (int nt = 0; nt < 4; nt++) {
        bf16x8 bfrag = *(const bf16x8*)&sW[cur][(size_t)(nt * 16 + lr) * 72 + ks * 32 + quad * 8];
        acc[nt] = __builtin_amdgcn_mfma_f32_16x16x32_bf16(afrag, bfrag, acc[nt], 0, 0, 0);
      }
    }
    __syncthreads();
  }
  int tokbase = (bt * 64 + h) * 64 + m0;
#pragma unroll
  for (int nt = 0; nt < 4; nt++) {
    int oc = nt * 16 + lr;
    float* dst = (oc < 32) ? (clr + oc) : (cli + (oc - 32));
#pragma unroll
    for (int reg = 0; reg < 4; reg++) {
      int m = quad * 4 + reg;
      dst[(size_t)(tokbase + m) * 32] = acc[nt][reg];
    }
  }
}

// ---------------- K3: forward DFT along W via bf16 MFMA ----------------
// Block = (h, bt). Out[kw][dcol] = sum_w T[kw][w] X[w][dcol], dcol: 0-31 re,
// 32-63 im. Forward combine: Or = P1r - P2i, Oi = P1i + P2r.
__global__ __launch_bounds__(256) void k3_dftw(
    const float* __restrict__ znr, const float* __restrict__ zni,
    float* __restrict__ fqr, float* __restrict__ fqi) {
  __shared__ __align__(16) short sXh[64 * 72];    // X^T hi  9.2 KB
  __shared__ __align__(16) short sXl[64 * 72];    // lo      9.2 KB
  __shared__ __align__(16) short sT[2][64 * 72];  // Tr,Ti  18.4 KB
  __shared__ float twr[64], twi[64];
  int h = blockIdx.x, bt = blockIdx.y;
  size_t base = (size_t)((bt * 64 + h) * 64) * 32;
  if (threadIdx.x < 64) {
    float ang = -2.f * PI_ * (float)threadIdx.x * (1.f / 64.f);
    twr[threadIdx.x] = cosf(ang);
    twi[threadIdx.x] = sinf(ang);
  }
  // stage X^T hi/lo (contiguous coalesced reads)
  for (int i = threadIdx.x; i < 2048; i += 256) {
    int w = i >> 5, d = i & 31;
    float vr = znr[base + i], vi = zni[base + i];
    short rh = f2bf(vr), ih = f2bf(vi);
    sXh[d * 72 + w] = rh;
    sXl[d * 72 + w] = f2bf(vr - bf2f(rh));
    sXh[(d + 32) * 72 + w] = ih;
    sXl[(d + 32) * 72 + w] = f2bf(vi - bf2f(ih));
  }
  __syncthreads();  // twr/twi + sX ready
  for (int i = threadIdx.x; i < 4096; i += 256) {
    int k = i >> 6, w = i & 63;
    int idx = (k * w) & 63;
    sT[0][k * 72 + w] = f2bf(twr[idx]);
    sT[1][k * 72 + w] = f2bf(twi[idx]);
  }
  __syncthreads();
  int lane = threadIdx.x & 63;
  int wv = threadIdx.x >> 6;
  int m0 = wv * 16;
  int lr = lane & 15;
  int quad = lane >> 4;
  const short* a_r = &sT[0][(size_t)(m0 + lr) * 72 + quad * 8];
  const short* a_i = &sT[1][(size_t)(m0 + lr) * 72 + quad * 8];
  f32x4 p1[4], p2[4];
#pragma unroll
  for (int nt = 0; nt < 4; nt++) {
    p1[nt][0] = 0.f; p1[nt][1] = 0.f; p1[nt][2] = 0.f; p1[nt][3] = 0.f;
    p2[nt][0] = 0.f; p2[nt][1] = 0.f; p2[nt][2] = 0.f; p2[nt][3] = 0.f;
  }
#pragma unroll
  for (int ks = 0; ks < 2; ks++) {
    bf16x8 tr = *(const bf16x8*)(a_r + ks * 32);
    bf16x8 ti = *(const bf16x8*)(a_i + ks * 32);
#pragma unroll
    for (int nt = 0; nt < 4; nt++) {
      bf16x8 xh = *(const bf16x8*)&sXh[(size_t)(nt * 16 + lr) * 72 + ks * 32 + quad * 8];
      bf16x8 xl = *(const bf16x8*)&sXl[(size_t)(nt * 16 + lr) * 72 + ks * 32 + quad * 8];
      p1[nt] = __builtin_amdgcn_mfma_f32_16x16x32_bf16(tr, xh, p1[nt], 0, 0, 0);
      p1[nt] = __builtin_amdgcn_mfma_f32_16x16x32_bf16(tr, xl, p1[nt], 0, 0, 0);
      p2[nt] = __builtin_amdgcn_mfma_f32_16x16x32_bf16(ti, xh, p2[nt], 0, 0, 0);
      p2[nt] = __builtin_amdgcn_mfma_f32_16x16x32_bf16(ti, xl, p2[nt], 0, 0, 0);
    }
  }
  // epilogue: forward combine, write fq[base + k*32 + d]
#pragma unroll
  for (int nt = 0; nt < 2; nt++) {
#pragma unroll
    for (int reg = 0; reg < 4; reg++) {
      int k = m0 + quad * 4 + reg;
      int d = nt * 16 + lr;
      float Or = p1[nt][reg] - p2[nt + 2][reg];
      float Oi = p1[nt + 2][reg] + p2[nt][reg];
      size_t la = base + (size_t)k * 32 + d;
      fqr[la] = Or;
      fqi[la] = Oi;
    }
  }
}

// ---------------- K4: fwd DFT along H, * filt, inv DFT along H via bf16 MFMA ----------------
__global__ __launch_bounds__(256) void k4_dfth(
    float* __restrict__ fqr, float* __restrict__ fqi,
    const float* __restrict__ flr, const float* __restrict__ fli) {
  __shared__ __align__(16) short sXh[64 * 72];    // X^T / F^T hi  9.2 KB
  __shared__ __align__(16) short sXl[64 * 72];    // lo            9.2 KB
  __shared__ __align__(16) short sT[2][64 * 72];  // Tr,Ti        18.4 KB
  __shared__ float twr[64], twi[64];
  int kw = blockIdx.x, bt = blockIdx.y;
  if (threadIdx.x < 64) {
    float ang = -2.f * PI_ * (float)threadIdx.x * (1.f / 64.f);
    twr[threadIdx.x] = cosf(ang);
    twi[threadIdx.x] = sinf(ang);
  }
  for (int i = threadIdx.x; i < 2048; i += 256) {
    int hh = i >> 5, d = i & 31;
    size_t ga = (size_t)((bt * 64 + hh) * 64 + kw) * 32 + d;
    float vr = fqr[ga], vi = fqi[ga];
    short rh = f2bf(vr), ih = f2bf(vi);
    sXh[d * 72 + hh] = rh;
    sXl[d * 72 + hh] = f2bf(vr - bf2f(rh));
    sXh[(d + 32) * 72 + hh] = ih;
    sXl[(d + 32) * 72 + hh] = f2bf(vi - bf2f(ih));
  }
  __syncthreads();
  for (int i = threadIdx.x; i < 4096; i += 256) {
    int kh = i >> 6, hh = i & 63;
    int idx = (kh * hh) & 63;
    sT[0][kh * 72 + hh] = f2bf(twr[idx]);
    sT[1][kh * 72 + hh] = f2bf(twi[idx]);
  }
  __syncthreads();
  int lane = threadIdx.x & 63;
  int wv = threadIdx.x >> 6;
  int m0 = wv * 16;
  int lr = lane & 15;
  int quad = lane >> 4;
  const short* a_r = &sT[0][(size_t)(m0 + lr) * 72 + quad * 8];
  const short* a_i = &sT[1][(size_t)(m0 + lr) * 72 + quad * 8];
  f32x4 p1[4], p2[4];
#pragma unroll
  for (int nt = 0; nt < 4; nt++) {
    p1[nt][0] = 0.f; p1[nt][1] = 0.f; p1[nt][2] = 0.f; p1[nt][3] = 0.f;
    p2[nt][0] = 0.f; p2[nt][1] = 0.f; p2[nt][2] = 0.f; p2[nt][3] = 0.f;
  }
#pragma unroll
  for (int ks = 0; ks < 2; ks++) {
    bf16x8 tr = *(const bf16x8*)(a_r + ks * 32);
    bf16x8 ti = *(const bf16x8*)(a_i + ks * 32);
#pragma unroll
    for (int nt = 0; nt < 4; nt++) {
      bf16x8 xh = *(const bf16x8*)&sXh[(size_t)(nt * 16 + lr) * 72 + ks * 32 + quad * 8];
      bf16x8 xl = *(const bf16x8*)&sXl[(size_t)(nt * 16 + lr) * 72 + ks * 32 + quad * 8];
      p1[nt] = __builtin_amdgcn_mfma_f32_16x16x32_bf16(tr, xh, p1[nt], 0, 0, 0);
      p1[nt] = __builtin_amdgcn_mfma_f32_16x16x32_bf16(tr, xl, p1[nt], 0, 0, 0);
      p2[nt] = __builtin_amdgcn_mfma_f32_16x16x32_bf16(ti, xh, p2[nt], 0, 0, 0);
      p2[nt] = __builtin_amdgcn_mfma_f32_16x16x32_bf16(ti, xl, p2[nt], 0, 0, 0);
    }
  }
  __syncthreads();
#pragma unroll
  for (int nt = 0; nt < 2; nt++) {
#pragma unroll
    for (int reg = 0; reg < 4; reg++) {
      int kh = m0 + quad * 4 + reg;
      int d = nt * 16 + lr;
      float Or = p1[nt][reg] - p2[nt + 2][reg];
      float Oi = p1[nt + 2][reg] + p2[nt][reg];
      size_t fa = (size_t)(kh * 64 + kw) * 32 + d;
      float fr = flr[fa], fi = fli[fa];
      float pr = Or * fr - Oi * fi;
      float pi = Or * fi + Oi * fr;
      short ph = f2bf(pr);
      sXh[d * 72 + kh] = ph;
      sXl[d * 72 + kh] = f2bf(pr - bf2f(ph));
      short qh = f2bf(pi);
      sXh[(d + 32) * 72 + kh] = qh;
      sXl[(d + 32) * 72 + kh] = f2bf(pi - bf2f(qh));
    }
  }
  __syncthreads();
#pragma unroll
  for (int nt = 0; nt < 4; nt++) {
    p1[nt][0] = 0.f; p1[nt][1] = 0.f; p1[nt][2] = 0.f; p1[nt][3] = 0.f;
    p2[nt][0] = 0.f; p2[nt][1] = 0.f; p2[nt][2] = 0.f; p2[nt][3] = 0.f;
  }
#pragma unroll
  for (int ks = 0; ks < 2; ks++) {
    bf16x8 tr = *(const bf16x8*)(a_r + ks * 32);
    bf16x8 ti = *(const bf16x8*)(a_i + ks * 32);
#pragma unroll
    for (int nt = 0; nt < 4; nt++) {
      bf16x8 xh = *(const bf16x8*)&sXh[(size_t)(nt * 16 + lr) * 72 + ks * 32 + quad * 8];
      bf16x8 xl = *(const bf16x8*)&sXl[(size_t)(nt * 16 + lr) * 72 + ks * 32 + quad * 8];
      p1[nt] = __builtin_amdgcn_mfma_f32_16x16x32_bf16(tr, xh, p1[nt], 0, 0, 0);
      p1[nt] = __builtin_amdgcn_mfma_f32_16x16x32_bf16(tr, xl, p1[nt], 0, 0, 0);
      p2[nt] = __builtin_amdgcn_mfma_f32_16x16x32_bf16(ti, xh, p2[nt], 0, 0, 0);
      p2[nt] = __builtin_amdgcn_mfma_f32_16x16x32_bf16(ti, xl, p2[nt], 0, 0, 0);
    }
  }
#pragma unroll
  for (int nt = 0; nt < 2; nt++) {
#pragma unroll
    for (int reg = 0; reg < 4; reg++) {
      int hh = m0 + quad * 4 + reg;
      int d = nt * 16 + lr;
      float Or = (p1[nt][reg] + p2[nt + 2][reg]) * 0.015625f;
      float Oi = (p1[nt + 2][reg] - p2[nt][reg]) * 0.015625f;
      size_t ga = (size_t)((bt * 64 + hh) * 64 + kw) * 32 + d;
      fqr[ga] = Or;
      fqi[ga] = Oi;
    }
  }
}

// ---------------- K5: inv DFT along W via bf16 MFMA + gate combine + residual ----------------
// Block = (h, bt). Out[w][d] = (1/64) sum_kw conj(T)[w][kw] F[kw][d];
// x = g*cliff + (1-g)*Out + resid -> znr/zni.
__global__ __launch_bounds__(256) void k5_idftw_combine(
    const float* __restrict__ fqr, const float* __restrict__ fqi,
    const float* __restrict__ clr, const float* __restrict__ cli,
    const float* __restrict__ xr_in, const float* __restrict__ xi_in,
    const float* __restrict__ gate,
    float* __restrict__ xr, float* __restrict__ xi) {
  __shared__ __align__(16) short sXh[64 * 72];    // F^T hi  9.2 KB
  __shared__ __align__(16) short sXl[64 * 72];    // lo      9.2 KB
  __shared__ __align__(16) short sT[2][64 * 72];  // Tr,Ti  18.4 KB
  __shared__ float twr[64], twi[64];
  int h = blockIdx.x, bt = blockIdx.y;
  size_t base = (size_t)((bt * 64 + h) * 64) * 32;
  if (threadIdx.x < 64) {
    float ang = -2.f * PI_ * (float)threadIdx.x * (1.f / 64.f);
    twr[threadIdx.x] = cosf(ang);
    twi[threadIdx.x] = sinf(ang);
  }
  for (int i = threadIdx.x; i < 2048; i += 256) {
    int kw = i >> 5, d = i & 31;
    float vr = fqr[base + i], vi = fqi[base + i];
    short rh = f2bf(vr), ih = f2bf(vi);
    sXh[d * 72 + kw] = rh;
    sXl[d * 72 + kw] = f2bf(vr - bf2f(rh));
    sXh[(d + 32) * 72 + kw] = ih;
    sXl[(d + 32) * 72 + kw] = f2bf(vi - bf2f(ih));
  }
  __syncthreads();
  for (int i = threadIdx.x; i < 4096; i += 256) {
    int w = i >> 6, kw = i & 63;
    int idx = (w * kw) & 63;
    sT[0][w * 72 + kw] = f2bf(twr[idx]);
    sT[1][w * 72 + kw] = f2bf(twi[idx]);
  }
  __syncthreads();
  int lane = threadIdx.x & 63;
  int wv = threadIdx.x >> 6;
  int m0 = wv * 16;
  int lr = lane & 15;
  int quad = lane >> 4;
  const short* a_r = &sT[0][(size_t)(m0 + lr) * 72 + quad * 8];
  const short* a_i = &sT[1][(size_t)(m0 + lr) * 72 + quad * 8];
  f32x4 p1[4], p2[4];
#pragma unroll
  for (int nt = 0; nt < 4; nt++) {
    p1[nt][0] = 0.f; p1[nt][1] = 0.f; p1[nt][2] = 0.f; p1[nt][3] = 0.f;
    p2[nt][0] = 0.f; p2[nt][1] = 0.f; p2[nt][2] = 0.f; p2[nt][3] = 0.f;
  }
#pragma unroll
  for (int ks = 0; ks < 2; ks++) {
    bf16x8 tr = *(const bf16x8*)(a_r + ks * 32);
    bf16x8 ti = *(const bf16x8*)(a_i + ks * 32);
#pragma unroll
    for (int nt = 0; nt < 4; nt++) {
      bf16x8 xh = *(const bf16x8*)&sXh[(size_t)(nt * 16 + lr) * 72 + ks * 32 + quad * 8];
      bf16x8 xl = *(const bf16x8*)&sXl[(size_t)(nt * 16 + lr) * 72 + ks * 32 + quad * 8];
      p1[nt] = __builtin_amdgcn_mfma_f32_16x16x32_bf16(tr, xh, p1[nt], 0, 0, 0);
      p1[nt] = __builtin_amdgcn_mfma_f32_16x16x32_bf16(tr, xl, p1[nt], 0, 0, 0);
      p2[nt] = __builtin_amdgcn_mfma_f32_16x16x32_bf16(ti, xh, p2[nt], 0, 0, 0);
      p2[nt] = __builtin_amdgcn_mfma_f32_16x16x32_bf16(ti, xl, p2[nt], 0, 0, 0);
    }
  }
  // epilogue: inverse combine *1/64, gate with cliff, + resid, write x
  float g = gate[0];
  float gi = 1.f - g;
#pragma unroll
  for (int nt = 0; nt < 2; nt++) {
#pragma unroll
    for (int reg = 0; reg < 4; reg++) {
      int w = m0 + quad * 4 + reg;
      int d = nt * 16 + lr;
      float Or = (p1[nt][reg] + p2[nt + 2][reg]) * 0.015625f;
      float Oi = (p1[nt + 2][reg] - p2[nt][reg]) * 0.015625f;
      size_t la = base + (size_t)w * 32 + d;
      size_t ga = (size_t)(bt * 32 + d) * 4096 + h * 64 + w;  // input [B,T,D,H,W]
      xr[la] = g * clr[la] + gi * Or + xr_in[ga];
      xi[la] = g * cli[la] + gi * Oi + xi_in[ga];
    }
  }
}

// ---------------- K6: temporal cnorm + eigen encode + decay scan + decode ----------------
__global__ __launch_bounds__(256) void k6_temporal(
    float* __restrict__ xr, float* __restrict__ xi,
    const float* __restrict__ lamr, const float* __restrict__ lami,
    const float* __restrict__ Er, const float* __restrict__ Ei,
    const float* __restrict__ Dmr, const float* __restrict__ Dmi,
    const float* __restrict__ lg, const float* __restrict__ lb,
    const float* __restrict__ dtp) {
  __shared__ float sEr[1024], sEi[1024], sDr[1024], sDi[1024];
  __shared__ __align__(16) float sXr[32 * 132];  // xt^T [d][tok], later h^T
  __shared__ __align__(16) float sXi[32 * 132];
  int n0 = blockIdx.x * 8;
  for (int i = threadIdx.x; i < 1024; i += 256) {
    sEr[i] = Er[i];
    sEi[i] = Ei[i];
    sDr[i] = Dmr[i];
    sDi[i] = Dmi[i];
  }
  if (threadIdx.x < 128) {
    int sIc = threadIdx.x >> 4;
    int t = threadIdx.x & 15;
    int n = n0 + sIc;
    int bb = n >> 12;
    int hw = n & 4095;
    size_t tokb = ((size_t)(bb * 16 + t)) * 4096 + hw;
    const float4* pr = (const float4*)(xr + tokb * 32);
    const float4* pi = (const float4*)(xi + tokb * 32);
    float rv[32], iv[32];
    float s = 0.f;
#pragma unroll
    for (int j = 0; j < 8; j++) {
      float4 a = pr[j];
      float4 c = pi[j];
      rv[4 * j] = a.x; rv[4 * j + 1] = a.y; rv[4 * j + 2] = a.z; rv[4 * j + 3] = a.w;
      iv[4 * j] = c.x; iv[4 * j + 1] = c.y; iv[4 * j + 2] = c.z; iv[4 * j + 3] = c.w;
      s += a.x + a.y + a.z + a.w + c.x + c.y + c.z + c.w;
    }
    float mu = s * 0.015625f;
    float v = 0.f;
#pragma unroll
    for (int d = 0; d < 32; d++) {
      float a = rv[d] - mu, c = iv[d] - mu;
      v += a * a + c * c;
    }
    float rstd = rsqrtf(v * 0.015625f + EPS_);
    int col = threadIdx.x;   // sIc*16 + t
#pragma unroll
    for (int d = 0; d < 32; d++) {
      sXr[d * 132 + col] = (rv[d] - mu) * rstd * lg[d] + lb[d];
      sXi[d * 132 + col] = (iv[d] - mu) * rstd * lg[32 + d] + lb[32 + d];
    }
  }
  __syncthreads();
  int sI = threadIdx.x >> 5;
  int e = threadIdx.x & 31;
  int tok0 = sI * 16;
  float dts = dtp[0];
  float lr = lamr[e], li = lami[e];
  float ex = expf(lr * dts);
  float dcr = ex * cosf(li * dts);
  float dci = ex * sinf(li * dts);
  float nr = dcr - 1.f, ni = dci;
  float invden = 1.f / (lr * lr + li * li);
  float fr = (nr * lr + ni * li) * invden;
  float fi = (ni * lr - nr * li) * invden;
  // ---- encode ----
  float xer[16], xei[16];
#pragma unroll
  for (int t = 0; t < 16; t++) { xer[t] = 0.f; xei[t] = 0.f; }
  for (int d = 0; d < 32; d++) {
    float er_ = sEr[d * 32 + e], ei_ = sEi[d * 32 + e];
    const float4* rb = (const float4*)&sXr[d * 132 + tok0];
    const float4* ib = (const float4*)&sXi[d * 132 + tok0];
#pragma unroll
    for (int j = 0; j < 4; j++) {
      float4 a4 = rb[j], c4 = ib[j];
      float av[4] = {a4.x, a4.y, a4.z, a4.w};
      float cv[4] = {c4.x, c4.y, c4.z, c4.w};
#pragma unroll
      for (int k = 0; k < 4; k++) {
        int t = 4 * j + k;
        xer[t] += av[k] * er_ - cv[k] * ei_;
        xei[t] += av[k] * ei_ + cv[k] * er_;
      }
    }
  }
  // ---- scan in registers ----
  float hr = 0.f, hi = 0.f;
#pragma unroll
  for (int t = 0; t < 16; t++) {
    float ur = xer[t] * fr - xei[t] * fi;
    float ui = xer[t] * fi + xei[t] * fr;
    float t1 = dcr * hr - dci * hi + ur;
    hi = dcr * hi + dci * hr + ui;
    hr = t1;
    sXr[e * 132 + tok0 + t] = hr;
    sXi[e * 132 + tok0 + t] = hi;
  }
  __syncthreads();
  // ---- decode ----
  float oacc[16];
#pragma unroll
  for (int t = 0; t < 16; t++) oacc[t] = 0.f;
  for (int d = 0; d < 32; d++) {
    float dr_ = sDr[d * 32 + e], di_ = sDi[d * 32 + e];
    const float4* rb = (const float4*)&sXr[d * 132 + tok0];
    const float4* ib = (const float4*)&sXi[d * 132 + tok0];
#pragma unroll
    for (int j = 0; j < 4; j++) {
      float4 a4 = rb[j], c4 = ib[j];
      float av[4] = {a4.x, a4.y, a4.z, a4.w};
      float cv[4] = {c4.x, c4.y, c4.z, c4.w};
#pragma unroll
      for (int k = 0; k < 4; k++) {
        int t = 4 * j + k;
        oacc[t] += av[k] * dr_ - cv[k] * di_;
      }
    }
  }
  int n = n0 + sI;
  int bb = n >> 12;
  int hw = n & 4095;
#pragma unroll
  for (int t = 0; t < 16; t++) {
    size_t tokb = ((size_t)(bb * 16 + t)) * 4096 + hw;
    xr[tokb * 32 + e] += oacc[t];  // drift is real-only
  }
}

// ---------------- K7: para pool MLP via bf16 MFMA + residual + output (F32 PLANAR) ----------------
// Hidden stored directly as bf16 [tok][el] (same values as prior f32->bf16 at
// read); GEMM2 A-read is a direct bf16x8 load. LDS 36.9 KB -> 4 blocks/CU.
__global__ __launch_bounds__(256) void k7_pool(
    const float* __restrict__ xr, const float* __restrict__ xi,
    const unsigned short* __restrict__ pwb1, const float* __restrict__ pb1,
    const unsigned short* __restrict__ pwb2, const float* __restrict__ pb2,
    float* __restrict__ out, long long out_n) {
  __shared__ __align__(16) short sXh[64 * 72];  // xp hi bf16 [tok][c]   9.2 KB
  __shared__ __align__(16) short sXl[64 * 72];  // xp lo bf16            9.2 KB
  __shared__ __align__(16) short sW[64 * 72];   // weight chunk [n][k]   9.2 KB
  __shared__ __align__(16) short sH[64 * 72];   // hidden bf16 [tok][el] 9.2 KB
  int tok0 = blockIdx.x * 64;
  for (int i = threadIdx.x; i < 4096; i += 256) {
    int t = i >> 6, c = i & 63;
    float v = (c < 32) ? xr[(size_t)(tok0 + t) * 32 + c]
                       : xi[(size_t)(tok0 + t) * 32 + c - 32];
    short hb = f2bf(v);
    sXh[t * 72 + c] = hb;
    sXl[t * 72 + c] = f2bf(v - bf2f(hb));
  }
  int lane = threadIdx.x & 63;
  int wv = threadIdx.x >> 6;
  int lr = lane & 15;
  int quad = lane >> 4;
  int m0 = wv * 16;
  f32x4 acc2[4];
#pragma unroll
  for (int nt = 0; nt < 4; nt++) {
    float bz = pb2[nt * 16 + lr];
    acc2[nt][0] = bz; acc2[nt][1] = bz; acc2[nt][2] = bz; acc2[nt][3] = bz;
  }
  for (int ec = 0; ec < 4; ec++) {
    __syncthreads();  // prev GEMM2 done with sW/sH; xp staged (ec=0)
    {
      const unsigned short* src = pwb1 + (size_t)ec * 4096;
      for (int v = threadIdx.x; v < 512; v += 256) {
        int el = v >> 3, c0 = (v & 7) * 8;
        *(bf16x8*)(&sW[el * 72 + c0]) = *(const bf16x8*)(src + v * 8);
      }
    }
    __syncthreads();
    f32x4 acc1[4];
#pragma unroll
    for (int nt = 0; nt < 4; nt++) {
      float bz = pb1[ec * 64 + nt * 16 + lr];
      acc1[nt][0] = bz; acc1[nt][1] = bz; acc1[nt][2] = bz; acc1[nt][3] = bz;
    }
    const short* arh = &sXh[(size_t)(m0 + lr) * 72 + quad * 8];
    const short* arl = &sXl[(size_t)(m0 + lr) * 72 + quad * 8];
#pragma unroll
    for (int ks = 0; ks < 2; ks++) {
      bf16x8 ah = *(const bf16x8*)(arh + ks * 32);
      bf16x8 al = *(const bf16x8*)(arl + ks * 32);
#pragma unroll
      for (int nt = 0; nt < 4; nt++) {
        bf16x8 bfrag = *(const bf16x8*)&sW[(size_t)(nt * 16 + lr) * 72 + ks * 32 + quad * 8];
        acc1[nt] = __builtin_amdgcn_mfma_f32_16x16x32_bf16(ah, bfrag, acc1[nt], 0, 0, 0);
        acc1[nt] = __builtin_amdgcn_mfma_f32_16x16x32_bf16(al, bfrag, acc1[nt], 0, 0, 0);
      }
    }
    // gelu -> bf16 directly (same value as prior f32-store + f2bf-at-read)
#pragma unroll
    for (int nt = 0; nt < 4; nt++) {
#pragma unroll
      for (int reg = 0; reg < 4; reg++) {
        float x = acc1[nt][reg];
        float u = 0.7978845608f * (x + 0.044715f * x * x * x);
        float e2 = __expf(2.f * u);
        float th = 1.f - 2.f / (e2 + 1.f);
        sH[(m0 + quad * 4 + reg) * 72 + nt * 16 + lr] = f2bf(0.5f * x * (1.f + th));
      }
    }
    __syncthreads();  // GEMM1 reads of sW done, sH writes done
    {
      const unsigned short* src = pwb2 + (size_t)ec * 4096;
      for (int v = threadIdx.x; v < 512; v += 256) {
        int oc = v >> 3, el0 = (v & 7) * 8;
        *(bf16x8*)(&sW[oc * 72 + el0]) = *(const bf16x8*)(src + v * 8);
      }
    }
    __syncthreads();
    // GEMM2: A = hidden bf16 direct load, accumulate into acc2
    const short* hrow = &sH[(size_t)(m0 + lr) * 72 + quad * 8];
#pragma unroll
    for (int ks = 0; ks < 2; ks++) {
      bf16x8 af = *(const bf16x8*)(hrow + ks * 32);
#pragma unroll
      for (int nt = 0; nt < 4; nt++) {
        bf16x8 bfrag = *(const bf16x8*)&sW[(size_t)(nt * 16 + lr) * 72 + ks * 32 + quad * 8];
        acc2[nt] = __builtin_amdgcn_mfma_f32_16x16x32_bf16(af, bfrag, acc2[nt], 0, 0, 0);
      }
    }
  }
  // epilogue: D[row=quad*4+reg][col=lr] -> + residual -> planar f32 out
#pragma unroll
  for (int nt = 0; nt < 4; nt++) {
    int oc = nt * 16 + lr;
#pragma unroll
    for (int reg = 0; reg < 4; reg++) {
      int t = tok0 + m0 + quad * 4 + reg;
      float resid = (oc < 32) ? xr[(size_t)t * 32 + oc] : xi[(size_t)t * 32 + oc - 32];
      float val = acc2[nt][reg] + resid;
      int bt = t >> 12;
      int hw = t & 4095;
      int d = (oc < 32) ? oc : oc - 32;
      size_t cidx = (size_t)(bt * 32 + d) * 4096 + hw;  // [B,T,D,H,W] index
      long long pos = (long long)cidx + ((oc < 32) ? 0ll : (long long)ND_);
      if (pos < out_n) out[pos] = val;
    }
  }
}

// ---------------- launch ----------------
extern "C" void kernel_launch(void* const* d_in, const int* in_sizes, int n_in,
                              void* d_out, int out_size, void* d_ws, size_t ws_size,
                              hipStream_t stream) {
  (void)in_sizes; (void)n_in;
  const float* xr_in = (const float*)d_in[0];
  const float* xi_in = (const float*)d_in[1];
  const float* dt = (const float*)d_in[2];
  const float* ln_s_g = (const float*)d_in[3];
  const float* ln_s_b = (const float*)d_in[4];
  const float* conv_w = (const float*)d_in[5];
  const float* conv_b = (const float*)d_in[6];
  const float* spec_fr = (const float*)d_in[7];
  const float* spec_fi = (const float*)d_in[8];
  const float* lam_r = (const float*)d_in[9];
  const float* lam_i = (const float*)d_in[10];
  const float* E_r = (const float*)d_in[11];
  const float* E_i = (const float*)d_in[12];
  const float* Dm_r = (const float*)d_in[13];
  const float* Dm_i = (const float*)d_in[14];
  const float* ln_t_g = (const float*)d_in[15];
  const float* ln_t_b = (const float*)d_in[16];
  const float* pw1 = (const float*)d_in[17];
  const float* pb1 = (const float*)d_in[18];
  const float* pw2 = (const float*)d_in[19];
  const float* pb2 = (const float*)d_in[20];
  const float* gate = (const float*)d_in[21];

  if (ws_size < 6ull * ND_ * 4ull) return;  // need 96 MB f32 scratch

  float* ws = (float*)d_ws;
  float* znr = ws;                 // -> becomes x_re after K5
  float* zni = ws + ND_;           // -> becomes x_im after K5
  float* clr = ws + 2 * ND_;
  float* cli = ws + 3 * ND_;
  float* fqr = ws + 4 * ND_;
  float* fqi = ws + 5 * ND_;
  float* out = (float*)d_out;
  // pre-K3 scratch aliases (consumed by K2 before K3/K4 overwrite them)
  unsigned short* znb = (unsigned short*)fqr;  // zn bf16 [tok][64], exactly ND_*4 B
  unsigned short* wb = (unsigned short*)fqi;   // conv_w bf16 [kk][oc][ic], 73 KB
  // post-K5 scratch aliases (fqr plane is dead after K5)
  unsigned short* pwb1 = (unsigned short*)fqr;       // pool w1 bf16, 32 KB
  unsigned short* pwb2 = pwb1 + 16384;               // pool w2 bf16 [ec][oc][el], 32 KB

  k0_prepw<<<144, 256, 0, stream>>>(conv_w, wb);
  k1_cnorm_spatial<<<512, 256, 0, stream>>>(xr_in, xi_in, ln_s_g, ln_s_b, znr, zni, znb);
  k2_conv<<<dim3(64, 32), 256, 0, stream>>>(znb, wb, conv_b, clr, cli);
  k3_dftw<<<dim3(64, 32), 256, 0, stream>>>(znr, zni, fqr, fqi);
  k4_dfth<<<dim3(64, 32), 256, 0, stream>>>(fqr, fqi, spec_fr, spec_fi);
  k5_idftw_combine<<<dim3(64, 32), 256, 0, stream>>>(fqr, fqi, clr, cli, xr_in, xi_in,
                                                     gate, znr, zni);
  k8_pool_prepw<<<128, 256, 0, stream>>>(pw1, pw2, pwb1, pwb2);
  k6_temporal<<<1024, 256, 0, stream>>>(znr, zni, lam_r, lam_i, E_r, E_i, Dm_r, Dm_i,
                                        ln_t_g, ln_t_b, dt);
  k7_pool<<<2048, 256, 0, stream>>>(znr, zni, pwb1, pb1, pwb2, pb2, out, (long long)out_size);
}